// Round 1
// baseline (364.522 us; speedup 1.0000x reference)
//
#include <hip/hip_runtime.h>
#include <math.h>

// S4 block: K-kernel via DPLR generating function + FFT conv + GELU + Linear + residual + LayerNorm.
// Shapes: B=8, L=4096, D=256, N=64.  All fp32.

typedef float2 cf;

__device__ __forceinline__ cf cmul(cf a, cf b){
  return make_float2(fmaf(a.x, b.x, -a.y*b.y), fmaf(a.x, b.y, a.y*b.x));
}
__device__ __forceinline__ cf cadd(cf a, cf b){ return make_float2(a.x+b.x, a.y+b.y); }
__device__ __forceinline__ cf csub(cf a, cf b){ return make_float2(a.x-b.x, a.y-b.y); }
__device__ __forceinline__ cf cscale(cf a, float s){ return make_float2(a.x*s, a.y*s); }
__device__ __forceinline__ cf cconj(cf a){ return make_float2(a.x, -a.y); }

// ---------------------------------------------------------------------------
// Stockham radix-2 complex FFT, N=4096, 256 threads, LDS ping-pong.
// dir = -1 forward, +1 inverse (no 1/N scaling applied here).
// Input in X, result ends in X (12 stages = even number of swaps). Y = scratch.
__device__ void fft4096(cf* X, cf* Y, float dir){
  cf* src = X; cf* dst = Y;
  for (int st = 0; st < 12; ++st){
    __syncthreads();
    const int s = 1 << st;
    #pragma unroll
    for (int ii = 0; ii < 8; ++ii){
      int i = threadIdx.x + (ii << 8);      // 0..2047
      int q = i & (s - 1);
      int p = i >> st;
      cf a = src[q + (p << st)];
      cf b = src[q + (p << st) + 2048];     // s*m == 2048 for every stage
      // w_p = exp(dir * i * 2*pi*p / n_cur), 2*pi/n_cur = pi/2048 * s
      float ang = dir * 1.5339807878856412e-3f * (float)(p << st);
      float sn, cs;
      __sincosf(ang, &sn, &cs);
      cf w = make_float2(cs, sn);
      int o = q + (p << (st + 1));
      dst[o]     = cadd(a, b);
      dst[o + s] = cmul(csub(a, b), w);
    }
    cf* t = src; src = dst; dst = t;
  }
  __syncthreads();
}

// ---------------------------------------------------------------------------
// Kernel 1: per-d S4 generating function -> at_roots[4096] -> ifft -> K (real)
// -> rfft(K, 8192) via packed complex-4096 trick -> Kd[d][0..4096] (complex).
__global__ __launch_bounds__(256)
void s4_kernel_kd(const float* __restrict__ B_ri, const float* __restrict__ Ct_ri,
                  const float* __restrict__ lam_ri, const float* __restrict__ p_ri,
                  const float* __restrict__ q_ri, const float* __restrict__ log_step,
                  float* __restrict__ Kd){
  __shared__ cf A[4096];
  __shared__ cf Bb[4096];
  // Phase-1 aliases inside Bb (clobbered by the first FFT stage, after a barrier).
  cf* w00  = Bb;        // conj(Ct)*B
  cf* w01  = Bb + 64;   // conj(Ct)*p
  cf* w10  = Bb + 128;  // conj(q)*B
  cf* w11  = Bb + 192;  // conj(q)*p
  cf* lamS = Bb + 256;

  const int d = blockIdx.x;
  const int tid = threadIdx.x;
  const float step = expf(log_step[d]);

  if (tid < 64){
    int n = tid;
    cf Bv = make_float2(B_ri[(d*64+n)*2],  B_ri[(d*64+n)*2+1]);
    cf Cv = make_float2(Ct_ri[(d*64+n)*2], Ct_ri[(d*64+n)*2+1]);
    cf pv = make_float2(p_ri[n*2], p_ri[n*2+1]);
    cf qv = make_float2(q_ri[n*2], q_ri[n*2+1]);
    cf lv = make_float2(lam_ri[n*2], lam_ri[n*2+1]);
    cf Cc = cconj(Cv), qc = cconj(qv);
    w00[n] = cmul(Cc, Bv);
    w01[n] = cmul(Cc, pv);
    w10[n] = cmul(qc, Bv);
    w11[n] = cmul(qc, pv);
    lamS[n] = lv;
  }
  __syncthreads();

  const float g2 = 2.0f / step;
  for (int l = tid; l < 4096; l += 256){
    cf ar;
    if (l == 2048){
      // omega -> -1: analytic limit at_roots = (step/2) * sum_n w00  (error O(1e-7))
      cf s00 = make_float2(0.f, 0.f);
      for (int n = 0; n < 64; ++n) s00 = cadd(s00, w00[n]);
      ar = cscale(s00, 0.5f * step);
    } else {
      float th = -(6.28318530717958647692f * (float)l) * (1.0f/4096.0f);
      float sn = sinf(th), cs = cosf(th);               // accurate (matters near l=2048)
      cf opw = make_float2(1.0f + cs,  sn);             // 1 + omega
      cf omw = make_float2(1.0f - cs, -sn);             // 1 - omega
      float idn = 1.0f / fmaf(opw.x, opw.x, opw.y*opw.y);
      cf ratio = make_float2((omw.x*opw.x + omw.y*opw.y)*idn,
                             (omw.y*opw.x - omw.x*opw.y)*idn);
      cf g  = cscale(ratio, g2);
      cf cc = make_float2(2.0f*opw.x*idn, -2.0f*opw.y*idn);   // 2/(1+omega)
      cf k00 = {0,0}, k01 = {0,0}, k10 = {0,0}, k11 = {0,0};
      for (int n = 0; n < 64; ++n){
        cf lv  = lamS[n];
        cf den = make_float2(g.x - lv.x, g.y - lv.y);
        float is = 1.0f / fmaf(den.x, den.x, den.y*den.y);
        cf r = make_float2(den.x*is, -den.y*is);              // 1/(g - lam)
        k00 = cadd(k00, cmul(w00[n], r));
        k01 = cadd(k01, cmul(w01[n], r));
        k10 = cadd(k10, cmul(w10[n], r));
        k11 = cadd(k11, cmul(w11[n], r));
      }
      cf onep = make_float2(1.0f + k11.x, k11.y);
      float ii = 1.0f / fmaf(onep.x, onep.x, onep.y*onep.y);
      cf inv1p = make_float2(onep.x*ii, -onep.y*ii);
      cf corr = cmul(k01, cmul(k10, inv1p));
      ar = cmul(cc, csub(k00, corr));
    }
    A[l] = ar;
  }

  // K = real(ifft(at_roots)) with 1/4096 scale
  fft4096(A, Bb, +1.0f);            // result in A

  // pack K (zero-padded to 8192) for rfft: Bb[n] = K[2n] + i*K[2n+1]
  const float inv = 1.0f / 4096.0f;
  for (int n = tid; n < 4096; n += 256){
    if (n < 2048) Bb[n] = make_float2(A[2*n].x * inv, A[2*n+1].x * inv);
    else          Bb[n] = make_float2(0.f, 0.f);
  }
  fft4096(Bb, A, -1.0f);            // result in Bb

  // unpack U[k] = rfft(K, 8192), k = 0..4096
  cf* out = (cf*)Kd + (size_t)d * 4097;
  for (int k = tid; k < 2048; k += 256){
    if (k == 0){
      cf z0 = Bb[0];
      out[0]    = make_float2(z0.x + z0.y, 0.0f);
      out[4096] = make_float2(z0.x - z0.y, 0.0f);
      out[2048] = cconj(Bb[2048]);
    } else {
      cf zk = Bb[k], zj = Bb[4096 - k];
      cf E = make_float2(0.5f*(zk.x + zj.x),  0.5f*(zk.y - zj.y));
      cf O = make_float2(0.5f*(zk.y + zj.y), -0.5f*(zk.x - zj.x));
      float phi = 7.669903939428206e-4f * (float)k;    // pi*k/4096
      float sn, cs; __sincosf(phi, &sn, &cs);
      cf t  = make_float2(cs, -sn);                    // e^{-i phi}
      cf tO = cmul(t, O);
      out[k]        = cadd(E, tO);
      out[4096 - k] = cconj(csub(E, tO));
    }
  }
}

// ---------------------------------------------------------------------------
// Kernel 2: tiled transpose u[B][L][D] -> ut[(b*256+d)][L]
__global__ __launch_bounds__(256)
void transpose_u(const float* __restrict__ u, float* __restrict__ ut){
  __shared__ float tile[32][33];
  const int b  = blockIdx.z;
  const int l0 = blockIdx.x * 32;
  const int d0 = blockIdx.y * 32;
  const int tx = threadIdx.x & 31;
  const int ty = threadIdx.x >> 5;
  const float* ub = u + (size_t)b * 4096 * 256;
  #pragma unroll
  for (int it = 0; it < 4; ++it){
    int l = l0 + ty + it*8;
    tile[tx][ty + it*8] = ub[(size_t)l*256 + d0 + tx];   // tile[d_local][l_local]
  }
  __syncthreads();
  float* utb = ut + (size_t)b * 256 * 4096;
  #pragma unroll
  for (int it = 0; it < 4; ++it){
    int dd = d0 + ty + it*8;
    utb[(size_t)dd*4096 + l0 + tx] = tile[ty + it*8][tx];
  }
}

// ---------------------------------------------------------------------------
// Kernel 3: per-(b,d) row, non-circular conv via packed real-FFT, in place.
__global__ __launch_bounds__(256)
void s4_conv(float* __restrict__ ut, const float* __restrict__ Kd){
  __shared__ cf A[4096];
  __shared__ cf Bb[4096];
  const int row = blockIdx.x;           // b*256 + d
  const int d   = row & 255;
  const int tid = threadIdx.x;
  float2* rp = (float2*)(ut + (size_t)row * 4096);

  for (int n = tid; n < 4096; n += 256)
    A[n] = (n < 2048) ? rp[n] : make_float2(0.f, 0.f);

  fft4096(A, Bb, -1.0f);                // Z in A

  const cf* kd = (const cf*)Kd + (size_t)d * 4097;
  for (int k = tid; k < 2048; k += 256){
    if (k == 0){
      cf z0 = A[0];
      float U0 = z0.x + z0.y, UN = z0.x - z0.y;
      cf P0 = cscale(kd[0], U0);
      cf PN = cscale(kd[4096], UN);
      cf cPN = cconj(PN);
      cf Ep = cscale(cadd(P0, cPN), 0.5f);
      cf Op = cscale(csub(P0, cPN), 0.5f);              // t'_0 = 1
      A[0] = make_float2(Ep.x - Op.y, Ep.y + Op.x);
      cf P = cmul(cconj(A[2048]), kd[2048]);            // U[2048] = conj(Z[2048])
      A[2048] = cconj(P);
    } else {
      cf zk = A[k], zj = A[4096 - k];
      cf E = make_float2(0.5f*(zk.x + zj.x),  0.5f*(zk.y - zj.y));
      cf O = make_float2(0.5f*(zk.y + zj.y), -0.5f*(zk.x - zj.x));
      float phi = 7.669903939428206e-4f * (float)k;     // pi*k/4096
      float sn, cs; __sincosf(phi, &sn, &cs);
      cf t  = make_float2(cs, -sn);                     // e^{-i phi}
      cf tO = cmul(t, O);
      cf Uk = cadd(E, tO);
      cf Uj = cconj(csub(E, tO));                       // U[4096-k]
      cf Pk = cmul(Uk, kd[k]);
      cf Pj = cmul(Uj, kd[4096 - k]);
      cf cPj = cconj(Pj), cPk = cconj(Pk);
      cf tp  = make_float2(cs, sn);                     // t'_k = e^{+i phi}
      cf Ek = cscale(cadd(Pk, cPj), 0.5f);
      cf Ok = cmul(tp, cscale(csub(Pk, cPj), 0.5f));
      A[k] = make_float2(Ek.x - Ok.y, Ek.y + Ok.x);
      cf tpj = make_float2(-cs, sn);                    // t'_{4096-k} = -conj(t')
      cf Ej = cscale(cadd(Pj, cPk), 0.5f);
      cf Oj = cmul(tpj, cscale(csub(Pj, cPk), 0.5f));
      A[4096 - k] = make_float2(Ej.x - Oj.y, Ej.y + Oj.x);
    }
  }

  fft4096(A, Bb, +1.0f);                // inverse; scale below
  const float inv = 1.0f / 4096.0f;
  for (int n = tid; n < 2048; n += 256)
    rp[n] = make_float2(A[n].x * inv, A[n].y * inv);    // first 4096 samples
}

// ---------------------------------------------------------------------------
// Kernel 4: transpose back + skip + exact GELU -> Z (written into d_out)
__device__ __forceinline__ float gelu_exact(float x){
  return 0.5f * x * (1.0f + erff(x * 0.70710678118654752f));
}

__global__ __launch_bounds__(256)
void fuse_skip_gelu(const float* __restrict__ convt, const float* __restrict__ u,
                    const float* __restrict__ D_skip, float* __restrict__ Z){
  __shared__ float tile[32][33];
  const int b  = blockIdx.z;
  const int l0 = blockIdx.x * 32;
  const int d0 = blockIdx.y * 32;
  const int tx = threadIdx.x & 31;
  const int ty = threadIdx.x >> 5;
  const float* cb = convt + (size_t)b * 256 * 4096;
  #pragma unroll
  for (int it = 0; it < 4; ++it){
    int dd = d0 + ty + it*8;
    tile[ty + it*8][tx] = cb[(size_t)dd*4096 + l0 + tx]; // tile[d_local][l_local]
  }
  __syncthreads();
  const float* ub = u + (size_t)b * 4096 * 256;
  float* Zb = Z + (size_t)b * 4096 * 256;
  #pragma unroll
  for (int it = 0; it < 4; ++it){
    int l  = l0 + ty + it*8;
    int dd = d0 + tx;
    float v = tile[tx][ty + it*8] + D_skip[dd] * ub[(size_t)l*256 + dd];
    Zb[(size_t)l*256 + dd] = gelu_exact(v);
  }
}

// ---------------------------------------------------------------------------
// Kernel 0: W[f][k] -> packed Wt: float4 over 4 consecutive k, indexed [k/4][f]
__global__ __launch_bounds__(256)
void transpose_w(const float* __restrict__ W, float* __restrict__ Wtp){
  __shared__ float tile[32][33];
  const int k0 = blockIdx.x * 32;
  const int f0 = blockIdx.y * 32;
  const int tx = threadIdx.x & 31;
  const int ty = threadIdx.x >> 5;
  #pragma unroll
  for (int it = 0; it < 4; ++it){
    int ff = f0 + ty + it*8;
    tile[tx][ty + it*8] = W[(size_t)ff*256 + k0 + tx];   // tile[k_local][f_local]
  }
  __syncthreads();
  #pragma unroll
  for (int it = 0; it < 4; ++it){
    int k = k0 + ty + it*8;
    int f = f0 + tx;
    Wtp[(size_t)((k >> 2)*256 + f)*4 + (k & 3)] = tile[ty + it*8][tx];
  }
}

// ---------------------------------------------------------------------------
// Kernel 5: X = Z @ W^T + b + u ; LayerNorm(X) -> out. In place on d_out.
__global__ __launch_bounds__(256)
void gemm_ln(const float* __restrict__ Wtp, const float* __restrict__ bias,
             const float* __restrict__ u, const float* __restrict__ gamma,
             const float* __restrict__ beta, float* __restrict__ ZX){
  __shared__ __align__(16) float zl[32][256];
  __shared__ float2 red[4][32];
  __shared__ float2 mv[32];
  const int t0 = blockIdx.x * 32;
  const int f  = threadIdx.x;

  const float4* Zg = (const float4*)ZX;
  #pragma unroll
  for (int i = threadIdx.x; i < 2048; i += 256){  // 32 rows * 64 float4
    int t = i >> 6, c4 = i & 63;
    ((float4*)zl)[t*64 + c4] = Zg[(size_t)(t0 + t)*64 + c4];
  }
  __syncthreads();

  float acc[32];
  #pragma unroll
  for (int t = 0; t < 32; ++t) acc[t] = 0.f;

  const float4* W4 = (const float4*)Wtp;
  for (int kb = 0; kb < 64; ++kb){
    float4 w4 = W4[kb*256 + f];
    #pragma unroll
    for (int t = 0; t < 32; ++t){
      const float4 z4 = *(const float4*)(&zl[t][kb*4]);  // LDS broadcast
      float a = acc[t];
      a = fmaf(z4.x, w4.x, a);
      a = fmaf(z4.y, w4.y, a);
      a = fmaf(z4.z, w4.z, a);
      a = fmaf(z4.w, w4.w, a);
      acc[t] = a;
    }
  }

  const float bf = bias[f], gf = gamma[f], btf = beta[f];
  #pragma unroll
  for (int t = 0; t < 32; ++t)
    acc[t] = acc[t] + bf + u[(size_t)(t0 + t)*256 + f];

  const int lane = threadIdx.x & 63, wv = threadIdx.x >> 6;
  #pragma unroll
  for (int t = 0; t < 32; ++t){
    float v = acc[t], v2 = v*v;
    for (int off = 32; off > 0; off >>= 1){
      v  += __shfl_down(v,  off);
      v2 += __shfl_down(v2, off);
    }
    if (lane == 0) red[wv][t] = make_float2(v, v2);
  }
  __syncthreads();
  if (threadIdx.x < 32){
    int t = threadIdx.x;
    float s = 0.f, s2 = 0.f;
    #pragma unroll
    for (int w = 0; w < 4; ++w){ s += red[w][t].x; s2 += red[w][t].y; }
    float mu  = s * (1.0f/256.0f);
    float var = s2 * (1.0f/256.0f) - mu*mu;
    mv[t] = make_float2(mu, rsqrtf(var + 1e-5f));
  }
  __syncthreads();
  #pragma unroll
  for (int t = 0; t < 32; ++t){
    float o = (acc[t] - mv[t].x) * mv[t].y * gf + btf;
    ZX[(size_t)(t0 + t)*256 + f] = o;
  }
}

// ---------------------------------------------------------------------------
extern "C" void kernel_launch(void* const* d_in, const int* in_sizes, int n_in,
                              void* d_out, int out_size, void* d_ws, size_t ws_size,
                              hipStream_t stream){
  (void)in_sizes; (void)n_in; (void)out_size; (void)ws_size;
  const float* u        = (const float*)d_in[0];
  const float* B_ri     = (const float*)d_in[1];
  const float* Ct_ri    = (const float*)d_in[2];
  const float* lam_ri   = (const float*)d_in[3];
  const float* p_ri     = (const float*)d_in[4];
  const float* q_ri     = (const float*)d_in[5];
  const float* log_step = (const float*)d_in[6];
  const float* D_skip   = (const float*)d_in[7];
  const float* W        = (const float*)d_in[8];
  const float* bias     = (const float*)d_in[9];
  const float* gamma    = (const float*)d_in[10];
  const float* beta     = (const float*)d_in[11];
  float* out = (float*)d_out;

  // Workspace layout (bytes): Kd 8,390,656 | Wtp 262,144 | ut 33,554,432  (total ~40.3 MB)
  char* ws = (char*)d_ws;
  float* Kd  = (float*)(ws);
  float* Wtp = (float*)(ws + 8390656);
  float* ut  = (float*)(ws + 8390656 + 262144);

  transpose_w   <<<dim3(8, 8),      256, 0, stream>>>(W, Wtp);
  s4_kernel_kd  <<<256,             256, 0, stream>>>(B_ri, Ct_ri, lam_ri, p_ri, q_ri, log_step, Kd);
  transpose_u   <<<dim3(128, 8, 8), 256, 0, stream>>>(u, ut);
  s4_conv       <<<2048,            256, 0, stream>>>(ut, Kd);
  fuse_skip_gelu<<<dim3(128, 8, 8), 256, 0, stream>>>(ut, u, D_skip, out);
  gemm_ln       <<<1024,            256, 0, stream>>>(Wtp, bias, u, gamma, beta, out);
}

// Round 2
// 304.626 us; speedup vs baseline: 1.1966x; 1.1966x over previous
//
#include <hip/hip_runtime.h>
#include <math.h>

// S4 block: K-kernel via DPLR generating function + FFT conv + GELU + MFMA Linear + residual + LayerNorm.
// Shapes: B=8, L=4096, D=256, N=64.  fp32 data, bf16 MFMA for the Linear.

typedef float2 cf;
typedef __attribute__((ext_vector_type(8))) short bf16x8;
typedef __attribute__((ext_vector_type(4))) float f32x4;

__device__ __forceinline__ cf cmul(cf a, cf b){
  return make_float2(fmaf(a.x, b.x, -a.y*b.y), fmaf(a.x, b.y, a.y*b.x));
}
__device__ __forceinline__ cf cadd(cf a, cf b){ return make_float2(a.x+b.x, a.y+b.y); }
__device__ __forceinline__ cf csub(cf a, cf b){ return make_float2(a.x-b.x, a.y-b.y); }
__device__ __forceinline__ cf cscale(cf a, float s){ return make_float2(a.x*s, a.y*s); }
__device__ __forceinline__ cf cconj(cf a){ return make_float2(a.x, -a.y); }

__device__ __forceinline__ short f2bf(float x){   // RNE float->bf16
  union { float f; unsigned u; } v; v.f = x;
  unsigned r = v.u + 0x7fffu + ((v.u >> 16) & 1u);
  return (short)(r >> 16);
}

// ---------------------------------------------------------------------------
// Stockham radix-2 complex FFT, N=4096, 256 threads, LDS ping-pong.
// dir = -1 forward, +1 inverse (no 1/N scaling applied here).
// Input in X, result ends in X (12 stages = even number of swaps). Y = scratch.
__device__ void fft4096(cf* X, cf* Y, float dir){
  cf* src = X; cf* dst = Y;
  for (int st = 0; st < 12; ++st){
    __syncthreads();
    const int s = 1 << st;
    #pragma unroll
    for (int ii = 0; ii < 8; ++ii){
      int i = threadIdx.x + (ii << 8);      // 0..2047
      int q = i & (s - 1);
      int p = i >> st;
      cf a = src[q + (p << st)];
      cf b = src[q + (p << st) + 2048];     // s*m == 2048 for every stage
      float ang = dir * 1.5339807878856412e-3f * (float)(p << st);  // pi/2048 * (p<<st)
      float sn, cs;
      __sincosf(ang, &sn, &cs);
      cf w = make_float2(cs, sn);
      int o = q + (p << (st + 1));
      dst[o]     = cadd(a, b);
      dst[o + s] = cmul(csub(a, b), w);
    }
    cf* t = src; src = dst; dst = t;
  }
  __syncthreads();
}

// ---------------------------------------------------------------------------
// Kernel 1: per-d S4 generating function -> at_roots[4096] -> ifft -> K (real)
// -> rfft(K, 8192) via packed complex-4096 trick -> Kd[d][0..4096] (complex).
__global__ __launch_bounds__(256)
void s4_kernel_kd(const float* __restrict__ B_ri, const float* __restrict__ Ct_ri,
                  const float* __restrict__ lam_ri, const float* __restrict__ p_ri,
                  const float* __restrict__ q_ri, const float* __restrict__ log_step,
                  float* __restrict__ Kd){
  __shared__ cf A[4096];
  __shared__ cf Bb[4096];
  cf* w00  = Bb;        // conj(Ct)*B
  cf* w01  = Bb + 64;   // conj(Ct)*p
  cf* w10  = Bb + 128;  // conj(q)*B
  cf* w11  = Bb + 192;  // conj(q)*p
  cf* lamS = Bb + 256;

  const int d = blockIdx.x;
  const int tid = threadIdx.x;
  const float step = expf(log_step[d]);

  if (tid < 64){
    int n = tid;
    cf Bv = make_float2(B_ri[(d*64+n)*2],  B_ri[(d*64+n)*2+1]);
    cf Cv = make_float2(Ct_ri[(d*64+n)*2], Ct_ri[(d*64+n)*2+1]);
    cf pv = make_float2(p_ri[n*2], p_ri[n*2+1]);
    cf qv = make_float2(q_ri[n*2], q_ri[n*2+1]);
    cf lv = make_float2(lam_ri[n*2], lam_ri[n*2+1]);
    cf Cc = cconj(Cv), qc = cconj(qv);
    w00[n] = cmul(Cc, Bv);
    w01[n] = cmul(Cc, pv);
    w10[n] = cmul(qc, Bv);
    w11[n] = cmul(qc, pv);
    lamS[n] = lv;
  }
  __syncthreads();

  const float g2 = 2.0f / step;
  for (int l = tid; l < 4096; l += 256){
    cf ar;
    if (l == 2048){
      cf s00 = make_float2(0.f, 0.f);
      for (int n = 0; n < 64; ++n) s00 = cadd(s00, w00[n]);
      ar = cscale(s00, 0.5f * step);
    } else {
      float th = -(6.28318530717958647692f * (float)l) * (1.0f/4096.0f);
      float sn = sinf(th), cs = cosf(th);
      cf opw = make_float2(1.0f + cs,  sn);
      cf omw = make_float2(1.0f - cs, -sn);
      float idn = 1.0f / fmaf(opw.x, opw.x, opw.y*opw.y);
      cf ratio = make_float2((omw.x*opw.x + omw.y*opw.y)*idn,
                             (omw.y*opw.x - omw.x*opw.y)*idn);
      cf g  = cscale(ratio, g2);
      cf cc = make_float2(2.0f*opw.x*idn, -2.0f*opw.y*idn);
      cf k00 = {0,0}, k01 = {0,0}, k10 = {0,0}, k11 = {0,0};
      for (int n = 0; n < 64; ++n){
        cf lv  = lamS[n];
        cf den = make_float2(g.x - lv.x, g.y - lv.y);
        float is = 1.0f / fmaf(den.x, den.x, den.y*den.y);
        cf r = make_float2(den.x*is, -den.y*is);
        k00 = cadd(k00, cmul(w00[n], r));
        k01 = cadd(k01, cmul(w01[n], r));
        k10 = cadd(k10, cmul(w10[n], r));
        k11 = cadd(k11, cmul(w11[n], r));
      }
      cf onep = make_float2(1.0f + k11.x, k11.y);
      float ii = 1.0f / fmaf(onep.x, onep.x, onep.y*onep.y);
      cf inv1p = make_float2(onep.x*ii, -onep.y*ii);
      cf corr = cmul(k01, cmul(k10, inv1p));
      ar = cmul(cc, csub(k00, corr));
    }
    A[l] = ar;
  }

  fft4096(A, Bb, +1.0f);            // K = ifft (scale applied at pack)

  const float inv = 1.0f / 4096.0f;
  for (int n = tid; n < 4096; n += 256){
    if (n < 2048) Bb[n] = make_float2(A[2*n].x * inv, A[2*n+1].x * inv);
    else          Bb[n] = make_float2(0.f, 0.f);
  }
  fft4096(Bb, A, -1.0f);            // packed rfft(K, 8192)

  cf* out = (cf*)Kd + (size_t)d * 4097;
  for (int k = tid; k < 2048; k += 256){
    if (k == 0){
      cf z0 = Bb[0];
      out[0]    = make_float2(z0.x + z0.y, 0.0f);
      out[4096] = make_float2(z0.x - z0.y, 0.0f);
      out[2048] = cconj(Bb[2048]);
    } else {
      cf zk = Bb[k], zj = Bb[4096 - k];
      cf E = make_float2(0.5f*(zk.x + zj.x),  0.5f*(zk.y - zj.y));
      cf O = make_float2(0.5f*(zk.y + zj.y), -0.5f*(zk.x - zj.x));
      float phi = 7.669903939428206e-4f * (float)k;    // pi*k/4096
      float sn, cs; __sincosf(phi, &sn, &cs);
      cf t  = make_float2(cs, -sn);
      cf tO = cmul(t, O);
      out[k]        = cadd(E, tO);
      out[4096 - k] = cconj(csub(E, tO));
    }
  }
}

// ---------------------------------------------------------------------------
// Kernel 2: tiled transpose u[B][L][D] -> ut[(b*256+d)][L]
__global__ __launch_bounds__(256)
void transpose_u(const float* __restrict__ u, float* __restrict__ ut){
  __shared__ float tile[32][33];
  const int b  = blockIdx.z;
  const int l0 = blockIdx.x * 32;
  const int d0 = blockIdx.y * 32;
  const int tx = threadIdx.x & 31;
  const int ty = threadIdx.x >> 5;
  const float* ub = u + (size_t)b * 4096 * 256;
  #pragma unroll
  for (int it = 0; it < 4; ++it){
    int l = l0 + ty + it*8;
    tile[tx][ty + it*8] = ub[(size_t)l*256 + d0 + tx];
  }
  __syncthreads();
  float* utb = ut + (size_t)b * 256 * 4096;
  #pragma unroll
  for (int it = 0; it < 4; ++it){
    int dd = d0 + ty + it*8;
    utb[(size_t)dd*4096 + l0 + tx] = tile[ty + it*8][tx];
  }
}

// ---------------------------------------------------------------------------
// Kernel 3: per-(b,d) row, non-circular conv via packed real-FFT, in place.
__global__ __launch_bounds__(256)
void s4_conv(float* __restrict__ ut, const float* __restrict__ Kd){
  __shared__ cf A[4096];
  __shared__ cf Bb[4096];
  const int row = blockIdx.x;           // b*256 + d
  const int d   = row & 255;
  const int tid = threadIdx.x;
  float2* rp = (float2*)(ut + (size_t)row * 4096);

  for (int n = tid; n < 4096; n += 256)
    A[n] = (n < 2048) ? rp[n] : make_float2(0.f, 0.f);

  fft4096(A, Bb, -1.0f);                // Z in A

  const cf* kd = (const cf*)Kd + (size_t)d * 4097;
  for (int k = tid; k < 2048; k += 256){
    if (k == 0){
      cf z0 = A[0];
      float U0 = z0.x + z0.y, UN = z0.x - z0.y;
      cf P0 = cscale(kd[0], U0);
      cf PN = cscale(kd[4096], UN);
      cf cPN = cconj(PN);
      cf Ep = cscale(cadd(P0, cPN), 0.5f);
      cf Op = cscale(csub(P0, cPN), 0.5f);
      A[0] = make_float2(Ep.x - Op.y, Ep.y + Op.x);
      cf P = cmul(cconj(A[2048]), kd[2048]);
      A[2048] = cconj(P);
    } else {
      cf zk = A[k], zj = A[4096 - k];
      cf E = make_float2(0.5f*(zk.x + zj.x),  0.5f*(zk.y - zj.y));
      cf O = make_float2(0.5f*(zk.y + zj.y), -0.5f*(zk.x - zj.x));
      float phi = 7.669903939428206e-4f * (float)k;     // pi*k/4096
      float sn, cs; __sincosf(phi, &sn, &cs);
      cf t  = make_float2(cs, -sn);
      cf tO = cmul(t, O);
      cf Uk = cadd(E, tO);
      cf Uj = cconj(csub(E, tO));
      cf Pk = cmul(Uk, kd[k]);
      cf Pj = cmul(Uj, kd[4096 - k]);
      cf cPj = cconj(Pj), cPk = cconj(Pk);
      cf tp  = make_float2(cs, sn);
      cf Ek = cscale(cadd(Pk, cPj), 0.5f);
      cf Ok = cmul(tp, cscale(csub(Pk, cPj), 0.5f));
      A[k] = make_float2(Ek.x - Ok.y, Ek.y + Ok.x);
      cf tpj = make_float2(-cs, sn);
      cf Ej = cscale(cadd(Pj, cPk), 0.5f);
      cf Oj = cmul(tpj, cscale(csub(Pj, cPk), 0.5f));
      A[4096 - k] = make_float2(Ej.x - Oj.y, Ej.y + Oj.x);
    }
  }

  fft4096(A, Bb, +1.0f);
  const float inv = 1.0f / 4096.0f;
  for (int n = tid; n < 2048; n += 256)
    rp[n] = make_float2(A[n].x * inv, A[n].y * inv);
}

// ---------------------------------------------------------------------------
// Kernel 4: transpose back + skip + exact GELU -> Z (f32, written into d_out)
__device__ __forceinline__ float gelu_exact(float x){
  return 0.5f * x * (1.0f + erff(x * 0.70710678118654752f));
}

__global__ __launch_bounds__(256)
void fuse_skip_gelu(const float* __restrict__ convt, const float* __restrict__ u,
                    const float* __restrict__ D_skip, float* __restrict__ Z){
  __shared__ float tile[32][33];
  const int b  = blockIdx.z;
  const int l0 = blockIdx.x * 32;
  const int d0 = blockIdx.y * 32;
  const int tx = threadIdx.x & 31;
  const int ty = threadIdx.x >> 5;
  const float* cb = convt + (size_t)b * 256 * 4096;
  #pragma unroll
  for (int it = 0; it < 4; ++it){
    int dd = d0 + ty + it*8;
    tile[ty + it*8][tx] = cb[(size_t)dd*4096 + l0 + tx];
  }
  __syncthreads();
  const float* ub = u + (size_t)b * 4096 * 256;
  float* Zb = Z + (size_t)b * 4096 * 256;
  #pragma unroll
  for (int it = 0; it < 4; ++it){
    int l  = l0 + ty + it*8;
    int dd = d0 + tx;
    float v = tile[tx][ty + it*8] + D_skip[dd] * ub[(size_t)l*256 + dd];
    Zb[(size_t)l*256 + dd] = gelu_exact(v);
  }
}

// ---------------------------------------------------------------------------
// Kernel 0: W[f][k] f32 -> Wb[f][k] bf16 (W is already the B-operand layout:
// lane n = f, 8 consecutive k contiguous).
__global__ __launch_bounds__(256)
void convert_w(const float* __restrict__ W, short* __restrict__ Wb){
  int i = (blockIdx.x * 256 + threadIdx.x) * 4;   // 65536 / 4 = 16384 threads
  float4 w = *(const float4*)(W + i);
  short4 o;
  o.x = f2bf(w.x); o.y = f2bf(w.y); o.z = f2bf(w.z); o.w = f2bf(w.w);
  *(short4*)(Wb + i) = o;
}

// ---------------------------------------------------------------------------
// Kernel 5: X = Z @ W^T + b + u ; LayerNorm(X) -> out. MFMA bf16, in place on
// d_out (each wave reads only its own 16 token rows, then overwrites them).
// mfma_f32_16x16x32_bf16: A lane: row=l&15, k=(l>>4)*8+j ; B lane: col=l&15,
// k=(l>>4)*8+j ; D lane: col=l&15, row=(l>>4)*4+reg  [measured m89].
__global__ __launch_bounds__(256)
void mfma_gemm_ln(const float* __restrict__ Z, const short* __restrict__ Wb,
                  const float* __restrict__ bias, const float* __restrict__ u,
                  const float* __restrict__ gamma, const float* __restrict__ beta,
                  float* __restrict__ out){
  const int w    = threadIdx.x >> 6;
  const int l    = threadIdx.x & 63;
  const int lm   = l & 15;          // A-row / B-col / D-col
  const int lk   = l >> 4;          // k-group
  const int tok0 = blockIdx.x * 64 + w * 16;

  f32x4 acc[16];
  #pragma unroll
  for (int nt = 0; nt < 16; ++nt) acc[nt] = (f32x4){0.f, 0.f, 0.f, 0.f};

  const float* zrow = Z + (size_t)(tok0 + lm) * 256;
  #pragma unroll
  for (int ks = 0; ks < 8; ++ks){
    const float4* ap = (const float4*)(zrow + ks*32 + lk*8);
    float4 a0 = ap[0], a1 = ap[1];
    bf16x8 af;
    af[0] = f2bf(a0.x); af[1] = f2bf(a0.y); af[2] = f2bf(a0.z); af[3] = f2bf(a0.w);
    af[4] = f2bf(a1.x); af[5] = f2bf(a1.y); af[6] = f2bf(a1.z); af[7] = f2bf(a1.w);
    #pragma unroll
    for (int nt = 0; nt < 16; ++nt){
      const bf16x8* bp = (const bf16x8*)(Wb + (size_t)(nt*16 + lm)*256 + ks*32 + lk*8);
      acc[nt] = __builtin_amdgcn_mfma_f32_16x16x32_bf16(af, *bp, acc[nt], 0, 0, 0);
    }
  }

  // epilogue: + bias + u, LayerNorm across 256 features (16-lane-group shuffle)
  float bb[16], gg[16], be[16];
  #pragma unroll
  for (int nt = 0; nt < 16; ++nt){
    int n = nt*16 + lm;
    bb[nt] = bias[n]; gg[nt] = gamma[n]; be[nt] = beta[n];
  }
  #pragma unroll
  for (int r = 0; r < 4; ++r){
    const int t = tok0 + lk*4 + r;
    const float* ur = u + (size_t)t * 256;
    float xv[16];
    float s = 0.f, s2 = 0.f;
    #pragma unroll
    for (int nt = 0; nt < 16; ++nt){
      float x = acc[nt][r] + bb[nt] + ur[nt*16 + lm];
      xv[nt] = x; s += x; s2 = fmaf(x, x, s2);
    }
    #pragma unroll
    for (int off = 1; off < 16; off <<= 1){
      s  += __shfl_xor(s,  off, 16);
      s2 += __shfl_xor(s2, off, 16);
    }
    float mu = s * (1.0f/256.0f);
    float rs = rsqrtf(s2 * (1.0f/256.0f) - mu*mu + 1e-5f);
    float* orow = out + (size_t)t * 256;
    #pragma unroll
    for (int nt = 0; nt < 16; ++nt)
      orow[nt*16 + lm] = (xv[nt] - mu) * rs * gg[nt] + be[nt];
  }
}

// ---------------------------------------------------------------------------
extern "C" void kernel_launch(void* const* d_in, const int* in_sizes, int n_in,
                              void* d_out, int out_size, void* d_ws, size_t ws_size,
                              hipStream_t stream){
  (void)in_sizes; (void)n_in; (void)out_size; (void)ws_size;
  const float* u        = (const float*)d_in[0];
  const float* B_ri     = (const float*)d_in[1];
  const float* Ct_ri    = (const float*)d_in[2];
  const float* lam_ri   = (const float*)d_in[3];
  const float* p_ri     = (const float*)d_in[4];
  const float* q_ri     = (const float*)d_in[5];
  const float* log_step = (const float*)d_in[6];
  const float* D_skip   = (const float*)d_in[7];
  const float* W        = (const float*)d_in[8];
  const float* bias     = (const float*)d_in[9];
  const float* gamma    = (const float*)d_in[10];
  const float* beta     = (const float*)d_in[11];
  float* out = (float*)d_out;

  // Workspace layout (bytes): Kd 8,390,656 | Wb 131,072 (pad to 262,144) | ut 33,554,432
  char* ws = (char*)d_ws;
  float* Kd  = (float*)(ws);
  short* Wb  = (short*)(ws + 8390656);
  float* ut  = (float*)(ws + 8390656 + 262144);

  convert_w     <<<64,              256, 0, stream>>>(W, Wb);
  s4_kernel_kd  <<<256,             256, 0, stream>>>(B_ri, Ct_ri, lam_ri, p_ri, q_ri, log_step, Kd);
  transpose_u   <<<dim3(128, 8, 8), 256, 0, stream>>>(u, ut);
  s4_conv       <<<2048,            256, 0, stream>>>(ut, Kd);
  fuse_skip_gelu<<<dim3(128, 8, 8), 256, 0, stream>>>(ut, u, D_skip, out);
  mfma_gemm_ln  <<<512,             256, 0, stream>>>(out, Wb, bias, u, gamma, beta, out);
}

// Round 3
// 208.658 us; speedup vs baseline: 1.7470x; 1.4599x over previous
//
#include <hip/hip_runtime.h>
#include <math.h>

// S4 block: Cauchy kernel (Hermitian-half) + even-bin identity + radix-4 FFTs
// + GELU + MFMA Linear + residual + LayerNorm.  B=8, L=4096, D=256, N=64.

typedef float2 cf;
typedef __attribute__((ext_vector_type(8))) short bf16x8;
typedef __attribute__((ext_vector_type(4))) float f32x4;

__device__ __forceinline__ cf cmul(cf a, cf b){
  return make_float2(fmaf(a.x, b.x, -a.y*b.y), fmaf(a.x, b.y, a.y*b.x));
}
__device__ __forceinline__ cf cadd(cf a, cf b){ return make_float2(a.x+b.x, a.y+b.y); }
__device__ __forceinline__ cf csub(cf a, cf b){ return make_float2(a.x-b.x, a.y-b.y); }
__device__ __forceinline__ cf cscale(cf a, float s){ return make_float2(a.x*s, a.y*s); }
__device__ __forceinline__ cf cconj(cf a){ return make_float2(a.x, -a.y); }

__device__ __forceinline__ short f2bf(float x){   // RNE float->bf16
  union { float f; unsigned u; } v; v.f = x;
  unsigned r = v.u + 0x7fffu + ((v.u >> 16) & 1u);
  return (short)(r >> 16);
}

// LDS index swizzle: keeps sequential reads conflict-free, spreads small-stride
// FFT writes across bank pairs.
__device__ __forceinline__ int SW(int i){ return i ^ ((i >> 4) & 15); }

// ---------------------------------------------------------------------------
// Radix-4 Stockham complex FFT, N=4096, 6 stages, 256 threads, LDS ping-pong.
// Derived by composing two radix-2 stages:
//   T0=A+C, T1=A-C, T2=B+D, T3=j*(B-D), j=dir*i
//   dst[o]=T0+T2; dst[o+s]=(T1+T3)w; dst[o+2s]=(T0-T2)w^2; dst[o+3s]=(T1-T3)w^3
// with w = exp(dir*2*pi*i*(p*s)/4096).  dir=-1 fwd, +1 inv (unscaled).
// All LDS accesses via SW().  Result ends in X (even # of swaps).
__device__ void fft4096r4(cf* X, cf* Y, float dir){
  cf* src = X; cf* dst = Y;
  int st2 = 0;
  #pragma unroll
  for (int st = 0; st < 6; ++st, st2 += 2){
    __syncthreads();
    const int s = 1 << st2;
    #pragma unroll
    for (int ii = 0; ii < 4; ++ii){
      int i = threadIdx.x + (ii << 8);          // butterfly 0..1023
      int q = i & (s - 1);
      int p = i >> st2;
      cf A = src[SW(i)];
      cf B = src[SW(i + 1024)];
      cf C = src[SW(i + 2048)];
      cf D = src[SW(i + 3072)];
      float ang = dir * 1.5339807878856412e-3f * (float)(p << st2);  // 2pi/4096
      float sn, cs; __sincosf(ang, &sn, &cs);
      cf w1 = make_float2(cs, sn);
      cf w2 = make_float2(fmaf(cs, cs, -sn*sn), 2.f*cs*sn);
      cf w3 = cmul(w1, w2);
      cf T0 = cadd(A, C), T1 = csub(A, C);
      cf T2 = cadd(B, D), Bd = csub(B, D);
      cf T3 = make_float2(-dir * Bd.y, dir * Bd.x);
      int o = q + (p << (st2 + 2));
      dst[SW(o)]         = cadd(T0, T2);
      dst[SW(o + s)]     = cmul(cadd(T1, T3), w1);
      dst[SW(o + 2*s)]   = cmul(csub(T0, T2), w2);
      dst[SW(o + 3*s)]   = cmul(csub(T1, T3), w3);
    }
    cf* t = src; src = dst; dst = t;
  }
  __syncthreads();
}

// ---------------------------------------------------------------------------
// Kernel 1a: Cauchy generating function, Hermitian half only (l = 0..2048).
// at_roots is Hermitian (eigenpairs of the real NPLR matrix close under
// conjugation; g is purely imaginary), and the reference's ifft().real
// projects onto the Hermitian part anyway.  Even-bin identity:
// rfft(K,8192)[2m] = fft(ifft(ar))[m] = ar[m]  ->  write ar straight into
// the even slots of Kd[d][0..4096].
__global__ __launch_bounds__(256)
void cauchy_ar(const float* __restrict__ B_ri, const float* __restrict__ Ct_ri,
               const float* __restrict__ lam_ri, const float* __restrict__ p_ri,
               const float* __restrict__ q_ri, const float* __restrict__ log_step,
               float* __restrict__ Kd){
  __shared__ cf w00[64], w01[64], w10[64], w11[64], lamS[64];
  const int d     = blockIdx.x >> 3;
  const int chunk = blockIdx.x & 7;
  const int tid   = threadIdx.x;
  const float step = expf(log_step[d]);

  if (tid < 64){
    int n = tid;
    cf Bv = make_float2(B_ri[(d*64+n)*2],  B_ri[(d*64+n)*2+1]);
    cf Cv = make_float2(Ct_ri[(d*64+n)*2], Ct_ri[(d*64+n)*2+1]);
    cf pv = make_float2(p_ri[n*2], p_ri[n*2+1]);
    cf qv = make_float2(q_ri[n*2], q_ri[n*2+1]);
    lamS[n] = make_float2(lam_ri[n*2], lam_ri[n*2+1]);
    cf Cc = cconj(Cv), qc = cconj(qv);
    w00[n] = cmul(Cc, Bv);
    w01[n] = cmul(Cc, pv);
    w10[n] = cmul(qc, Bv);
    w11[n] = cmul(qc, pv);
  }
  __syncthreads();

  cf* out = (cf*)Kd + (size_t)d * 4097;
  const int l = chunk * 256 + tid;               // 0..2047
  {
    float th = -(6.28318530717958647692f * (float)l) * (1.0f/4096.0f);
    float sn = sinf(th), cs = cosf(th);          // accurate sin/cos
    cf opw = make_float2(1.0f + cs,  sn);        // 1 + omega
    cf omw = make_float2(1.0f - cs, -sn);        // 1 - omega
    float idn = 1.0f / fmaf(opw.x, opw.x, opw.y*opw.y);
    cf ratio = make_float2((omw.x*opw.x + omw.y*opw.y)*idn,
                           (omw.y*opw.x - omw.x*opw.y)*idn);
    cf g  = cscale(ratio, 2.0f / step);
    cf cc = make_float2(2.0f*opw.x*idn, -2.0f*opw.y*idn);   // 2/(1+omega)
    cf k00 = {0,0}, k01 = {0,0}, k10 = {0,0}, k11 = {0,0};
    #pragma unroll 4
    for (int n = 0; n < 64; ++n){
      cf lv  = lamS[n];
      cf den = make_float2(g.x - lv.x, g.y - lv.y);
      float is = 1.0f / fmaf(den.x, den.x, den.y*den.y);
      cf r = make_float2(den.x*is, -den.y*is);               // 1/(g - lam)
      k00 = cadd(k00, cmul(w00[n], r));
      k01 = cadd(k01, cmul(w01[n], r));
      k10 = cadd(k10, cmul(w10[n], r));
      k11 = cadd(k11, cmul(w11[n], r));
    }
    cf onep = make_float2(1.0f + k11.x, k11.y);
    float ii = 1.0f / fmaf(onep.x, onep.x, onep.y*onep.y);
    cf inv1p = make_float2(onep.x*ii, -onep.y*ii);
    cf corr = cmul(k01, cmul(k10, inv1p));
    out[2*l] = cmul(cc, csub(k00, corr));
  }
  if (chunk == 7 && tid == 255){
    // l = 2048: omega -> -1 analytic limit: (step/2) * sum_n w00
    cf s00 = make_float2(0.f, 0.f);
    for (int n = 0; n < 64; ++n) s00 = cadd(s00, w00[n]);
    out[4096] = cscale(s00, 0.5f * step);
  }
}

// ---------------------------------------------------------------------------
// Kernel 1b: odd bins of Kd.  Kd[2m+1] = FFT4096( Re(K[n]) * e^{-i pi n/4096} )[m],
// K = ifft4096(ar).  ar read from Kd even slots (mirror-conj for n > 2048).
__global__ __launch_bounds__(256)
void fft_kd(float* __restrict__ Kd){
  __shared__ cf A[4096];
  __shared__ cf Bu[4096];
  const int d = blockIdx.x;
  const int tid = threadIdx.x;
  cf* kd = (cf*)Kd + (size_t)d * 4097;

  const float inv = 1.0f / 4096.0f;
  for (int m = tid; m < 4096; m += 256){
    cf v = (m <= 2048) ? kd[2*m] : cconj(kd[2*(4096 - m)]);
    A[SW(m)] = cscale(v, inv);
  }
  fft4096r4(A, Bu, +1.0f);            // K (imag ~ 0)

  for (int n = tid; n < 4096; n += 256){
    float kr = A[SW(n)].x;            // Re(K) — matches reference .real
    float phi = -7.669903939428206e-4f * (float)n;   // -pi*n/4096
    float sn, cs; __sincosf(phi, &sn, &cs);
    A[SW(n)] = make_float2(kr*cs, kr*sn);
  }
  fft4096r4(A, Bu, -1.0f);

  for (int m = tid; m < 2048; m += 256)
    kd[2*m + 1] = A[SW(m)];
}

// ---------------------------------------------------------------------------
// Kernel 2: tiled transpose u[B][L][D] -> ut[(b*256+d)][L]
__global__ __launch_bounds__(256)
void transpose_u(const float* __restrict__ u, float* __restrict__ ut){
  __shared__ float tile[32][33];
  const int b  = blockIdx.z;
  const int l0 = blockIdx.x * 32;
  const int d0 = blockIdx.y * 32;
  const int tx = threadIdx.x & 31;
  const int ty = threadIdx.x >> 5;
  const float* ub = u + (size_t)b * 4096 * 256;
  #pragma unroll
  for (int it = 0; it < 4; ++it){
    int l = l0 + ty + it*8;
    tile[tx][ty + it*8] = ub[(size_t)l*256 + d0 + tx];
  }
  __syncthreads();
  float* utb = ut + (size_t)b * 256 * 4096;
  #pragma unroll
  for (int it = 0; it < 4; ++it){
    int dd = d0 + ty + it*8;
    utb[(size_t)dd*4096 + l0 + tx] = tile[ty + it*8][tx];
  }
}

// ---------------------------------------------------------------------------
// Kernel 3: per-(b,d) row, non-circular conv via packed real-FFT, in place.
__global__ __launch_bounds__(256)
void s4_conv(float* __restrict__ ut, const float* __restrict__ Kd){
  __shared__ cf A[4096];
  __shared__ cf Bu[4096];
  const int row = blockIdx.x;           // b*256 + d
  const int d   = row & 255;
  const int tid = threadIdx.x;
  float2* rp = (float2*)(ut + (size_t)row * 4096);

  for (int n = tid; n < 4096; n += 256)
    A[SW(n)] = (n < 2048) ? rp[n] : make_float2(0.f, 0.f);

  fft4096r4(A, Bu, -1.0f);              // Z

  const cf* kd = (const cf*)Kd + (size_t)d * 4097;
  for (int k = tid; k < 2048; k += 256){
    if (k == 0){
      cf z0 = A[SW(0)];
      float U0 = z0.x + z0.y, UN = z0.x - z0.y;
      cf P0 = cscale(kd[0], U0);
      cf PN = cscale(kd[4096], UN);
      cf cPN = cconj(PN);
      cf Ep = cscale(cadd(P0, cPN), 0.5f);
      cf Op = cscale(csub(P0, cPN), 0.5f);
      A[SW(0)] = make_float2(Ep.x - Op.y, Ep.y + Op.x);
      cf P = cmul(cconj(A[SW(2048)]), kd[2048]);
      A[SW(2048)] = cconj(P);
    } else {
      cf zk = A[SW(k)], zj = A[SW(4096 - k)];
      cf E = make_float2(0.5f*(zk.x + zj.x),  0.5f*(zk.y - zj.y));
      cf O = make_float2(0.5f*(zk.y + zj.y), -0.5f*(zk.x - zj.x));
      float phi = 7.669903939428206e-4f * (float)k;     // pi*k/4096
      float sn, cs; __sincosf(phi, &sn, &cs);
      cf t  = make_float2(cs, -sn);
      cf tO = cmul(t, O);
      cf Uk = cadd(E, tO);
      cf Uj = cconj(csub(E, tO));
      cf Pk = cmul(Uk, kd[k]);
      cf Pj = cmul(Uj, kd[4096 - k]);
      cf cPj = cconj(Pj), cPk = cconj(Pk);
      cf tp  = make_float2(cs, sn);
      cf Ek = cscale(cadd(Pk, cPj), 0.5f);
      cf Ok = cmul(tp, cscale(csub(Pk, cPj), 0.5f));
      A[SW(k)] = make_float2(Ek.x - Ok.y, Ek.y + Ok.x);
      cf tpj = make_float2(-cs, sn);
      cf Ej = cscale(cadd(Pj, cPk), 0.5f);
      cf Oj = cmul(tpj, cscale(csub(Pj, cPk), 0.5f));
      A[SW(4096 - k)] = make_float2(Ej.x - Oj.y, Ej.y + Oj.x);
    }
  }

  fft4096r4(A, Bu, +1.0f);
  const float inv = 1.0f / 4096.0f;
  for (int n = tid; n < 2048; n += 256)
    rp[n] = make_float2(A[SW(n)].x * inv, A[SW(n)].y * inv);
}

// ---------------------------------------------------------------------------
// Kernel 4: transpose back + skip + exact GELU -> Z (f32, written into d_out)
__device__ __forceinline__ float gelu_exact(float x){
  return 0.5f * x * (1.0f + erff(x * 0.70710678118654752f));
}

__global__ __launch_bounds__(256)
void fuse_skip_gelu(const float* __restrict__ convt, const float* __restrict__ u,
                    const float* __restrict__ D_skip, float* __restrict__ Z){
  __shared__ float tile[32][33];
  const int b  = blockIdx.z;
  const int l0 = blockIdx.x * 32;
  const int d0 = blockIdx.y * 32;
  const int tx = threadIdx.x & 31;
  const int ty = threadIdx.x >> 5;
  const float* cb = convt + (size_t)b * 256 * 4096;
  #pragma unroll
  for (int it = 0; it < 4; ++it){
    int dd = d0 + ty + it*8;
    tile[ty + it*8][tx] = cb[(size_t)dd*4096 + l0 + tx];
  }
  __syncthreads();
  const float* ub = u + (size_t)b * 4096 * 256;
  float* Zb = Z + (size_t)b * 4096 * 256;
  #pragma unroll
  for (int it = 0; it < 4; ++it){
    int l  = l0 + ty + it*8;
    int dd = d0 + tx;
    float v = tile[tx][ty + it*8] + D_skip[dd] * ub[(size_t)l*256 + dd];
    Zb[(size_t)l*256 + dd] = gelu_exact(v);
  }
}

// ---------------------------------------------------------------------------
// Kernel 0: W[f][k] f32 -> Wb[f][k] bf16 (already the MFMA B-operand layout).
__global__ __launch_bounds__(256)
void convert_w(const float* __restrict__ W, short* __restrict__ Wb){
  int i = (blockIdx.x * 256 + threadIdx.x) * 4;
  float4 w = *(const float4*)(W + i);
  short4 o;
  o.x = f2bf(w.x); o.y = f2bf(w.y); o.z = f2bf(w.z); o.w = f2bf(w.w);
  *(short4*)(Wb + i) = o;
}

// ---------------------------------------------------------------------------
// Kernel 5: X = Z @ W^T + b + u ; LayerNorm(X) -> out. MFMA bf16, in place on
// d_out.  mfma_f32_16x16x32_bf16: A row=l&15,k=(l>>4)*8+j; B col=l&15; D
// col=l&15,row=(l>>4)*4+reg  [measured m89].
__global__ __launch_bounds__(256)
void mfma_gemm_ln(const float* __restrict__ Z, const short* __restrict__ Wb,
                  const float* __restrict__ bias, const float* __restrict__ u,
                  const float* __restrict__ gamma, const float* __restrict__ beta,
                  float* __restrict__ out){
  const int w    = threadIdx.x >> 6;
  const int l    = threadIdx.x & 63;
  const int lm   = l & 15;
  const int lk   = l >> 4;
  const int tok0 = blockIdx.x * 64 + w * 16;

  f32x4 acc[16];
  #pragma unroll
  for (int nt = 0; nt < 16; ++nt) acc[nt] = (f32x4){0.f, 0.f, 0.f, 0.f};

  const float* zrow = Z + (size_t)(tok0 + lm) * 256;
  #pragma unroll
  for (int ks = 0; ks < 8; ++ks){
    const float4* ap = (const float4*)(zrow + ks*32 + lk*8);
    float4 a0 = ap[0], a1 = ap[1];
    bf16x8 af;
    af[0] = f2bf(a0.x); af[1] = f2bf(a0.y); af[2] = f2bf(a0.z); af[3] = f2bf(a0.w);
    af[4] = f2bf(a1.x); af[5] = f2bf(a1.y); af[6] = f2bf(a1.z); af[7] = f2bf(a1.w);
    #pragma unroll
    for (int nt = 0; nt < 16; ++nt){
      const bf16x8* bp = (const bf16x8*)(Wb + (size_t)(nt*16 + lm)*256 + ks*32 + lk*8);
      acc[nt] = __builtin_amdgcn_mfma_f32_16x16x32_bf16(af, *bp, acc[nt], 0, 0, 0);
    }
  }

  float bb[16], gg[16], be[16];
  #pragma unroll
  for (int nt = 0; nt < 16; ++nt){
    int n = nt*16 + lm;
    bb[nt] = bias[n]; gg[nt] = gamma[n]; be[nt] = beta[n];
  }
  #pragma unroll
  for (int r = 0; r < 4; ++r){
    const int t = tok0 + lk*4 + r;
    const float* ur = u + (size_t)t * 256;
    float xv[16];
    float s = 0.f, s2 = 0.f;
    #pragma unroll
    for (int nt = 0; nt < 16; ++nt){
      float x = acc[nt][r] + bb[nt] + ur[nt*16 + lm];
      xv[nt] = x; s += x; s2 = fmaf(x, x, s2);
    }
    #pragma unroll
    for (int off = 1; off < 16; off <<= 1){
      s  += __shfl_xor(s,  off, 16);
      s2 += __shfl_xor(s2, off, 16);
    }
    float mu = s * (1.0f/256.0f);
    float rs = rsqrtf(s2 * (1.0f/256.0f) - mu*mu + 1e-5f);
    float* orow = out + (size_t)t * 256;
    #pragma unroll
    for (int nt = 0; nt < 16; ++nt)
      orow[nt*16 + lm] = (xv[nt] - mu) * rs * gg[nt] + be[nt];
  }
}

// ---------------------------------------------------------------------------
extern "C" void kernel_launch(void* const* d_in, const int* in_sizes, int n_in,
                              void* d_out, int out_size, void* d_ws, size_t ws_size,
                              hipStream_t stream){
  (void)in_sizes; (void)n_in; (void)out_size; (void)ws_size;
  const float* u        = (const float*)d_in[0];
  const float* B_ri     = (const float*)d_in[1];
  const float* Ct_ri    = (const float*)d_in[2];
  const float* lam_ri   = (const float*)d_in[3];
  const float* p_ri     = (const float*)d_in[4];
  const float* q_ri     = (const float*)d_in[5];
  const float* log_step = (const float*)d_in[6];
  const float* D_skip   = (const float*)d_in[7];
  const float* W        = (const float*)d_in[8];
  const float* bias     = (const float*)d_in[9];
  const float* gamma    = (const float*)d_in[10];
  const float* beta     = (const float*)d_in[11];
  float* out = (float*)d_out;

  // Workspace: Kd 8,390,656 B | Wb 131,072 B (pad 262,144) | ut 33,554,432 B
  char* ws = (char*)d_ws;
  float* Kd  = (float*)(ws);
  short* Wb  = (short*)(ws + 8390656);
  float* ut  = (float*)(ws + 8390656 + 262144);

  convert_w     <<<64,              256, 0, stream>>>(W, Wb);
  cauchy_ar     <<<2048,            256, 0, stream>>>(B_ri, Ct_ri, lam_ri, p_ri, q_ri, log_step, Kd);
  fft_kd        <<<256,             256, 0, stream>>>(Kd);
  transpose_u   <<<dim3(128, 8, 8), 256, 0, stream>>>(u, ut);
  s4_conv       <<<2048,            256, 0, stream>>>(ut, Kd);
  fuse_skip_gelu<<<dim3(128, 8, 8), 256, 0, stream>>>(ut, u, D_skip, out);
  mfma_gemm_ln  <<<512,             256, 0, stream>>>(out, Wb, bias, u, gamma, beta, out);
}

// Round 4
// 159.120 us; speedup vs baseline: 2.2909x; 1.3113x over previous
//
#include <hip/hip_runtime.h>
#include <math.h>

// S4 block: Cauchy (Hermitian-half) + even-bin identity + register four-step
// FFTs (16x16x16) + fused GELU+MFMA Linear + residual + LayerNorm.
// B=8, L=4096, D=256, N=64.

typedef float2 cf;
typedef __attribute__((ext_vector_type(8))) short bf16x8;
typedef __attribute__((ext_vector_type(4))) float f32x4;

__device__ __forceinline__ cf cmul(cf a, cf b){
  return make_float2(fmaf(a.x, b.x, -a.y*b.y), fmaf(a.x, b.y, a.y*b.x));
}
__device__ __forceinline__ cf cadd(cf a, cf b){ return make_float2(a.x+b.x, a.y+b.y); }
__device__ __forceinline__ cf csub(cf a, cf b){ return make_float2(a.x-b.x, a.y-b.y); }
__device__ __forceinline__ cf cscale(cf a, float s){ return make_float2(a.x*s, a.y*s); }
__device__ __forceinline__ cf cconj(cf a){ return make_float2(a.x, -a.y); }

__device__ __forceinline__ short f2bf(float x){   // RNE float->bf16
  union { float f; unsigned u; } v; v.f = x;
  unsigned r = v.u + 0x7fffu + ((v.u >> 16) & 1u);
  return (short)(r >> 16);
}

// LDS swizzle: XOR bits[7:4] into bits[3:0]. Balances every exchange pattern
// of the four-step FFT to the 4-lanes-per-bank-pair b64 minimum.
__device__ __forceinline__ int SW(int i){ return i ^ ((i >> 4) & 15); }
// After fft16, output V[k] sits in v[RI(k)].
__device__ __forceinline__ constexpr int RI(int k){ return ((k & 3) << 2) | (k >> 2); }

#define C8 0.92387953251f
#define S8 0.38268343236f
#define RH 0.70710678119f

// DFT4 (w = e^{dir*2pi*i/4}): a..d in natural order -> X0..X3 in a..d.
__device__ __forceinline__ void r4(cf& a, cf& b, cf& c, cf& d, float dir){
  cf T0 = cadd(a, c), T1 = csub(a, c);
  cf T2 = cadd(b, d), Bd = csub(b, d);
  cf T3 = make_float2(-dir*Bd.y, dir*Bd.x);     // J*(b-d), J = dir*i
  a = cadd(T0, T2); b = cadd(T1, T3); c = csub(T0, T2); d = csub(T1, T3);
}

// FFT16 of v[0..15] (natural input order). Output V[k] at v[RI(k)].
// Four-step 16 = 4x4: DFT4 over stride-4, constant twiddles w16^{c*b}, DFT4.
__device__ __forceinline__ void fft16(cf* v, float dir){
  r4(v[0], v[4], v[8],  v[12], dir);
  r4(v[1], v[5], v[9],  v[13], dir);
  r4(v[2], v[6], v[10], v[14], dir);
  r4(v[3], v[7], v[11], v[15], dir);
  cf w1 = make_float2(C8,  dir*S8);
  cf w2 = make_float2(RH,  dir*RH);
  cf w3 = make_float2(S8,  dir*C8);
  cf w4 = make_float2(0.f, dir);
  cf w6 = make_float2(-RH, dir*RH);
  cf w9 = make_float2(-C8, -dir*S8);
  v[5]  = cmul(v[5],  w1); v[6]  = cmul(v[6],  w2); v[7]  = cmul(v[7],  w3);
  v[9]  = cmul(v[9],  w2); v[10] = cmul(v[10], w4); v[11] = cmul(v[11], w6);
  v[13] = cmul(v[13], w3); v[14] = cmul(v[14], w6); v[15] = cmul(v[15], w9);
  r4(v[0],  v[1],  v[2],  v[3],  dir);
  r4(v[4],  v[5],  v[6],  v[7],  dir);
  r4(v[8],  v[9],  v[10], v[11], dir);
  r4(v[12], v[13], v[14], v[15], dir);
}

// 4096-pt FFT, four-step 16x(16x16), one shared cf[4096] buffer (SW-indexed).
// Entry: v[n1] = x[n1*256 + t], t = threadIdx.x.
// Exit:  V[k1 + 16*ka + 256*kb] = v[RI(kb)], k1 = t>>4, ka = t&15.
// Starts with a barrier (protects caller's prior LDS reads).
__device__ void fft4096_reg(cf* v, cf* lds, float dir){
  const int t = threadIdx.x;
  fft16(v, dir);
  float sn, cs;
  __sincosf(dir * 1.5339807878856412e-3f * (float)t, &sn, &cs);   // 2pi/4096
  cf w = make_float2(cs, sn), cw = w;
  __syncthreads();
  lds[SW(t)] = v[0];
  #pragma unroll
  for (int k1 = 1; k1 < 16; ++k1){
    lds[SW(k1*256 + t)] = cmul(v[RI(k1)], cw);
    cw = cmul(cw, w);
  }
  __syncthreads();
  const int k1 = t >> 4, m2 = t & 15;
  #pragma unroll
  for (int m1 = 0; m1 < 16; ++m1) v[m1] = lds[SW(k1*256 + m1*16 + m2)];
  fft16(v, dir);
  __sincosf(dir * 2.45436926061703e-2f * (float)m2, &sn, &cs);    // 2pi/256
  w = make_float2(cs, sn); cw = w;
  __syncthreads();
  lds[SW(k1*256 + m2)] = v[0];
  #pragma unroll
  for (int ka = 1; ka < 16; ++ka){
    lds[SW(k1*256 + ka*16 + m2)] = cmul(v[RI(ka)], cw);
    cw = cmul(cw, w);
  }
  __syncthreads();
  const int ka = t & 15;
  #pragma unroll
  for (int m2b = 0; m2b < 16; ++m2b) v[m2b] = lds[SW(k1*256 + ka*16 + m2b)];
  fft16(v, dir);
}

// ---------------------------------------------------------------------------
// Kernel 1a: Cauchy generating function, Hermitian half (l = 0..2048).
// Even-bin identity: rfft(K,8192)[2m] = ar[m] -> KdE[d][m], m = 0..2048.
__global__ __launch_bounds__(256)
void cauchy_ar(const float* __restrict__ B_ri, const float* __restrict__ Ct_ri,
               const float* __restrict__ lam_ri, const float* __restrict__ p_ri,
               const float* __restrict__ q_ri, const float* __restrict__ log_step,
               float* __restrict__ KdE){
  __shared__ cf w00[64], w01[64], w10[64], w11[64], lamS[64];
  const int d     = blockIdx.x >> 3;
  const int chunk = blockIdx.x & 7;
  const int tid   = threadIdx.x;
  const float step = expf(log_step[d]);

  if (tid < 64){
    int n = tid;
    cf Bv = make_float2(B_ri[(d*64+n)*2],  B_ri[(d*64+n)*2+1]);
    cf Cv = make_float2(Ct_ri[(d*64+n)*2], Ct_ri[(d*64+n)*2+1]);
    cf pv = make_float2(p_ri[n*2], p_ri[n*2+1]);
    cf qv = make_float2(q_ri[n*2], q_ri[n*2+1]);
    lamS[n] = make_float2(lam_ri[n*2], lam_ri[n*2+1]);
    cf Cc = cconj(Cv), qc = cconj(qv);
    w00[n] = cmul(Cc, Bv);
    w01[n] = cmul(Cc, pv);
    w10[n] = cmul(qc, Bv);
    w11[n] = cmul(qc, pv);
  }
  __syncthreads();

  cf* out = (cf*)KdE + (size_t)d * 2049;
  const int l = chunk * 256 + tid;               // 0..2047
  {
    float th = -(6.28318530717958647692f * (float)l) * (1.0f/4096.0f);
    float sn = sinf(th), cs = cosf(th);          // accurate sin/cos
    cf opw = make_float2(1.0f + cs,  sn);        // 1 + omega
    cf omw = make_float2(1.0f - cs, -sn);        // 1 - omega
    float idn = 1.0f / fmaf(opw.x, opw.x, opw.y*opw.y);
    cf ratio = make_float2((omw.x*opw.x + omw.y*opw.y)*idn,
                           (omw.y*opw.x - omw.x*opw.y)*idn);
    cf g  = cscale(ratio, 2.0f / step);
    cf cc = make_float2(2.0f*opw.x*idn, -2.0f*opw.y*idn);   // 2/(1+omega)
    cf k00 = {0,0}, k01 = {0,0}, k10 = {0,0}, k11 = {0,0};
    #pragma unroll 4
    for (int n = 0; n < 64; ++n){
      cf lv  = lamS[n];
      cf den = make_float2(g.x - lv.x, g.y - lv.y);
      float is = 1.0f / fmaf(den.x, den.x, den.y*den.y);
      cf r = make_float2(den.x*is, -den.y*is);               // 1/(g - lam)
      k00 = cadd(k00, cmul(w00[n], r));
      k01 = cadd(k01, cmul(w01[n], r));
      k10 = cadd(k10, cmul(w10[n], r));
      k11 = cadd(k11, cmul(w11[n], r));
    }
    cf onep = make_float2(1.0f + k11.x, k11.y);
    float ii = 1.0f / fmaf(onep.x, onep.x, onep.y*onep.y);
    cf inv1p = make_float2(onep.x*ii, -onep.y*ii);
    cf corr = cmul(k01, cmul(k10, inv1p));
    out[l] = cmul(cc, csub(k00, corr));
  }
  if (chunk == 7 && tid == 255){
    // l = 2048: omega -> -1 analytic limit: (step/2) * sum_n w00
    cf s00 = make_float2(0.f, 0.f);
    for (int n = 0; n < 64; ++n) s00 = cadd(s00, w00[n]);
    out[2048] = cscale(s00, 0.5f * step);
  }
}

// ---------------------------------------------------------------------------
// Kernel 1b: odd bins. KdO[d][m] = FFT4096( Re(K[n]) e^{-i pi n/4096} )[m],
// m = 0..2047, where K = ifft4096(ar), ar from KdE (mirror-conj for n>2048).
__global__ __launch_bounds__(256)
void fft_kd(const float* __restrict__ KdE, float* __restrict__ KdO){
  __shared__ cf L[4096];
  const int d = blockIdx.x, t = threadIdx.x;
  const cf* kdE = (const cf*)KdE + (size_t)d * 2049;
  cf* kdO = (cf*)KdO + (size_t)d * 2048;
  cf v[16];
  const float inv = 1.0f / 4096.0f;
  #pragma unroll
  for (int n1 = 0; n1 < 16; ++n1){
    int m = n1*256 + t;
    cf a = (m <= 2048) ? kdE[m] : cconj(kdE[4096 - m]);
    v[n1] = cscale(a, inv);
  }
  fft4096_reg(v, L, +1.0f);            // K (real part is K)
  const int k1 = t >> 4, ka = t & 15;
  __syncthreads();
  #pragma unroll
  for (int kb = 0; kb < 16; ++kb){
    int g = k1 + 16*ka + 256*kb;
    float kr = v[RI(kb)].x;            // Re(K) — matches reference .real
    float sn, cs; __sincosf(-7.669903939428206e-4f * (float)g, &sn, &cs);
    L[SW(g)] = make_float2(kr*cs, kr*sn);
  }
  __syncthreads();
  #pragma unroll
  for (int n1 = 0; n1 < 16; ++n1) v[n1] = L[SW(n1*256 + t)];
  fft4096_reg(v, L, -1.0f);
  #pragma unroll
  for (int kb = 0; kb < 8; ++kb)
    kdO[k1 + 16*ka + 256*kb] = v[RI(kb)];
}

// ---------------------------------------------------------------------------
// Kernel 2: tiled transpose u[B][L][D] -> ut[(b*256+d)][L]
__global__ __launch_bounds__(256)
void transpose_u(const float* __restrict__ u, float* __restrict__ ut){
  __shared__ float tile[32][33];
  const int b  = blockIdx.z;
  const int l0 = blockIdx.x * 32;
  const int d0 = blockIdx.y * 32;
  const int tx = threadIdx.x & 31;
  const int ty = threadIdx.x >> 5;
  const float* ub = u + (size_t)b * 4096 * 256;
  #pragma unroll
  for (int it = 0; it < 4; ++it){
    int l = l0 + ty + it*8;
    tile[tx][ty + it*8] = ub[(size_t)l*256 + d0 + tx];
  }
  __syncthreads();
  float* utb = ut + (size_t)b * 256 * 4096;
  #pragma unroll
  for (int it = 0; it < 4; ++it){
    int dd = d0 + ty + it*8;
    utb[(size_t)dd*4096 + l0 + tx] = tile[ty + it*8][tx];
  }
}

// ---------------------------------------------------------------------------
// Kernel 3: per-(b,d) non-circular conv via packed real-FFT, in place on ut.
__global__ __launch_bounds__(256)
void s4_conv(float* __restrict__ ut, const float* __restrict__ KdE,
             const float* __restrict__ KdO){
  __shared__ cf L[4096];
  const int row = blockIdx.x;           // b*256 + d
  const int d   = row & 255;
  const int t   = threadIdx.x;
  float2* rp = (float2*)(ut + (size_t)row * 4096);

  cf v[16];
  #pragma unroll
  for (int n1 = 0; n1 < 8; ++n1) v[n1] = rp[n1*256 + t];
  #pragma unroll
  for (int n1 = 8; n1 < 16; ++n1) v[n1] = make_float2(0.f, 0.f);

  fft4096_reg(v, L, -1.0f);             // Z
  const int k1 = t >> 4, ka = t & 15;
  __syncthreads();
  #pragma unroll
  for (int kb = 0; kb < 16; ++kb)
    L[SW(k1 + 16*ka + 256*kb)] = v[RI(kb)];
  __syncthreads();

  const cf* kdE = (const cf*)KdE + (size_t)d * 2049;
  const cf* kdO = (const cf*)KdO + (size_t)d * 2048;
  #pragma unroll
  for (int m = 0; m < 8; ++m){
    int k = t + m*256;                  // 0..2047
    if (k == 0){
      cf z0 = L[SW(0)];
      float U0 = z0.x + z0.y, UN = z0.x - z0.y;
      cf P0 = cscale(kdE[0], U0);
      cf PN = cscale(kdE[2048], UN);
      cf cPN = cconj(PN);
      cf Ep = cscale(cadd(P0, cPN), 0.5f);
      cf Op = cscale(csub(P0, cPN), 0.5f);
      L[SW(0)] = make_float2(Ep.x - Op.y, Ep.y + Op.x);
      cf P = cmul(cconj(L[SW(2048)]), kdE[1024]);
      L[SW(2048)] = cconj(P);
    } else {
      cf zk = L[SW(k)], zj = L[SW(4096 - k)];
      cf E = make_float2(0.5f*(zk.x + zj.x),  0.5f*(zk.y - zj.y));
      cf O = make_float2(0.5f*(zk.y + zj.y), -0.5f*(zk.x - zj.x));
      float phi = 7.669903939428206e-4f * (float)k;     // pi*k/4096
      float sn, cs; __sincosf(phi, &sn, &cs);
      cf tw = make_float2(cs, -sn);
      cf tO = cmul(tw, O);
      cf Uk = cadd(E, tO);
      cf Uj = cconj(csub(E, tO));                        // U[4096-k]
      int h = k >> 1;
      cf kk, kj;
      if (k & 1){ kk = kdO[h]; kj = kdO[2047 - h]; }
      else      { kk = kdE[h]; kj = kdE[2048 - h]; }
      cf Pk = cmul(Uk, kk);
      cf Pj = cmul(Uj, kj);
      cf cPj = cconj(Pj), cPk = cconj(Pk);
      cf tp  = make_float2(cs, sn);                      // e^{+i phi}
      cf Ek = cscale(cadd(Pk, cPj), 0.5f);
      cf Ok = cmul(tp, cscale(csub(Pk, cPj), 0.5f));
      L[SW(k)] = make_float2(Ek.x - Ok.y, Ek.y + Ok.x);
      cf tpj = make_float2(-cs, sn);                     // t'_{4096-k}
      cf Ej = cscale(cadd(Pj, cPk), 0.5f);
      cf Oj = cmul(tpj, cscale(csub(Pj, cPk), 0.5f));
      L[SW(4096 - k)] = make_float2(Ej.x - Oj.y, Ej.y + Oj.x);
    }
  }
  __syncthreads();

  #pragma unroll
  for (int n1 = 0; n1 < 16; ++n1) v[n1] = L[SW(n1*256 + t)];
  fft4096_reg(v, L, +1.0f);
  const float inv = 1.0f / 4096.0f;
  #pragma unroll
  for (int kb = 0; kb < 8; ++kb)
    rp[k1 + 16*ka + 256*kb] = cscale(v[RI(kb)], inv);
}

// ---------------------------------------------------------------------------
// Kernel 0: W[f][k] f32 -> Wb[f][k] bf16 (already the MFMA B-operand layout).
__global__ __launch_bounds__(256)
void convert_w(const float* __restrict__ W, short* __restrict__ Wb){
  int i = (blockIdx.x * 256 + threadIdx.x) * 4;
  float4 w = *(const float4*)(W + i);
  short4 o;
  o.x = f2bf(w.x); o.y = f2bf(w.y); o.z = f2bf(w.z); o.w = f2bf(w.w);
  *(short4*)(Wb + i) = o;
}

// ---------------------------------------------------------------------------
// Kernel 5: fused  Z = gelu(conv + D_skip*u)  ->  X = Z@W^T + b + u  ->  LN.
// A-fragments gathered straight from ut (conv, [d][L] layout) + u; exact GELU
// in-flight; MFMA bf16; epilogue LN in registers.  Writes d_out only.
__device__ __forceinline__ float gelu_exact(float x){
  return 0.5f * x * (1.0f + erff(x * 0.70710678118654752f));
}

__global__ __launch_bounds__(256)
void mfma_gemm_ln(const float* __restrict__ ut, const short* __restrict__ Wb,
                  const float* __restrict__ Dsk, const float* __restrict__ bias,
                  const float* __restrict__ u, const float* __restrict__ gamma,
                  const float* __restrict__ beta, float* __restrict__ out){
  const int w    = threadIdx.x >> 6;
  const int l    = threadIdx.x & 63;
  const int lm   = l & 15;           // A-row / B-col / D-col
  const int lk   = l >> 4;           // k-group
  const int tokB = blockIdx.x * 64;  // 64 tokens/block, never straddles batch
  const int b    = tokB >> 12;
  const int tok0 = tokB + w * 16;
  const int tg   = tok0 + lm;        // this lane's A-row (global token)
  const int ll   = tg & 4095;        // l within batch

  f32x4 acc[16];
  #pragma unroll
  for (int nt = 0; nt < 16; ++nt) acc[nt] = (f32x4){0.f, 0.f, 0.f, 0.f};

  const float* urow = u + (size_t)tg * 256;
  #pragma unroll
  for (int ks = 0; ks < 8; ++ks){
    const int k0 = ks*32 + lk*8;
    const float4 u0 = *(const float4*)(urow + k0);
    const float4 u1 = *(const float4*)(urow + k0 + 4);
    const float uu[8] = {u0.x, u0.y, u0.z, u0.w, u1.x, u1.y, u1.z, u1.w};
    const float* cbase = ut + (size_t)(b*256 + k0) * 4096 + ll;
    bf16x8 af;
    #pragma unroll
    for (int j = 0; j < 8; ++j){
      float cv = cbase[(size_t)j * 4096];
      float x  = fmaf(Dsk[k0 + j], uu[j], cv);
      af[j] = f2bf(gelu_exact(x));
    }
    #pragma unroll
    for (int nt = 0; nt < 16; ++nt){
      const bf16x8* bp = (const bf16x8*)(Wb + (size_t)(nt*16 + lm)*256 + k0);
      acc[nt] = __builtin_amdgcn_mfma_f32_16x16x32_bf16(af, *bp, acc[nt], 0, 0, 0);
    }
  }

  float bb[16], gg[16], be[16];
  #pragma unroll
  for (int nt = 0; nt < 16; ++nt){
    int n = nt*16 + lm;
    bb[nt] = bias[n]; gg[nt] = gamma[n]; be[nt] = beta[n];
  }
  #pragma unroll
  for (int r = 0; r < 4; ++r){
    const int tt = tok0 + lk*4 + r;
    const float* ur = u + (size_t)tt * 256;
    float xv[16];
    float s = 0.f, s2 = 0.f;
    #pragma unroll
    for (int nt = 0; nt < 16; ++nt){
      float x = acc[nt][r] + bb[nt] + ur[nt*16 + lm];
      xv[nt] = x; s += x; s2 = fmaf(x, x, s2);
    }
    #pragma unroll
    for (int off = 1; off < 16; off <<= 1){
      s  += __shfl_xor(s,  off, 16);
      s2 += __shfl_xor(s2, off, 16);
    }
    float mu = s * (1.0f/256.0f);
    float rs = rsqrtf(s2 * (1.0f/256.0f) - mu*mu + 1e-5f);
    float* orow = out + (size_t)tt * 256;
    #pragma unroll
    for (int nt = 0; nt < 16; ++nt)
      orow[nt*16 + lm] = (xv[nt] - mu) * rs * gg[nt] + be[nt];
  }
}

// ---------------------------------------------------------------------------
extern "C" void kernel_launch(void* const* d_in, const int* in_sizes, int n_in,
                              void* d_out, int out_size, void* d_ws, size_t ws_size,
                              hipStream_t stream){
  (void)in_sizes; (void)n_in; (void)out_size; (void)ws_size;
  const float* u        = (const float*)d_in[0];
  const float* B_ri     = (const float*)d_in[1];
  const float* Ct_ri    = (const float*)d_in[2];
  const float* lam_ri   = (const float*)d_in[3];
  const float* p_ri     = (const float*)d_in[4];
  const float* q_ri     = (const float*)d_in[5];
  const float* log_step = (const float*)d_in[6];
  const float* D_skip   = (const float*)d_in[7];
  const float* W        = (const float*)d_in[8];
  const float* bias     = (const float*)d_in[9];
  const float* gamma    = (const float*)d_in[10];
  const float* beta     = (const float*)d_in[11];
  float* out = (float*)d_out;

  // Workspace: KdE 4,196,352 | KdO 4,194,304 | Wb 131,072 | ut 33,554,432
  char* ws = (char*)d_ws;
  float* KdE = (float*)(ws);
  float* KdO = (float*)(ws + 4196352);
  short* Wb  = (short*)(ws + 4196352 + 4194304);
  float* ut  = (float*)(ws + 4196352 + 4194304 + 131072);

  convert_w   <<<64,              256, 0, stream>>>(W, Wb);
  cauchy_ar   <<<2048,            256, 0, stream>>>(B_ri, Ct_ri, lam_ri, p_ri, q_ri, log_step, KdE);
  fft_kd      <<<256,             256, 0, stream>>>(KdE, KdO);
  transpose_u <<<dim3(128, 8, 8), 256, 0, stream>>>(u, ut);
  s4_conv     <<<2048,            256, 0, stream>>>(ut, KdE, KdO);
  mfma_gemm_ln<<<512,             256, 0, stream>>>(ut, Wb, D_skip, bias, u, gamma, beta, out);
}

// Round 5
// 154.815 us; speedup vs baseline: 2.3546x; 1.0278x over previous
//
#include <hip/hip_runtime.h>
#include <math.h>

// S4 block: Cauchy (Hermitian-half) + even-bin identity + register four-step
// FFTs (16x16x16) + LDS-staged fused GELU+MFMA Linear + residual + LayerNorm.
// B=8, L=4096, D=256, N=64.

typedef float2 cf;
typedef __attribute__((ext_vector_type(8))) short bf16x8;
typedef __attribute__((ext_vector_type(4))) float f32x4;

__device__ __forceinline__ cf cmul(cf a, cf b){
  return make_float2(fmaf(a.x, b.x, -a.y*b.y), fmaf(a.x, b.y, a.y*b.x));
}
__device__ __forceinline__ cf cadd(cf a, cf b){ return make_float2(a.x+b.x, a.y+b.y); }
__device__ __forceinline__ cf csub(cf a, cf b){ return make_float2(a.x-b.x, a.y-b.y); }
__device__ __forceinline__ cf cscale(cf a, float s){ return make_float2(a.x*s, a.y*s); }
__device__ __forceinline__ cf cconj(cf a){ return make_float2(a.x, -a.y); }

__device__ __forceinline__ short f2bf(float x){   // RNE float->bf16
  union { float f; unsigned u; } v; v.f = x;
  unsigned r = v.u + 0x7fffu + ((v.u >> 16) & 1u);
  return (short)(r >> 16);
}

// LDS swizzle for FFT buffer: XOR bits[7:4] into bits[3:0].
__device__ __forceinline__ int SW(int i){ return i ^ ((i >> 4) & 15); }
// After fft16, output V[k] sits in v[RI(k)].
__device__ __forceinline__ constexpr int RI(int k){ return ((k & 3) << 2) | (k >> 2); }

#define C8 0.92387953251f
#define S8 0.38268343236f
#define RH 0.70710678119f

__device__ __forceinline__ void r4(cf& a, cf& b, cf& c, cf& d, float dir){
  cf T0 = cadd(a, c), T1 = csub(a, c);
  cf T2 = cadd(b, d), Bd = csub(b, d);
  cf T3 = make_float2(-dir*Bd.y, dir*Bd.x);     // J*(b-d), J = dir*i
  a = cadd(T0, T2); b = cadd(T1, T3); c = csub(T0, T2); d = csub(T1, T3);
}

__device__ __forceinline__ void fft16(cf* v, float dir){
  r4(v[0], v[4], v[8],  v[12], dir);
  r4(v[1], v[5], v[9],  v[13], dir);
  r4(v[2], v[6], v[10], v[14], dir);
  r4(v[3], v[7], v[11], v[15], dir);
  cf w1 = make_float2(C8,  dir*S8);
  cf w2 = make_float2(RH,  dir*RH);
  cf w3 = make_float2(S8,  dir*C8);
  cf w4 = make_float2(0.f, dir);
  cf w6 = make_float2(-RH, dir*RH);
  cf w9 = make_float2(-C8, -dir*S8);
  v[5]  = cmul(v[5],  w1); v[6]  = cmul(v[6],  w2); v[7]  = cmul(v[7],  w3);
  v[9]  = cmul(v[9],  w2); v[10] = cmul(v[10], w4); v[11] = cmul(v[11], w6);
  v[13] = cmul(v[13], w3); v[14] = cmul(v[14], w6); v[15] = cmul(v[15], w9);
  r4(v[0],  v[1],  v[2],  v[3],  dir);
  r4(v[4],  v[5],  v[6],  v[7],  dir);
  r4(v[8],  v[9],  v[10], v[11], dir);
  r4(v[12], v[13], v[14], v[15], dir);
}

// 4096-pt FFT, four-step 16x(16x16), one shared cf[4096] buffer (SW-indexed).
// Entry: v[n1] = x[n1*256 + t].  Exit: V[k1+16*ka+256*kb] = v[RI(kb)],
// k1 = t>>4, ka = t&15.  Starts with a barrier.
__device__ void fft4096_reg(cf* v, cf* lds, float dir){
  const int t = threadIdx.x;
  fft16(v, dir);
  float sn, cs;
  __sincosf(dir * 1.5339807878856412e-3f * (float)t, &sn, &cs);   // 2pi/4096
  cf w = make_float2(cs, sn), cw = w;
  __syncthreads();
  lds[SW(t)] = v[0];
  #pragma unroll
  for (int k1 = 1; k1 < 16; ++k1){
    lds[SW(k1*256 + t)] = cmul(v[RI(k1)], cw);
    cw = cmul(cw, w);
  }
  __syncthreads();
  const int k1 = t >> 4, m2 = t & 15;
  #pragma unroll
  for (int m1 = 0; m1 < 16; ++m1) v[m1] = lds[SW(k1*256 + m1*16 + m2)];
  fft16(v, dir);
  __sincosf(dir * 2.45436926061703e-2f * (float)m2, &sn, &cs);    // 2pi/256
  w = make_float2(cs, sn); cw = w;
  __syncthreads();
  lds[SW(k1*256 + m2)] = v[0];
  #pragma unroll
  for (int ka = 1; ka < 16; ++ka){
    lds[SW(k1*256 + ka*16 + m2)] = cmul(v[RI(ka)], cw);
    cw = cmul(cw, w);
  }
  __syncthreads();
  const int ka = t & 15;
  #pragma unroll
  for (int m2b = 0; m2b < 16; ++m2b) v[m2b] = lds[SW(k1*256 + ka*16 + m2b)];
  fft16(v, dir);
}

// ---------------------------------------------------------------------------
// Kernel 1a: Cauchy generating function, Hermitian half (l = 0..2048).
// Even-bin identity: rfft(K,8192)[2m] = ar[m] -> KdE[d][m], m = 0..2048.
__global__ __launch_bounds__(256)
void cauchy_ar(const float* __restrict__ B_ri, const float* __restrict__ Ct_ri,
               const float* __restrict__ lam_ri, const float* __restrict__ p_ri,
               const float* __restrict__ q_ri, const float* __restrict__ log_step,
               float* __restrict__ KdE){
  __shared__ cf w00[64], w01[64], w10[64], w11[64], lamS[64];
  const int d     = blockIdx.x >> 3;
  const int chunk = blockIdx.x & 7;
  const int tid   = threadIdx.x;
  const float step = expf(log_step[d]);

  if (tid < 64){
    int n = tid;
    cf Bv = make_float2(B_ri[(d*64+n)*2],  B_ri[(d*64+n)*2+1]);
    cf Cv = make_float2(Ct_ri[(d*64+n)*2], Ct_ri[(d*64+n)*2+1]);
    cf pv = make_float2(p_ri[n*2], p_ri[n*2+1]);
    cf qv = make_float2(q_ri[n*2], q_ri[n*2+1]);
    lamS[n] = make_float2(lam_ri[n*2], lam_ri[n*2+1]);
    cf Cc = cconj(Cv), qc = cconj(qv);
    w00[n] = cmul(Cc, Bv);
    w01[n] = cmul(Cc, pv);
    w10[n] = cmul(qc, Bv);
    w11[n] = cmul(qc, pv);
  }
  __syncthreads();

  cf* out = (cf*)KdE + (size_t)d * 2049;
  const int l = chunk * 256 + tid;               // 0..2047
  {
    float th = -(6.28318530717958647692f * (float)l) * (1.0f/4096.0f);
    float sn = sinf(th), cs = cosf(th);          // accurate sin/cos
    cf opw = make_float2(1.0f + cs,  sn);        // 1 + omega
    cf omw = make_float2(1.0f - cs, -sn);        // 1 - omega
    float idn = 1.0f / fmaf(opw.x, opw.x, opw.y*opw.y);
    cf ratio = make_float2((omw.x*opw.x + omw.y*opw.y)*idn,
                           (omw.y*opw.x - omw.x*opw.y)*idn);
    cf g  = cscale(ratio, 2.0f / step);
    cf cc = make_float2(2.0f*opw.x*idn, -2.0f*opw.y*idn);   // 2/(1+omega)
    cf k00 = {0,0}, k01 = {0,0}, k10 = {0,0}, k11 = {0,0};
    #pragma unroll 4
    for (int n = 0; n < 64; ++n){
      cf lv  = lamS[n];
      cf den = make_float2(g.x - lv.x, g.y - lv.y);
      float is = 1.0f / fmaf(den.x, den.x, den.y*den.y);
      cf r = make_float2(den.x*is, -den.y*is);               // 1/(g - lam)
      k00 = cadd(k00, cmul(w00[n], r));
      k01 = cadd(k01, cmul(w01[n], r));
      k10 = cadd(k10, cmul(w10[n], r));
      k11 = cadd(k11, cmul(w11[n], r));
    }
    cf onep = make_float2(1.0f + k11.x, k11.y);
    float ii = 1.0f / fmaf(onep.x, onep.x, onep.y*onep.y);
    cf inv1p = make_float2(onep.x*ii, -onep.y*ii);
    cf corr = cmul(k01, cmul(k10, inv1p));
    out[l] = cmul(cc, csub(k00, corr));
  }
  if (chunk == 7 && tid == 255){
    cf s00 = make_float2(0.f, 0.f);
    for (int n = 0; n < 64; ++n) s00 = cadd(s00, w00[n]);
    out[2048] = cscale(s00, 0.5f * step);
  }
}

// ---------------------------------------------------------------------------
// Kernel 1b: odd bins. KdO[d][m] = FFT4096( Re(K[n]) e^{-i pi n/4096} )[m].
__global__ __launch_bounds__(256)
void fft_kd(const float* __restrict__ KdE, float* __restrict__ KdO){
  __shared__ cf L[4096];
  const int d = blockIdx.x, t = threadIdx.x;
  const cf* kdE = (const cf*)KdE + (size_t)d * 2049;
  cf* kdO = (cf*)KdO + (size_t)d * 2048;
  cf v[16];
  const float inv = 1.0f / 4096.0f;
  #pragma unroll
  for (int n1 = 0; n1 < 16; ++n1){
    int m = n1*256 + t;
    cf a = (m <= 2048) ? kdE[m] : cconj(kdE[4096 - m]);
    v[n1] = cscale(a, inv);
  }
  fft4096_reg(v, L, +1.0f);            // K (real part)
  const int k1 = t >> 4, ka = t & 15;
  __syncthreads();
  #pragma unroll
  for (int kb = 0; kb < 16; ++kb){
    int g = k1 + 16*ka + 256*kb;
    float kr = v[RI(kb)].x;
    float sn, cs; __sincosf(-7.669903939428206e-4f * (float)g, &sn, &cs);
    L[SW(g)] = make_float2(kr*cs, kr*sn);
  }
  __syncthreads();
  #pragma unroll
  for (int n1 = 0; n1 < 16; ++n1) v[n1] = L[SW(n1*256 + t)];
  fft4096_reg(v, L, -1.0f);
  #pragma unroll
  for (int kb = 0; kb < 8; ++kb)
    kdO[k1 + 16*ka + 256*kb] = v[RI(kb)];
}

// ---------------------------------------------------------------------------
// Kernel 2: tiled transpose u[B][L][D] -> ut[(b*256+d)][L]
__global__ __launch_bounds__(256)
void transpose_u(const float* __restrict__ u, float* __restrict__ ut){
  __shared__ float tile[32][33];
  const int b  = blockIdx.z;
  const int l0 = blockIdx.x * 32;
  const int d0 = blockIdx.y * 32;
  const int tx = threadIdx.x & 31;
  const int ty = threadIdx.x >> 5;
  const float* ub = u + (size_t)b * 4096 * 256;
  #pragma unroll
  for (int it = 0; it < 4; ++it){
    int l = l0 + ty + it*8;
    tile[tx][ty + it*8] = ub[(size_t)l*256 + d0 + tx];
  }
  __syncthreads();
  float* utb = ut + (size_t)b * 256 * 4096;
  #pragma unroll
  for (int it = 0; it < 4; ++it){
    int dd = d0 + ty + it*8;
    utb[(size_t)dd*4096 + l0 + tx] = tile[ty + it*8][tx];
  }
}

// ---------------------------------------------------------------------------
// Kernel 3: per-(b,d) non-circular conv via packed real-FFT, in place on ut.
__global__ __launch_bounds__(256)
void s4_conv(float* __restrict__ ut, const float* __restrict__ KdE,
             const float* __restrict__ KdO){
  __shared__ cf L[4096];
  const int row = blockIdx.x;           // b*256 + d
  const int d   = row & 255;
  const int t   = threadIdx.x;
  float2* rp = (float2*)(ut + (size_t)row * 4096);

  cf v[16];
  #pragma unroll
  for (int n1 = 0; n1 < 8; ++n1) v[n1] = rp[n1*256 + t];
  #pragma unroll
  for (int n1 = 8; n1 < 16; ++n1) v[n1] = make_float2(0.f, 0.f);

  fft4096_reg(v, L, -1.0f);             // Z
  const int k1 = t >> 4, ka = t & 15;
  __syncthreads();
  #pragma unroll
  for (int kb = 0; kb < 16; ++kb)
    L[SW(k1 + 16*ka + 256*kb)] = v[RI(kb)];
  __syncthreads();

  const cf* kdE = (const cf*)KdE + (size_t)d * 2049;
  const cf* kdO = (const cf*)KdO + (size_t)d * 2048;
  #pragma unroll
  for (int m = 0; m < 8; ++m){
    int k = t + m*256;                  // 0..2047
    if (k == 0){
      cf z0 = L[SW(0)];
      float U0 = z0.x + z0.y, UN = z0.x - z0.y;
      cf P0 = cscale(kdE[0], U0);
      cf PN = cscale(kdE[2048], UN);
      cf cPN = cconj(PN);
      cf Ep = cscale(cadd(P0, cPN), 0.5f);
      cf Op = cscale(csub(P0, cPN), 0.5f);
      L[SW(0)] = make_float2(Ep.x - Op.y, Ep.y + Op.x);
      cf P = cmul(cconj(L[SW(2048)]), kdE[1024]);
      L[SW(2048)] = cconj(P);
    } else {
      cf zk = L[SW(k)], zj = L[SW(4096 - k)];
      cf E = make_float2(0.5f*(zk.x + zj.x),  0.5f*(zk.y - zj.y));
      cf O = make_float2(0.5f*(zk.y + zj.y), -0.5f*(zk.x - zj.x));
      float phi = 7.669903939428206e-4f * (float)k;     // pi*k/4096
      float sn, cs; __sincosf(phi, &sn, &cs);
      cf tw = make_float2(cs, -sn);
      cf tO = cmul(tw, O);
      cf Uk = cadd(E, tO);
      cf Uj = cconj(csub(E, tO));                        // U[4096-k]
      int h = k >> 1;
      cf kk, kj;
      if (k & 1){ kk = kdO[h]; kj = kdO[2047 - h]; }
      else      { kk = kdE[h]; kj = kdE[2048 - h]; }
      cf Pk = cmul(Uk, kk);
      cf Pj = cmul(Uj, kj);
      cf cPj = cconj(Pj), cPk = cconj(Pk);
      cf tp  = make_float2(cs, sn);
      cf Ek = cscale(cadd(Pk, cPj), 0.5f);
      cf Ok = cmul(tp, cscale(csub(Pk, cPj), 0.5f));
      L[SW(k)] = make_float2(Ek.x - Ok.y, Ek.y + Ok.x);
      cf tpj = make_float2(-cs, sn);
      cf Ej = cscale(cadd(Pj, cPk), 0.5f);
      cf Oj = cmul(tpj, cscale(csub(Pj, cPk), 0.5f));
      L[SW(4096 - k)] = make_float2(Ej.x - Oj.y, Ej.y + Oj.x);
    }
  }
  __syncthreads();

  #pragma unroll
  for (int n1 = 0; n1 < 16; ++n1) v[n1] = L[SW(n1*256 + t)];
  fft4096_reg(v, L, +1.0f);
  const float inv = 1.0f / 4096.0f;
  #pragma unroll
  for (int kb = 0; kb < 8; ++kb)
    rp[k1 + 16*ka + 256*kb] = cscale(v[RI(kb)], inv);
}

// ---------------------------------------------------------------------------
// Kernel 0: W[f][k] f32 -> Wb[f][k] bf16 (already the MFMA B-operand layout).
__global__ __launch_bounds__(256)
void convert_w(const float* __restrict__ W, short* __restrict__ Wb){
  int i = (blockIdx.x * 256 + threadIdx.x) * 4;
  float4 w = *(const float4*)(W + i);
  short4 o;
  o.x = f2bf(w.x); o.y = f2bf(w.y); o.z = f2bf(w.z); o.w = f2bf(w.w);
  *(short4*)(Wb + i) = o;
}

// ---------------------------------------------------------------------------
// Kernel 5: fused  Z = gelu(conv + D_skip*u) -> X = Z@W^T + b + u -> LN.
// LDS-staged: ut chunks loaded coalesced into St[d][l] (stride-69 rows ->
// conflict-free column reads), gelu'd into bf16 A-tile At[tok][k] (stride-264
// rows -> 2-way-free ds_read_b128 for MFMA A-fragments).  Writes d_out only.
__device__ __forceinline__ float gelu_exact(float x){
  return 0.5f * x * (1.0f + erff(x * 0.70710678118654752f));
}

__global__ __launch_bounds__(256)
void mfma_gemm_ln(const float* __restrict__ ut, const short* __restrict__ Wb,
                  const float* __restrict__ Dsk, const float* __restrict__ bias,
                  const float* __restrict__ u, const float* __restrict__ gamma,
                  const float* __restrict__ beta, float* __restrict__ out){
  __shared__ short At[64][264];       // bf16 A-tile [token-local][k]
  __shared__ float St[64][69];        // stage [d-local][l-local]
  const int w    = threadIdx.x >> 6;
  const int l    = threadIdx.x & 63;
  const int lm   = l & 15;            // A-row / B-col / D-col
  const int lk   = l >> 4;            // k-group / quarter-wave
  const int tokB = blockIdx.x * 64;   // 64 tokens/block (never straddles batch)
  const int b    = tokB >> 12;
  const int l0   = tokB & 4095;

  const float* utb = ut + (size_t)(b * 256) * 4096 + l0;
  const float* ub  = u  + (size_t)tokB * 256;

  #pragma unroll
  for (int c = 0; c < 4; ++c){        // k-chunks of 64
    __syncthreads();                  // St reusable (prev chunk's reads done)
    // phase 1: stage conv [64 d][64 l], coalesced along l
    #pragma unroll
    for (int it = 0; it < 4; ++it){
      int rl = w*16 + it*4 + lk;      // d-local 0..63
      const float4 a = *(const float4*)(utb + (size_t)(c*64 + rl)*4096 + lm*4);
      St[rl][lm*4 + 0] = a.x; St[rl][lm*4 + 1] = a.y;
      St[rl][lm*4 + 2] = a.z; St[rl][lm*4 + 3] = a.w;
    }
    __syncthreads();
    // phase 2: transpose-read + skip + gelu -> bf16 A-tile
    const float4 dk = *(const float4*)(Dsk + c*64 + lm*4);
    #pragma unroll
    for (int p = 0; p < 4; ++p){
      int tl = p*16 + w*4 + lk;       // token-local 0..63
      const float4 uv = *(const float4*)(ub + (size_t)tl*256 + c*64 + lm*4);
      short4 o;
      o.x = f2bf(gelu_exact(fmaf(dk.x, uv.x, St[lm*4 + 0][tl])));
      o.y = f2bf(gelu_exact(fmaf(dk.y, uv.y, St[lm*4 + 1][tl])));
      o.z = f2bf(gelu_exact(fmaf(dk.z, uv.z, St[lm*4 + 2][tl])));
      o.w = f2bf(gelu_exact(fmaf(dk.w, uv.w, St[lm*4 + 3][tl])));
      *(short4*)&At[tl][c*64 + lm*4] = o;
    }
  }
  __syncthreads();

  f32x4 acc[16];
  #pragma unroll
  for (int nt = 0; nt < 16; ++nt) acc[nt] = (f32x4){0.f, 0.f, 0.f, 0.f};

  #pragma unroll
  for (int ks = 0; ks < 8; ++ks){
    const bf16x8 af = *(const bf16x8*)&At[w*16 + lm][ks*32 + lk*8];
    #pragma unroll
    for (int nt = 0; nt < 16; ++nt){
      const bf16x8* bp = (const bf16x8*)(Wb + (size_t)(nt*16 + lm)*256 + ks*32 + lk*8);
      acc[nt] = __builtin_amdgcn_mfma_f32_16x16x32_bf16(af, *bp, acc[nt], 0, 0, 0);
    }
  }

  // epilogue: + bias + u residual, LayerNorm across 256 features
  const int tok0 = tokB + w * 16;
  float bb[16], gg[16], be[16];
  #pragma unroll
  for (int nt = 0; nt < 16; ++nt){
    int n = nt*16 + lm;
    bb[nt] = bias[n]; gg[nt] = gamma[n]; be[nt] = beta[n];
  }
  #pragma unroll
  for (int r = 0; r < 4; ++r){
    const int tt = tok0 + lk*4 + r;
    const float* ur = u + (size_t)tt * 256;
    float xv[16];
    float s = 0.f, s2 = 0.f;
    #pragma unroll
    for (int nt = 0; nt < 16; ++nt){
      float x = acc[nt][r] + bb[nt] + ur[nt*16 + lm];
      xv[nt] = x; s += x; s2 = fmaf(x, x, s2);
    }
    #pragma unroll
    for (int off = 1; off < 16; off <<= 1){
      s  += __shfl_xor(s,  off, 16);
      s2 += __shfl_xor(s2, off, 16);
    }
    float mu = s * (1.0f/256.0f);
    float rs = rsqrtf(s2 * (1.0f/256.0f) - mu*mu + 1e-5f);
    float* orow = out + (size_t)tt * 256;
    #pragma unroll
    for (int nt = 0; nt < 16; ++nt)
      orow[nt*16 + lm] = (xv[nt] - mu) * rs * gg[nt] + be[nt];
  }
}

// ---------------------------------------------------------------------------
extern "C" void kernel_launch(void* const* d_in, const int* in_sizes, int n_in,
                              void* d_out, int out_size, void* d_ws, size_t ws_size,
                              hipStream_t stream){
  (void)in_sizes; (void)n_in; (void)out_size; (void)ws_size;
  const float* u        = (const float*)d_in[0];
  const float* B_ri     = (const float*)d_in[1];
  const float* Ct_ri    = (const float*)d_in[2];
  const float* lam_ri   = (const float*)d_in[3];
  const float* p_ri     = (const float*)d_in[4];
  const float* q_ri     = (const float*)d_in[5];
  const float* log_step = (const float*)d_in[6];
  const float* D_skip   = (const float*)d_in[7];
  const float* W        = (const float*)d_in[8];
  const float* bias     = (const float*)d_in[9];
  const float* gamma    = (const float*)d_in[10];
  const float* beta     = (const float*)d_in[11];
  float* out = (float*)d_out;

  // Workspace: KdE 4,196,352 | KdO 4,194,304 | Wb 131,072 | ut 33,554,432
  char* ws = (char*)d_ws;
  float* KdE = (float*)(ws);
  float* KdO = (float*)(ws + 4196352);
  short* Wb  = (short*)(ws + 4196352 + 4194304);
  float* ut  = (float*)(ws + 4196352 + 4194304 + 131072);

  convert_w   <<<64,              256, 0, stream>>>(W, Wb);
  cauchy_ar   <<<2048,            256, 0, stream>>>(B_ri, Ct_ri, lam_ri, p_ri, q_ri, log_step, KdE);
  fft_kd      <<<256,             256, 0, stream>>>(KdE, KdO);
  transpose_u <<<dim3(128, 8, 8), 256, 0, stream>>>(u, ut);
  s4_conv     <<<2048,            256, 0, stream>>>(ut, KdE, KdO);
  mfma_gemm_ln<<<512,             256, 0, stream>>>(ut, Wb, D_skip, bias, u, gamma, beta, out);
}

// Round 6
// 153.234 us; speedup vs baseline: 2.3789x; 1.0103x over previous
//
#include <hip/hip_runtime.h>
#include <math.h>

// S4 block: Cauchy (Hermitian-half) + even-bin identity + register four-step
// FFTs (16x16x16) + LDS-staged fused GELU+MFMA Linear + residual + LayerNorm.
// B=8, L=4096, D=256, N=64.

typedef float2 cf;
typedef __attribute__((ext_vector_type(8))) short bf16x8;
typedef __attribute__((ext_vector_type(4))) float f32x4;

__device__ __forceinline__ cf cmul(cf a, cf b){
  return make_float2(fmaf(a.x, b.x, -a.y*b.y), fmaf(a.x, b.y, a.y*b.x));
}
__device__ __forceinline__ cf cadd(cf a, cf b){ return make_float2(a.x+b.x, a.y+b.y); }
__device__ __forceinline__ cf csub(cf a, cf b){ return make_float2(a.x-b.x, a.y-b.y); }
__device__ __forceinline__ cf cscale(cf a, float s){ return make_float2(a.x*s, a.y*s); }
__device__ __forceinline__ cf cconj(cf a){ return make_float2(a.x, -a.y); }

__device__ __forceinline__ short f2bf(float x){   // RNE float->bf16
  union { float f; unsigned u; } v; v.f = x;
  unsigned r = v.u + 0x7fffu + ((v.u >> 16) & 1u);
  return (short)(r >> 16);
}

// LDS swizzle for FFT buffer: XOR bits[7:4] into bits[3:0].
__device__ __forceinline__ int SW(int i){ return i ^ ((i >> 4) & 15); }
// After fft16, output V[k] sits in v[RI(k)].
__device__ __forceinline__ constexpr int RI(int k){ return ((k & 3) << 2) | (k >> 2); }

#define C8 0.92387953251f
#define S8 0.38268343236f
#define RH 0.70710678119f

__device__ __forceinline__ void r4(cf& a, cf& b, cf& c, cf& d, float dir){
  cf T0 = cadd(a, c), T1 = csub(a, c);
  cf T2 = cadd(b, d), Bd = csub(b, d);
  cf T3 = make_float2(-dir*Bd.y, dir*Bd.x);     // J*(b-d), J = dir*i
  a = cadd(T0, T2); b = cadd(T1, T3); c = csub(T0, T2); d = csub(T1, T3);
}

__device__ __forceinline__ void fft16(cf* v, float dir){
  r4(v[0], v[4], v[8],  v[12], dir);
  r4(v[1], v[5], v[9],  v[13], dir);
  r4(v[2], v[6], v[10], v[14], dir);
  r4(v[3], v[7], v[11], v[15], dir);
  cf w1 = make_float2(C8,  dir*S8);
  cf w2 = make_float2(RH,  dir*RH);
  cf w3 = make_float2(S8,  dir*C8);
  cf w4 = make_float2(0.f, dir);
  cf w6 = make_float2(-RH, dir*RH);
  cf w9 = make_float2(-C8, -dir*S8);
  v[5]  = cmul(v[5],  w1); v[6]  = cmul(v[6],  w2); v[7]  = cmul(v[7],  w3);
  v[9]  = cmul(v[9],  w2); v[10] = cmul(v[10], w4); v[11] = cmul(v[11], w6);
  v[13] = cmul(v[13], w3); v[14] = cmul(v[14], w6); v[15] = cmul(v[15], w9);
  r4(v[0],  v[1],  v[2],  v[3],  dir);
  r4(v[4],  v[5],  v[6],  v[7],  dir);
  r4(v[8],  v[9],  v[10], v[11], dir);
  r4(v[12], v[13], v[14], v[15], dir);
}

// 4096-pt FFT, four-step 16x(16x16), one shared cf[4096] buffer (SW-indexed).
// Entry: v[n1] = x[n1*256 + t].  Exit: V[k1+16*ka+256*kb] = v[RI(kb)],
// k1 = t>>4, ka = t&15.  Starts with a barrier.
__device__ void fft4096_reg(cf* v, cf* lds, float dir){
  const int t = threadIdx.x;
  fft16(v, dir);
  float sn, cs;
  __sincosf(dir * 1.5339807878856412e-3f * (float)t, &sn, &cs);   // 2pi/4096
  cf w = make_float2(cs, sn), cw = w;
  __syncthreads();
  lds[SW(t)] = v[0];
  #pragma unroll
  for (int k1 = 1; k1 < 16; ++k1){
    lds[SW(k1*256 + t)] = cmul(v[RI(k1)], cw);
    cw = cmul(cw, w);
  }
  __syncthreads();
  const int k1 = t >> 4, m2 = t & 15;
  #pragma unroll
  for (int m1 = 0; m1 < 16; ++m1) v[m1] = lds[SW(k1*256 + m1*16 + m2)];
  fft16(v, dir);
  __sincosf(dir * 2.45436926061703e-2f * (float)m2, &sn, &cs);    // 2pi/256
  w = make_float2(cs, sn); cw = w;
  __syncthreads();
  lds[SW(k1*256 + m2)] = v[0];
  #pragma unroll
  for (int ka = 1; ka < 16; ++ka){
    lds[SW(k1*256 + ka*16 + m2)] = cmul(v[RI(ka)], cw);
    cw = cmul(cw, w);
  }
  __syncthreads();
  const int ka = t & 15;
  #pragma unroll
  for (int m2b = 0; m2b < 16; ++m2b) v[m2b] = lds[SW(k1*256 + ka*16 + m2b)];
  fft16(v, dir);
}

// ---------------------------------------------------------------------------
// Kernel 1a: Cauchy generating function, Hermitian half (l = 0..2048).
// Even-bin identity: rfft(K,8192)[2m] = ar[m] -> KdE[d][m], m = 0..2048.
__global__ __launch_bounds__(256)
void cauchy_ar(const float* __restrict__ B_ri, const float* __restrict__ Ct_ri,
               const float* __restrict__ lam_ri, const float* __restrict__ p_ri,
               const float* __restrict__ q_ri, const float* __restrict__ log_step,
               float* __restrict__ KdE){
  __shared__ cf w00[64], w01[64], w10[64], w11[64], lamS[64];
  const int d     = blockIdx.x >> 3;
  const int chunk = blockIdx.x & 7;
  const int tid   = threadIdx.x;
  const float step = expf(log_step[d]);

  if (tid < 64){
    int n = tid;
    cf Bv = make_float2(B_ri[(d*64+n)*2],  B_ri[(d*64+n)*2+1]);
    cf Cv = make_float2(Ct_ri[(d*64+n)*2], Ct_ri[(d*64+n)*2+1]);
    cf pv = make_float2(p_ri[n*2], p_ri[n*2+1]);
    cf qv = make_float2(q_ri[n*2], q_ri[n*2+1]);
    lamS[n] = make_float2(lam_ri[n*2], lam_ri[n*2+1]);
    cf Cc = cconj(Cv), qc = cconj(qv);
    w00[n] = cmul(Cc, Bv);
    w01[n] = cmul(Cc, pv);
    w10[n] = cmul(qc, Bv);
    w11[n] = cmul(qc, pv);
  }
  __syncthreads();

  cf* out = (cf*)KdE + (size_t)d * 2049;
  const int l = chunk * 256 + tid;               // 0..2047
  {
    float th = -(6.28318530717958647692f * (float)l) * (1.0f/4096.0f);
    float sn = sinf(th), cs = cosf(th);          // accurate sin/cos
    cf opw = make_float2(1.0f + cs,  sn);        // 1 + omega
    cf omw = make_float2(1.0f - cs, -sn);        // 1 - omega
    float idn = 1.0f / fmaf(opw.x, opw.x, opw.y*opw.y);
    cf ratio = make_float2((omw.x*opw.x + omw.y*opw.y)*idn,
                           (omw.y*opw.x - omw.x*opw.y)*idn);
    cf g  = cscale(ratio, 2.0f / step);
    cf cc = make_float2(2.0f*opw.x*idn, -2.0f*opw.y*idn);   // 2/(1+omega)
    cf k00 = {0,0}, k01 = {0,0}, k10 = {0,0}, k11 = {0,0};
    #pragma unroll 4
    for (int n = 0; n < 64; ++n){
      cf lv  = lamS[n];
      cf den = make_float2(g.x - lv.x, g.y - lv.y);
      float is = 1.0f / fmaf(den.x, den.x, den.y*den.y);
      cf r = make_float2(den.x*is, -den.y*is);               // 1/(g - lam)
      k00 = cadd(k00, cmul(w00[n], r));
      k01 = cadd(k01, cmul(w01[n], r));
      k10 = cadd(k10, cmul(w10[n], r));
      k11 = cadd(k11, cmul(w11[n], r));
    }
    cf onep = make_float2(1.0f + k11.x, k11.y);
    float ii = 1.0f / fmaf(onep.x, onep.x, onep.y*onep.y);
    cf inv1p = make_float2(onep.x*ii, -onep.y*ii);
    cf corr = cmul(k01, cmul(k10, inv1p));
    out[l] = cmul(cc, csub(k00, corr));
  }
  if (chunk == 7 && tid == 255){
    cf s00 = make_float2(0.f, 0.f);
    for (int n = 0; n < 64; ++n) s00 = cadd(s00, w00[n]);
    out[2048] = cscale(s00, 0.5f * step);
  }
}

// ---------------------------------------------------------------------------
// Kernel 1b: odd bins. KdO[d][m] = FFT4096( Re(K[n]) e^{-i pi n/4096} )[m].
__global__ __launch_bounds__(256)
void fft_kd(const float* __restrict__ KdE, float* __restrict__ KdO){
  __shared__ cf L[4096];
  const int d = blockIdx.x, t = threadIdx.x;
  const cf* kdE = (const cf*)KdE + (size_t)d * 2049;
  cf* kdO = (cf*)KdO + (size_t)d * 2048;
  cf v[16];
  const float inv = 1.0f / 4096.0f;
  #pragma unroll
  for (int n1 = 0; n1 < 16; ++n1){
    int m = n1*256 + t;
    cf a = (m <= 2048) ? kdE[m] : cconj(kdE[4096 - m]);
    v[n1] = cscale(a, inv);
  }
  fft4096_reg(v, L, +1.0f);            // K (real part)
  const int k1 = t >> 4, ka = t & 15;
  __syncthreads();
  #pragma unroll
  for (int kb = 0; kb < 16; ++kb){
    int g = k1 + 16*ka + 256*kb;
    float kr = v[RI(kb)].x;
    float sn, cs; __sincosf(-7.669903939428206e-4f * (float)g, &sn, &cs);
    L[SW(g)] = make_float2(kr*cs, kr*sn);
  }
  __syncthreads();
  #pragma unroll
  for (int n1 = 0; n1 < 16; ++n1) v[n1] = L[SW(n1*256 + t)];
  fft4096_reg(v, L, -1.0f);
  #pragma unroll
  for (int kb = 0; kb < 8; ++kb)
    kdO[k1 + 16*ka + 256*kb] = v[RI(kb)];
}

// ---------------------------------------------------------------------------
// Kernel 2: tiled transpose u[B][L][D] -> ut[(b*256+d)][L]
__global__ __launch_bounds__(256)
void transpose_u(const float* __restrict__ u, float* __restrict__ ut){
  __shared__ float tile[32][33];
  const int b  = blockIdx.z;
  const int l0 = blockIdx.x * 32;
  const int d0 = blockIdx.y * 32;
  const int tx = threadIdx.x & 31;
  const int ty = threadIdx.x >> 5;
  const float* ub = u + (size_t)b * 4096 * 256;
  #pragma unroll
  for (int it = 0; it < 4; ++it){
    int l = l0 + ty + it*8;
    tile[tx][ty + it*8] = ub[(size_t)l*256 + d0 + tx];
  }
  __syncthreads();
  float* utb = ut + (size_t)b * 256 * 4096;
  #pragma unroll
  for (int it = 0; it < 4; ++it){
    int dd = d0 + ty + it*8;
    utb[(size_t)dd*4096 + l0 + tx] = tile[ty + it*8][tx];
  }
}

// ---------------------------------------------------------------------------
// Kernel 3: per-(b,d) non-circular conv via packed real-FFT, in place on ut.
__global__ __launch_bounds__(256)
void s4_conv(float* __restrict__ ut, const float* __restrict__ KdE,
             const float* __restrict__ KdO){
  __shared__ cf L[4096];
  const int row = blockIdx.x;           // b*256 + d
  const int d   = row & 255;
  const int t   = threadIdx.x;
  float2* rp = (float2*)(ut + (size_t)row * 4096);

  cf v[16];
  #pragma unroll
  for (int n1 = 0; n1 < 8; ++n1) v[n1] = rp[n1*256 + t];
  #pragma unroll
  for (int n1 = 8; n1 < 16; ++n1) v[n1] = make_float2(0.f, 0.f);

  fft4096_reg(v, L, -1.0f);             // Z
  const int k1 = t >> 4, ka = t & 15;
  __syncthreads();
  #pragma unroll
  for (int kb = 0; kb < 16; ++kb)
    L[SW(k1 + 16*ka + 256*kb)] = v[RI(kb)];
  __syncthreads();

  const cf* kdE = (const cf*)KdE + (size_t)d * 2049;
  const cf* kdO = (const cf*)KdO + (size_t)d * 2048;
  #pragma unroll
  for (int m = 0; m < 8; ++m){
    int k = t + m*256;                  // 0..2047
    if (k == 0){
      cf z0 = L[SW(0)];
      float U0 = z0.x + z0.y, UN = z0.x - z0.y;
      cf P0 = cscale(kdE[0], U0);
      cf PN = cscale(kdE[2048], UN);
      cf cPN = cconj(PN);
      cf Ep = cscale(cadd(P0, cPN), 0.5f);
      cf Op = cscale(csub(P0, cPN), 0.5f);
      L[SW(0)] = make_float2(Ep.x - Op.y, Ep.y + Op.x);
      cf P = cmul(cconj(L[SW(2048)]), kdE[1024]);
      L[SW(2048)] = cconj(P);
    } else {
      cf zk = L[SW(k)], zj = L[SW(4096 - k)];
      cf E = make_float2(0.5f*(zk.x + zj.x),  0.5f*(zk.y - zj.y));
      cf O = make_float2(0.5f*(zk.y + zj.y), -0.5f*(zk.x - zj.x));
      float phi = 7.669903939428206e-4f * (float)k;     // pi*k/4096
      float sn, cs; __sincosf(phi, &sn, &cs);
      cf tw = make_float2(cs, -sn);
      cf tO = cmul(tw, O);
      cf Uk = cadd(E, tO);
      cf Uj = cconj(csub(E, tO));                        // U[4096-k]
      int h = k >> 1;
      cf kk, kj;
      if (k & 1){ kk = kdO[h]; kj = kdO[2047 - h]; }
      else      { kk = kdE[h]; kj = kdE[2048 - h]; }
      cf Pk = cmul(Uk, kk);
      cf Pj = cmul(Uj, kj);
      cf cPj = cconj(Pj), cPk = cconj(Pk);
      cf tp  = make_float2(cs, sn);
      cf Ek = cscale(cadd(Pk, cPj), 0.5f);
      cf Ok = cmul(tp, cscale(csub(Pk, cPj), 0.5f));
      L[SW(k)] = make_float2(Ek.x - Ok.y, Ek.y + Ok.x);
      cf tpj = make_float2(-cs, sn);
      cf Ej = cscale(cadd(Pj, cPk), 0.5f);
      cf Oj = cmul(tpj, cscale(csub(Pj, cPk), 0.5f));
      L[SW(4096 - k)] = make_float2(Ej.x - Oj.y, Ej.y + Oj.x);
    }
  }
  __syncthreads();

  #pragma unroll
  for (int n1 = 0; n1 < 16; ++n1) v[n1] = L[SW(n1*256 + t)];
  fft4096_reg(v, L, +1.0f);
  const float inv = 1.0f / 4096.0f;
  #pragma unroll
  for (int kb = 0; kb < 8; ++kb)
    rp[k1 + 16*ka + 256*kb] = cscale(v[RI(kb)], inv);
}

// ---------------------------------------------------------------------------
// Kernel 0: W[f][k] f32 -> Wb[f][k] bf16 (MFMA A-operand layout: row=f,
// 8 consecutive k per lane).
__global__ __launch_bounds__(256)
void convert_w(const float* __restrict__ W, short* __restrict__ Wb){
  int i = (blockIdx.x * 256 + threadIdx.x) * 4;
  float4 w = *(const float4*)(W + i);
  short4 o;
  o.x = f2bf(w.x); o.y = f2bf(w.y); o.z = f2bf(w.z); o.w = f2bf(w.w);
  *(short4*)(Wb + i) = o;
}

// ---------------------------------------------------------------------------
// Kernel 5: fused  Z = gelu(conv + D_skip*u) -> X = Z@W^T + b + u -> LN.
// MFMA with A = W (rows = features), B = Z^T (cols = tokens): D-layout gives
// each lane ONE token (col = lane&15) and per-lane-contiguous features
// (row = (lane>>4)*4 + reg) -> fully vectorized float4 epilogue + in-lane LN.
__device__ __forceinline__ float gelu_exact(float x){
  return 0.5f * x * (1.0f + erff(x * 0.70710678118654752f));
}

__global__ __launch_bounds__(256)
void mfma_gemm_ln(const float* __restrict__ ut, const short* __restrict__ Wb,
                  const float* __restrict__ Dsk, const float* __restrict__ bias,
                  const float* __restrict__ u, const float* __restrict__ gamma,
                  const float* __restrict__ beta, float* __restrict__ out){
  __shared__ short At[64][264];       // bf16 Z-tile [token-local][k]
  __shared__ float St[64][69];        // stage [k-local][token-local]
  __shared__ float prm[3][256];       // bias / gamma / beta
  const int w    = threadIdx.x >> 6;
  const int l    = threadIdx.x & 63;
  const int lm   = l & 15;
  const int lk   = l >> 4;
  const int tokB = blockIdx.x * 64;   // 64 tokens/block (never straddles batch)
  const int b    = tokB >> 12;
  const int l0   = tokB & 4095;

  prm[0][threadIdx.x] = bias[threadIdx.x];
  prm[1][threadIdx.x] = gamma[threadIdx.x];
  prm[2][threadIdx.x] = beta[threadIdx.x];

  const float* utb = ut + (size_t)(b * 256) * 4096 + l0;
  const float* ub  = u  + (size_t)tokB * 256;

  // prefetch chunk 0 of conv (coalesced along l)
  float4 pre[4];
  #pragma unroll
  for (int it = 0; it < 4; ++it){
    int rl = w*16 + it*4 + lk;
    pre[it] = *(const float4*)(utb + (size_t)rl*4096 + lm*4);
  }

  #pragma unroll
  for (int c = 0; c < 4; ++c){        // k-chunks of 64
    __syncthreads();                  // St reusable (prev chunk's reads done)
    #pragma unroll
    for (int it = 0; it < 4; ++it){
      int rl = w*16 + it*4 + lk;
      St[rl][lm*4 + 0] = pre[it].x; St[rl][lm*4 + 1] = pre[it].y;
      St[rl][lm*4 + 2] = pre[it].z; St[rl][lm*4 + 3] = pre[it].w;
    }
    if (c < 3){                       // issue next chunk's loads early
      #pragma unroll
      for (int it = 0; it < 4; ++it){
        int rl = w*16 + it*4 + lk;
        pre[it] = *(const float4*)(utb + (size_t)((c+1)*64 + rl)*4096 + lm*4);
      }
    }
    __syncthreads();
    // transpose-read + skip + gelu -> bf16 Z-tile
    const float4 dk = *(const float4*)(Dsk + c*64 + lm*4);
    #pragma unroll
    for (int p = 0; p < 4; ++p){
      int tl = p*16 + w*4 + lk;       // token-local 0..63
      const float4 uv = *(const float4*)(ub + (size_t)tl*256 + c*64 + lm*4);
      short4 o;
      o.x = f2bf(gelu_exact(fmaf(dk.x, uv.x, St[lm*4 + 0][tl])));
      o.y = f2bf(gelu_exact(fmaf(dk.y, uv.y, St[lm*4 + 1][tl])));
      o.z = f2bf(gelu_exact(fmaf(dk.z, uv.z, St[lm*4 + 2][tl])));
      o.w = f2bf(gelu_exact(fmaf(dk.w, uv.w, St[lm*4 + 3][tl])));
      *(short4*)&At[tl][c*64 + lm*4] = o;
    }
  }
  __syncthreads();

  f32x4 acc[16];
  #pragma unroll
  for (int nt = 0; nt < 16; ++nt) acc[nt] = (f32x4){0.f, 0.f, 0.f, 0.f};

  #pragma unroll
  for (int ks = 0; ks < 8; ++ks){
    const bf16x8 zf = *(const bf16x8*)&At[w*16 + lm][ks*32 + lk*8];  // B: token col
    #pragma unroll
    for (int nt = 0; nt < 16; ++nt){
      const bf16x8* ap = (const bf16x8*)(Wb + (size_t)(nt*16 + lm)*256 + ks*32 + lk*8);
      acc[nt] = __builtin_amdgcn_mfma_f32_16x16x32_bf16(*ap, zf, acc[nt], 0, 0, 0);
    }
  }

  // epilogue: x = X + bias + u ; LayerNorm over features (in-lane + 2 shuffles)
  // lane holds token tt = tokB + w*16 + lm, features f = nt*16 + lk*4 + r.
  const int tt = tokB + w*16 + lm;
  const float* ur = u + (size_t)tt * 256;
  float s = 0.f, s2 = 0.f;
  #pragma unroll
  for (int nt = 0; nt < 16; ++nt){
    const int f0 = nt*16 + lk*4;
    const float4 uv = *(const float4*)(ur + f0);
    const float4 bv = *(const float4*)&prm[0][f0];
    acc[nt][0] += bv.x + uv.x;
    acc[nt][1] += bv.y + uv.y;
    acc[nt][2] += bv.z + uv.z;
    acc[nt][3] += bv.w + uv.w;
    s += acc[nt][0] + acc[nt][1] + acc[nt][2] + acc[nt][3];
    s2 = fmaf(acc[nt][0], acc[nt][0], s2);
    s2 = fmaf(acc[nt][1], acc[nt][1], s2);
    s2 = fmaf(acc[nt][2], acc[nt][2], s2);
    s2 = fmaf(acc[nt][3], acc[nt][3], s2);
  }
  s  += __shfl_xor(s,  16); s  += __shfl_xor(s,  32);
  s2 += __shfl_xor(s2, 16); s2 += __shfl_xor(s2, 32);
  const float mu = s * (1.0f/256.0f);
  const float rs = rsqrtf(s2 * (1.0f/256.0f) - mu*mu + 1e-5f);
  float* orow = out + (size_t)tt * 256;
  #pragma unroll
  for (int nt = 0; nt < 16; ++nt){
    const int f0 = nt*16 + lk*4;
    const float4 gv = *(const float4*)&prm[1][f0];
    const float4 ev = *(const float4*)&prm[2][f0];
    float4 o;
    o.x = (acc[nt][0] - mu) * rs * gv.x + ev.x;
    o.y = (acc[nt][1] - mu) * rs * gv.y + ev.y;
    o.z = (acc[nt][2] - mu) * rs * gv.z + ev.z;
    o.w = (acc[nt][3] - mu) * rs * gv.w + ev.w;
    *(float4*)(orow + f0) = o;
  }
}

// ---------------------------------------------------------------------------
extern "C" void kernel_launch(void* const* d_in, const int* in_sizes, int n_in,
                              void* d_out, int out_size, void* d_ws, size_t ws_size,
                              hipStream_t stream){
  (void)in_sizes; (void)n_in; (void)out_size; (void)ws_size;
  const float* u        = (const float*)d_in[0];
  const float* B_ri     = (const float*)d_in[1];
  const float* Ct_ri    = (const float*)d_in[2];
  const float* lam_ri   = (const float*)d_in[3];
  const float* p_ri     = (const float*)d_in[4];
  const float* q_ri     = (const float*)d_in[5];
  const float* log_step = (const float*)d_in[6];
  const float* D_skip   = (const float*)d_in[7];
  const float* W        = (const float*)d_in[8];
  const float* bias     = (const float*)d_in[9];
  const float* gamma    = (const float*)d_in[10];
  const float* beta     = (const float*)d_in[11];
  float* out = (float*)d_out;

  // Workspace: KdE 4,196,352 | KdO 4,194,304 | Wb 131,072 | ut 33,554,432
  char* ws = (char*)d_ws;
  float* KdE = (float*)(ws);
  float* KdO = (float*)(ws + 4196352);
  short* Wb  = (short*)(ws + 4196352 + 4194304);
  float* ut  = (float*)(ws + 4196352 + 4194304 + 131072);

  convert_w   <<<64,              256, 0, stream>>>(W, Wb);
  cauchy_ar   <<<2048,            256, 0, stream>>>(B_ri, Ct_ri, lam_ri, p_ri, q_ri, log_step, KdE);
  fft_kd      <<<256,             256, 0, stream>>>(KdE, KdO);
  transpose_u <<<dim3(128, 8, 8), 256, 0, stream>>>(u, ut);
  s4_conv     <<<2048,            256, 0, stream>>>(ut, KdE, KdO);
  mfma_gemm_ln<<<512,             256, 0, stream>>>(ut, Wb, D_skip, bias, u, gamma, beta, out);
}

// Round 7
// 146.259 us; speedup vs baseline: 2.4923x; 1.0477x over previous
//
#include <hip/hip_runtime.h>
#include <math.h>

// S4 block: Cauchy (Hermitian-half) + even-bin identity + register four-step
// FFTs (16x16x16); s4_conv fuses skip+GELU and emits bf16; GEMM+LN is a pure
// bf16 MFMA kernel with double-buffered LDS staging.  B=8, L=4096, D=256, N=64.

typedef float2 cf;
typedef __attribute__((ext_vector_type(8))) short bf16x8;
typedef __attribute__((ext_vector_type(4))) float f32x4;

__device__ __forceinline__ cf cmul(cf a, cf b){
  return make_float2(fmaf(a.x, b.x, -a.y*b.y), fmaf(a.x, b.y, a.y*b.x));
}
__device__ __forceinline__ cf cadd(cf a, cf b){ return make_float2(a.x+b.x, a.y+b.y); }
__device__ __forceinline__ cf csub(cf a, cf b){ return make_float2(a.x-b.x, a.y-b.y); }
__device__ __forceinline__ cf cscale(cf a, float s){ return make_float2(a.x*s, a.y*s); }
__device__ __forceinline__ cf cconj(cf a){ return make_float2(a.x, -a.y); }

__device__ __forceinline__ short f2bf(float x){   // RNE float->bf16
  union { float f; unsigned u; } v; v.f = x;
  unsigned r = v.u + 0x7fffu + ((v.u >> 16) & 1u);
  return (short)(r >> 16);
}

// LDS swizzle for FFT buffer: XOR bits[7:4] into bits[3:0].
__device__ __forceinline__ int SW(int i){ return i ^ ((i >> 4) & 15); }
// After fft16, output V[k] sits in v[RI(k)].
__device__ __forceinline__ constexpr int RI(int k){ return ((k & 3) << 2) | (k >> 2); }

#define C8 0.92387953251f
#define S8 0.38268343236f
#define RH 0.70710678119f

__device__ __forceinline__ void r4(cf& a, cf& b, cf& c, cf& d, float dir){
  cf T0 = cadd(a, c), T1 = csub(a, c);
  cf T2 = cadd(b, d), Bd = csub(b, d);
  cf T3 = make_float2(-dir*Bd.y, dir*Bd.x);     // J*(b-d), J = dir*i
  a = cadd(T0, T2); b = cadd(T1, T3); c = csub(T0, T2); d = csub(T1, T3);
}

__device__ __forceinline__ void fft16(cf* v, float dir){
  r4(v[0], v[4], v[8],  v[12], dir);
  r4(v[1], v[5], v[9],  v[13], dir);
  r4(v[2], v[6], v[10], v[14], dir);
  r4(v[3], v[7], v[11], v[15], dir);
  cf w1 = make_float2(C8,  dir*S8);
  cf w2 = make_float2(RH,  dir*RH);
  cf w3 = make_float2(S8,  dir*C8);
  cf w4 = make_float2(0.f, dir);
  cf w6 = make_float2(-RH, dir*RH);
  cf w9 = make_float2(-C8, -dir*S8);
  v[5]  = cmul(v[5],  w1); v[6]  = cmul(v[6],  w2); v[7]  = cmul(v[7],  w3);
  v[9]  = cmul(v[9],  w2); v[10] = cmul(v[10], w4); v[11] = cmul(v[11], w6);
  v[13] = cmul(v[13], w3); v[14] = cmul(v[14], w6); v[15] = cmul(v[15], w9);
  r4(v[0],  v[1],  v[2],  v[3],  dir);
  r4(v[4],  v[5],  v[6],  v[7],  dir);
  r4(v[8],  v[9],  v[10], v[11], dir);
  r4(v[12], v[13], v[14], v[15], dir);
}

// 4096-pt FFT, four-step 16x(16x16), one shared cf[4096] buffer (SW-indexed).
// Entry: v[n1] = x[n1*256 + t].  Exit: V[k1+16*ka+256*kb] = v[RI(kb)],
// k1 = t>>4, ka = t&15.  Starts with a barrier.
__device__ void fft4096_reg(cf* v, cf* lds, float dir){
  const int t = threadIdx.x;
  fft16(v, dir);
  float sn, cs;
  __sincosf(dir * 1.5339807878856412e-3f * (float)t, &sn, &cs);   // 2pi/4096
  cf w = make_float2(cs, sn), cw = w;
  __syncthreads();
  lds[SW(t)] = v[0];
  #pragma unroll
  for (int k1 = 1; k1 < 16; ++k1){
    lds[SW(k1*256 + t)] = cmul(v[RI(k1)], cw);
    cw = cmul(cw, w);
  }
  __syncthreads();
  const int k1 = t >> 4, m2 = t & 15;
  #pragma unroll
  for (int m1 = 0; m1 < 16; ++m1) v[m1] = lds[SW(k1*256 + m1*16 + m2)];
  fft16(v, dir);
  __sincosf(dir * 2.45436926061703e-2f * (float)m2, &sn, &cs);    // 2pi/256
  w = make_float2(cs, sn); cw = w;
  __syncthreads();
  lds[SW(k1*256 + m2)] = v[0];
  #pragma unroll
  for (int ka = 1; ka < 16; ++ka){
    lds[SW(k1*256 + ka*16 + m2)] = cmul(v[RI(ka)], cw);
    cw = cmul(cw, w);
  }
  __syncthreads();
  const int ka = t & 15;
  #pragma unroll
  for (int m2b = 0; m2b < 16; ++m2b) v[m2b] = lds[SW(k1*256 + ka*16 + m2b)];
  fft16(v, dir);
}

// ---------------------------------------------------------------------------
// Kernel 1a: Cauchy generating function, Hermitian half (l = 0..2048).
// Even-bin identity: rfft(K,8192)[2m] = ar[m] -> KdE[d][m], m = 0..2048.
__global__ __launch_bounds__(256)
void cauchy_ar(const float* __restrict__ B_ri, const float* __restrict__ Ct_ri,
               const float* __restrict__ lam_ri, const float* __restrict__ p_ri,
               const float* __restrict__ q_ri, const float* __restrict__ log_step,
               float* __restrict__ KdE){
  __shared__ cf w00[64], w01[64], w10[64], w11[64], lamS[64];
  const int d     = blockIdx.x >> 3;
  const int chunk = blockIdx.x & 7;
  const int tid   = threadIdx.x;
  const float step = expf(log_step[d]);

  if (tid < 64){
    int n = tid;
    cf Bv = make_float2(B_ri[(d*64+n)*2],  B_ri[(d*64+n)*2+1]);
    cf Cv = make_float2(Ct_ri[(d*64+n)*2], Ct_ri[(d*64+n)*2+1]);
    cf pv = make_float2(p_ri[n*2], p_ri[n*2+1]);
    cf qv = make_float2(q_ri[n*2], q_ri[n*2+1]);
    lamS[n] = make_float2(lam_ri[n*2], lam_ri[n*2+1]);
    cf Cc = cconj(Cv), qc = cconj(qv);
    w00[n] = cmul(Cc, Bv);
    w01[n] = cmul(Cc, pv);
    w10[n] = cmul(qc, Bv);
    w11[n] = cmul(qc, pv);
  }
  __syncthreads();

  cf* out = (cf*)KdE + (size_t)d * 2049;
  const int l = chunk * 256 + tid;               // 0..2047
  {
    float th = -(6.28318530717958647692f * (float)l) * (1.0f/4096.0f);
    float sn = sinf(th), cs = cosf(th);          // accurate sin/cos
    cf opw = make_float2(1.0f + cs,  sn);        // 1 + omega
    cf omw = make_float2(1.0f - cs, -sn);        // 1 - omega
    float idn = 1.0f / fmaf(opw.x, opw.x, opw.y*opw.y);
    cf ratio = make_float2((omw.x*opw.x + omw.y*opw.y)*idn,
                           (omw.y*opw.x - omw.x*opw.y)*idn);
    cf g  = cscale(ratio, 2.0f / step);
    cf cc = make_float2(2.0f*opw.x*idn, -2.0f*opw.y*idn);   // 2/(1+omega)
    cf k00 = {0,0}, k01 = {0,0}, k10 = {0,0}, k11 = {0,0};
    #pragma unroll 4
    for (int n = 0; n < 64; ++n){
      cf lv  = lamS[n];
      cf den = make_float2(g.x - lv.x, g.y - lv.y);
      float is = 1.0f / fmaf(den.x, den.x, den.y*den.y);
      cf r = make_float2(den.x*is, -den.y*is);               // 1/(g - lam)
      k00 = cadd(k00, cmul(w00[n], r));
      k01 = cadd(k01, cmul(w01[n], r));
      k10 = cadd(k10, cmul(w10[n], r));
      k11 = cadd(k11, cmul(w11[n], r));
    }
    cf onep = make_float2(1.0f + k11.x, k11.y);
    float ii = 1.0f / fmaf(onep.x, onep.x, onep.y*onep.y);
    cf inv1p = make_float2(onep.x*ii, -onep.y*ii);
    cf corr = cmul(k01, cmul(k10, inv1p));
    out[l] = cmul(cc, csub(k00, corr));
  }
  if (chunk == 7 && tid == 255){
    cf s00 = make_float2(0.f, 0.f);
    for (int n = 0; n < 64; ++n) s00 = cadd(s00, w00[n]);
    out[2048] = cscale(s00, 0.5f * step);
  }
}

// ---------------------------------------------------------------------------
// Kernel 1b: odd bins. KdO[d][m] = FFT4096( Re(K[n]) e^{-i pi n/4096} )[m].
__global__ __launch_bounds__(256)
void fft_kd(const float* __restrict__ KdE, float* __restrict__ KdO){
  __shared__ cf L[4096];
  const int d = blockIdx.x, t = threadIdx.x;
  const cf* kdE = (const cf*)KdE + (size_t)d * 2049;
  cf* kdO = (cf*)KdO + (size_t)d * 2048;
  cf v[16];
  const float inv = 1.0f / 4096.0f;
  #pragma unroll
  for (int n1 = 0; n1 < 16; ++n1){
    int m = n1*256 + t;
    cf a = (m <= 2048) ? kdE[m] : cconj(kdE[4096 - m]);
    v[n1] = cscale(a, inv);
  }
  fft4096_reg(v, L, +1.0f);            // K (real part)
  const int k1 = t >> 4, ka = t & 15;
  __syncthreads();
  #pragma unroll
  for (int kb = 0; kb < 16; ++kb){
    int g = k1 + 16*ka + 256*kb;
    float kr = v[RI(kb)].x;
    float sn, cs; __sincosf(-7.669903939428206e-4f * (float)g, &sn, &cs);
    L[SW(g)] = make_float2(kr*cs, kr*sn);
  }
  __syncthreads();
  #pragma unroll
  for (int n1 = 0; n1 < 16; ++n1) v[n1] = L[SW(n1*256 + t)];
  fft4096_reg(v, L, -1.0f);
  #pragma unroll
  for (int kb = 0; kb < 8; ++kb)
    kdO[k1 + 16*ka + 256*kb] = v[RI(kb)];
}

// ---------------------------------------------------------------------------
// Kernel 2: tiled transpose u[B][L][D] -> ut[(b*256+d)][L]
__global__ __launch_bounds__(256)
void transpose_u(const float* __restrict__ u, float* __restrict__ ut){
  __shared__ float tile[32][33];
  const int b  = blockIdx.z;
  const int l0 = blockIdx.x * 32;
  const int d0 = blockIdx.y * 32;
  const int tx = threadIdx.x & 31;
  const int ty = threadIdx.x >> 5;
  const float* ub = u + (size_t)b * 4096 * 256;
  #pragma unroll
  for (int it = 0; it < 4; ++it){
    int l = l0 + ty + it*8;
    tile[tx][ty + it*8] = ub[(size_t)l*256 + d0 + tx];
  }
  __syncthreads();
  float* utb = ut + (size_t)b * 256 * 4096;
  #pragma unroll
  for (int it = 0; it < 4; ++it){
    int dd = d0 + ty + it*8;
    utb[(size_t)dd*4096 + l0 + tx] = tile[ty + it*8][tx];
  }
}

// ---------------------------------------------------------------------------
// Kernel 3: per-(b,d) non-circular conv via packed real-FFT; fuses
// skip + exact GELU and writes bf16 Z overlaying the row's own storage.
__device__ __forceinline__ float gelu_exact(float x){
  return 0.5f * x * (1.0f + erff(x * 0.70710678118654752f));
}

__global__ __launch_bounds__(256)
void s4_conv(float* __restrict__ ut, const float* __restrict__ KdE,
             const float* __restrict__ KdO, const float* __restrict__ Dsk){
  __shared__ cf L[4096];
  const int row = blockIdx.x;           // b*256 + d
  const int d   = row & 255;
  const int t   = threadIdx.x;
  float2* rp = (float2*)(ut + (size_t)row * 4096);
  const float dskd = Dsk[d];

  cf v[16], uin[8];
  #pragma unroll
  for (int n1 = 0; n1 < 8; ++n1){ uin[n1] = rp[n1*256 + t]; v[n1] = uin[n1]; }
  #pragma unroll
  for (int n1 = 8; n1 < 16; ++n1) v[n1] = make_float2(0.f, 0.f);

  fft4096_reg(v, L, -1.0f);             // Z
  const int k1 = t >> 4, ka = t & 15;
  __syncthreads();
  #pragma unroll
  for (int kb = 0; kb < 16; ++kb)
    L[SW(k1 + 16*ka + 256*kb)] = v[RI(kb)];
  __syncthreads();

  const cf* kdE = (const cf*)KdE + (size_t)d * 2049;
  const cf* kdO = (const cf*)KdO + (size_t)d * 2048;
  #pragma unroll
  for (int m = 0; m < 8; ++m){
    int k = t + m*256;                  // 0..2047
    if (k == 0){
      cf z0 = L[SW(0)];
      float U0 = z0.x + z0.y, UN = z0.x - z0.y;
      cf P0 = cscale(kdE[0], U0);
      cf PN = cscale(kdE[2048], UN);
      cf cPN = cconj(PN);
      cf Ep = cscale(cadd(P0, cPN), 0.5f);
      cf Op = cscale(csub(P0, cPN), 0.5f);
      L[SW(0)] = make_float2(Ep.x - Op.y, Ep.y + Op.x);
      cf P = cmul(cconj(L[SW(2048)]), kdE[1024]);
      L[SW(2048)] = cconj(P);
    } else {
      cf zk = L[SW(k)], zj = L[SW(4096 - k)];
      cf E = make_float2(0.5f*(zk.x + zj.x),  0.5f*(zk.y - zj.y));
      cf O = make_float2(0.5f*(zk.y + zj.y), -0.5f*(zk.x - zj.x));
      float phi = 7.669903939428206e-4f * (float)k;     // pi*k/4096
      float sn, cs; __sincosf(phi, &sn, &cs);
      cf tw = make_float2(cs, -sn);
      cf tO = cmul(tw, O);
      cf Uk = cadd(E, tO);
      cf Uj = cconj(csub(E, tO));                        // U[4096-k]
      int h = k >> 1;
      cf kk, kj;
      if (k & 1){ kk = kdO[h]; kj = kdO[2047 - h]; }
      else      { kk = kdE[h]; kj = kdE[2048 - h]; }
      cf Pk = cmul(Uk, kk);
      cf Pj = cmul(Uj, kj);
      cf cPj = cconj(Pj), cPk = cconj(Pk);
      cf tp  = make_float2(cs, sn);
      cf Ek = cscale(cadd(Pk, cPj), 0.5f);
      cf Ok = cmul(tp, cscale(csub(Pk, cPj), 0.5f));
      L[SW(k)] = make_float2(Ek.x - Ok.y, Ek.y + Ok.x);
      cf tpj = make_float2(-cs, sn);
      cf Ej = cscale(cadd(Pj, cPk), 0.5f);
      cf Oj = cmul(tpj, cscale(csub(Pj, cPk), 0.5f));
      L[SW(4096 - k)] = make_float2(Ej.x - Oj.y, Ej.y + Oj.x);
    }
  }
  __syncthreads();

  #pragma unroll
  for (int n1 = 0; n1 < 16; ++n1) v[n1] = L[SW(n1*256 + t)];
  fft4096_reg(v, L, +1.0f);

  // conv tokens (pairs g<2048) -> LDS -> align with uin layout -> gelu -> bf16
  __syncthreads();
  #pragma unroll
  for (int kb = 0; kb < 8; ++kb)
    L[SW(k1 + 16*ka + 256*kb)] = v[RI(kb)];
  __syncthreads();
  const float inv = 1.0f / 4096.0f;
  unsigned* og = (unsigned*)rp;         // bf16 overlay (2 tokens / dword)
  #pragma unroll
  for (int n1 = 0; n1 < 8; ++n1){
    int g = n1*256 + t;
    cf cv = L[SW(g)];
    float x0 = fmaf(dskd, uin[n1].x, cv.x * inv);
    float x1 = fmaf(dskd, uin[n1].y, cv.y * inv);
    unsigned b0 = (unsigned)(unsigned short)f2bf(gelu_exact(x0));
    unsigned b1 = (unsigned)(unsigned short)f2bf(gelu_exact(x1));
    og[g] = b0 | (b1 << 16);
  }
}

// ---------------------------------------------------------------------------
// Kernel 0: W[f][k] f32 -> Wb[f][k] bf16 (MFMA A-operand layout).
__global__ __launch_bounds__(256)
void convert_w(const float* __restrict__ W, short* __restrict__ Wb){
  int i = (blockIdx.x * 256 + threadIdx.x) * 4;
  float4 w = *(const float4*)(W + i);
  short4 o;
  o.x = f2bf(w.x); o.y = f2bf(w.y); o.z = f2bf(w.z); o.w = f2bf(w.w);
  *(short4*)(Wb + i) = o;
}

// ---------------------------------------------------------------------------
// Kernel 5: X = Z @ W^T + b + u ; LayerNorm -> out.  Z read as bf16 from the
// ut overlay ([k][token], row stride 16384 B).  Double-buffered 8 KB St tiles,
// XOR-swizzled (slot8 ^= (row>>3)&7): conflict-free b128 writes AND u16
// column reads.  A = W rows (features), B = Z (tokens) -> in-lane LN.
__global__ __launch_bounds__(256)
void mfma_gemm_ln(const float* __restrict__ utg, const short* __restrict__ Wb,
                  const float* __restrict__ bias, const float* __restrict__ u,
                  const float* __restrict__ gamma, const float* __restrict__ beta,
                  float* __restrict__ out){
  __shared__ short St[2][64][64];
  __shared__ float prm[3][256];
  const int w    = threadIdx.x >> 6;
  const int l    = threadIdx.x & 63;
  const int lm   = l & 15;
  const int lk   = l >> 4;
  const int tokB = blockIdx.x * 64;   // never straddles batch (64 | 4096)
  const int b    = tokB >> 12;
  const int l0   = tokB & 4095;

  prm[0][threadIdx.x] = bias[threadIdx.x];
  prm[1][threadIdx.x] = gamma[threadIdx.x];
  prm[2][threadIdx.x] = beta[threadIdx.x];

  // staging lane coords: 2 instrs/wave/chunk, 8 rows x 8 slot8 each
  const int srow = (l >> 3);          // row offset within 8-row group
  const int sg8  = l & 7;             // token-group (8 bf16 = 16 B)
  const char* ubase = (const char*)utg + (size_t)(b * 256) * 16384;

  bf16x8 pre[2];
  #pragma unroll
  for (int it = 0; it < 2; ++it){     // chunk 0 loads (issued first)
    int r = w*16 + it*8 + srow;
    pre[it] = *(const bf16x8*)((const unsigned short*)(ubase + (size_t)r * 16384) + l0 + sg8*8);
  }

  f32x4 acc[16];
  #pragma unroll
  for (int nt = 0; nt < 16; ++nt) acc[nt] = (f32x4){0.f, 0.f, 0.f, 0.f};

  const int tg  = (w*16 + lm) >> 3;   // this lane's token-group
  const int tlo = lm & 7;

  for (int c = 0; c < 4; ++c){
    const int buf = c & 1;
    #pragma unroll
    for (int it = 0; it < 2; ++it){   // write staged regs (swizzled slot)
      int r = w*16 + it*8 + srow;
      int sl = (sg8 ^ ((r >> 3) & 7)) * 8;
      *(bf16x8*)&St[buf][r][sl] = pre[it];
    }
    __syncthreads();
    if (c < 3){                       // issue next chunk AFTER barrier (T14)
      #pragma unroll
      for (int it = 0; it < 2; ++it){
        int r = w*16 + it*8 + srow;
        pre[it] = *(const bf16x8*)((const unsigned short*)(ubase + (size_t)((c+1)*64 + r) * 16384) + l0 + sg8*8);
      }
    }
    #pragma unroll
    for (int s2 = 0; s2 < 2; ++s2){
      const int ks  = c*2 + s2;
      const int p   = (s2*4 + lk) & 7;          // (k_local>>3)&7
      const int idx = ((tg ^ p) << 3) | tlo;
      bf16x8 zf;
      #pragma unroll
      for (int j = 0; j < 8; ++j)
        zf[j] = St[buf][s2*32 + lk*8 + j][idx];
      #pragma unroll
      for (int nt = 0; nt < 16; ++nt){
        const bf16x8* ap = (const bf16x8*)(Wb + (size_t)(nt*16 + lm)*256 + ks*32 + lk*8);
        acc[nt] = __builtin_amdgcn_mfma_f32_16x16x32_bf16(*ap, zf, acc[nt], 0, 0, 0);
      }
    }
    __syncthreads();                  // St[buf] reads done before rewrite
  }

  // epilogue: x = X + bias + u ; LayerNorm over features (in-lane + 2 shuffles)
  const int tt = tokB + w*16 + lm;
  const float* ur = u + (size_t)tt * 256;
  float s = 0.f, s2 = 0.f;
  #pragma unroll
  for (int nt = 0; nt < 16; ++nt){
    const int f0 = nt*16 + lk*4;
    const float4 uv = *(const float4*)(ur + f0);
    const float4 bv = *(const float4*)&prm[0][f0];
    acc[nt][0] += bv.x + uv.x;
    acc[nt][1] += bv.y + uv.y;
    acc[nt][2] += bv.z + uv.z;
    acc[nt][3] += bv.w + uv.w;
    s += acc[nt][0] + acc[nt][1] + acc[nt][2] + acc[nt][3];
    s2 = fmaf(acc[nt][0], acc[nt][0], s2);
    s2 = fmaf(acc[nt][1], acc[nt][1], s2);
    s2 = fmaf(acc[nt][2], acc[nt][2], s2);
    s2 = fmaf(acc[nt][3], acc[nt][3], s2);
  }
  s  += __shfl_xor(s,  16); s  += __shfl_xor(s,  32);
  s2 += __shfl_xor(s2, 16); s2 += __shfl_xor(s2, 32);
  const float mu = s * (1.0f/256.0f);
  const float rs = rsqrtf(s2 * (1.0f/256.0f) - mu*mu + 1e-5f);
  float* orow = out + (size_t)tt * 256;
  #pragma unroll
  for (int nt = 0; nt < 16; ++nt){
    const int f0 = nt*16 + lk*4;
    const float4 gv = *(const float4*)&prm[1][f0];
    const float4 ev = *(const float4*)&prm[2][f0];
    float4 o;
    o.x = (acc[nt][0] - mu) * rs * gv.x + ev.x;
    o.y = (acc[nt][1] - mu) * rs * gv.y + ev.y;
    o.z = (acc[nt][2] - mu) * rs * gv.z + ev.z;
    o.w = (acc[nt][3] - mu) * rs * gv.w + ev.w;
    *(float4*)(orow + f0) = o;
  }
}

// ---------------------------------------------------------------------------
extern "C" void kernel_launch(void* const* d_in, const int* in_sizes, int n_in,
                              void* d_out, int out_size, void* d_ws, size_t ws_size,
                              hipStream_t stream){
  (void)in_sizes; (void)n_in; (void)out_size; (void)ws_size;
  const float* u        = (const float*)d_in[0];
  const float* B_ri     = (const float*)d_in[1];
  const float* Ct_ri    = (const float*)d_in[2];
  const float* lam_ri   = (const float*)d_in[3];
  const float* p_ri     = (const float*)d_in[4];
  const float* q_ri     = (const float*)d_in[5];
  const float* log_step = (const float*)d_in[6];
  const float* D_skip   = (const float*)d_in[7];
  const float* W        = (const float*)d_in[8];
  const float* bias     = (const float*)d_in[9];
  const float* gamma    = (const float*)d_in[10];
  const float* beta     = (const float*)d_in[11];
  float* out = (float*)d_out;

  // Workspace: KdE 4,196,352 | KdO 4,194,304 | Wb 131,072 | ut 33,554,432
  char* ws = (char*)d_ws;
  float* KdE = (float*)(ws);
  float* KdO = (float*)(ws + 4196352);
  short* Wb  = (short*)(ws + 4196352 + 4194304);
  float* ut  = (float*)(ws + 4196352 + 4194304 + 131072);

  convert_w   <<<64,              256, 0, stream>>>(W, Wb);
  cauchy_ar   <<<2048,            256, 0, stream>>>(B_ri, Ct_ri, lam_ri, p_ri, q_ri, log_step, KdE);
  fft_kd      <<<256,             256, 0, stream>>>(KdE, KdO);
  transpose_u <<<dim3(128, 8, 8), 256, 0, stream>>>(u, ut);
  s4_conv     <<<2048,            256, 0, stream>>>(ut, KdE, KdO, D_skip);
  mfma_gemm_ln<<<512,             256, 0, stream>>>(ut, Wb, bias, u, gamma, beta, out);
}

// Round 8
// 140.427 us; speedup vs baseline: 2.5958x; 1.0415x over previous
//
#include <hip/hip_runtime.h>
#include <math.h>

// S4 block: Cauchy (Hermitian-half) + even-bin identity + register four-step
// FFTs (16x16x16, template-DIR, tree twiddles, folded swizzle addressing);
// s4_conv fuses skip+GELU (fast erf) -> bf16; GEMM+LN pure bf16 MFMA.
// B=8, L=4096, D=256, N=64.

typedef float2 cf;
typedef __attribute__((ext_vector_type(8))) short bf16x8;
typedef __attribute__((ext_vector_type(4))) float f32x4;

__device__ __forceinline__ cf cmul(cf a, cf b){
  return make_float2(fmaf(a.x, b.x, -a.y*b.y), fmaf(a.x, b.y, a.y*b.x));
}
__device__ __forceinline__ cf cadd(cf a, cf b){ return make_float2(a.x+b.x, a.y+b.y); }
__device__ __forceinline__ cf csub(cf a, cf b){ return make_float2(a.x-b.x, a.y-b.y); }
__device__ __forceinline__ cf cscale(cf a, float s){ return make_float2(a.x*s, a.y*s); }
__device__ __forceinline__ cf cconj(cf a){ return make_float2(a.x, -a.y); }

__device__ __forceinline__ short f2bf(float x){   // RNE float->bf16
  union { float f; unsigned u; } v; v.f = x;
  unsigned r = v.u + 0x7fffu + ((v.u >> 16) & 1u);
  return (short)(r >> 16);
}

// Generic LDS swizzle (used only where the folded form doesn't apply).
__device__ __forceinline__ int SW(int i){ return i ^ ((i >> 4) & 15); }
// After fft16, output V[k] sits in v[RI(k)].
__device__ __forceinline__ constexpr int RI(int k){ return ((k & 3) << 2) | (k >> 2); }

#define C8 0.92387953251f
#define S8 0.38268343236f
#define RH 0.70710678119f

template<int DIR>
__device__ __forceinline__ void r4(cf& a, cf& b, cf& c, cf& d){
  cf T0 = cadd(a, c), T1 = csub(a, c);
  cf T2 = cadd(b, d), Bd = csub(b, d);
  cf T3 = (DIR > 0) ? make_float2(-Bd.y, Bd.x) : make_float2(Bd.y, -Bd.x);
  a = cadd(T0, T2); b = cadd(T1, T3); c = csub(T0, T2); d = csub(T1, T3);
}

template<int DIR>
__device__ __forceinline__ void fft16(cf* v){
  r4<DIR>(v[0], v[4], v[8],  v[12]);
  r4<DIR>(v[1], v[5], v[9],  v[13]);
  r4<DIR>(v[2], v[6], v[10], v[14]);
  r4<DIR>(v[3], v[7], v[11], v[15]);
  constexpr float D = (float)DIR;
  const cf w1 = make_float2(C8,  D*S8);
  const cf w2 = make_float2(RH,  D*RH);
  const cf w3 = make_float2(S8,  D*C8);
  const cf w6 = make_float2(-RH, D*RH);
  const cf w9 = make_float2(-C8, -D*S8);
  v[5]  = cmul(v[5],  w1);
  v[6]  = cmul(v[6],  w2);
  v[7]  = cmul(v[7],  w3);
  v[9]  = cmul(v[9],  w2);
  v[10] = make_float2(-D*v[10].y, D*v[10].x);     // * (0, D)
  v[11] = cmul(v[11], w6);
  v[13] = cmul(v[13], w3);
  v[14] = cmul(v[14], w6);
  v[15] = cmul(v[15], w9);
  r4<DIR>(v[0],  v[1],  v[2],  v[3]);
  r4<DIR>(v[4],  v[5],  v[6],  v[7]);
  r4<DIR>(v[8],  v[9],  v[10], v[11]);
  r4<DIR>(v[12], v[13], v[14], v[15]);
}

// 4096-pt FFT, four-step 16x(16x16), one shared cf[4096] buffer.
// Entry: v[n1] = x[n1*256 + t].  Exit: V[k1+16*ka+256*kb] = v[RI(kb)],
// k1 = t>>4, ka = t&15.  Starts with a barrier.  Swizzle folded into
// compile-time offsets; twiddles via depth-4 product tree.
template<int DIR>
__device__ void fft4096_reg(cf* v, cf* lds){
  const int t = threadIdx.x;
  const int k1 = t >> 4, m2 = t & 15;
  const int swt = t ^ k1;                 // SW(t)
  constexpr float D = (float)DIR;
  fft16<DIR>(v);
  float sn, cs;
  __sincosf(D * 1.5339807878856412e-3f * (float)t, &sn, &cs);   // 2pi/4096
  __syncthreads();
  {
    cf* p = lds + swt;
    cf w1 = make_float2(cs, sn);
    p[0]    = v[0];
    p[256]  = cmul(v[RI(1)],  w1);
    cf w2 = cmul(w1, w1);
    p[512]  = cmul(v[RI(2)],  w2);
    cf w3 = cmul(w2, w1);
    p[768]  = cmul(v[RI(3)],  w3);
    cf w4 = cmul(w2, w2);
    p[1024] = cmul(v[RI(4)],  w4);
    cf w5 = cmul(w4, w1);
    p[1280] = cmul(v[RI(5)],  w5);
    cf w6 = cmul(w4, w2);
    p[1536] = cmul(v[RI(6)],  w6);
    cf w7 = cmul(w4, w3);
    p[1792] = cmul(v[RI(7)],  w7);
    cf w8 = cmul(w4, w4);
    p[2048] = cmul(v[RI(8)],  w8);
    p[2304] = cmul(v[RI(9)],  cmul(w8, w1));
    p[2560] = cmul(v[RI(10)], cmul(w8, w2));
    p[2816] = cmul(v[RI(11)], cmul(w8, w3));
    p[3072] = cmul(v[RI(12)], cmul(w8, w4));
    p[3328] = cmul(v[RI(13)], cmul(w8, w5));
    p[3584] = cmul(v[RI(14)], cmul(w8, w6));
    p[3840] = cmul(v[RI(15)], cmul(w8, w7));
  }
  __syncthreads();
  {
    cf* p = lds + k1*256;
    #pragma unroll
    for (int m1 = 0; m1 < 16; ++m1) v[m1] = p[m1*16 + (m2 ^ m1)];
  }
  fft16<DIR>(v);
  __sincosf(D * 2.45436926061703e-2f * (float)m2, &sn, &cs);    // 2pi/256
  __syncthreads();
  {
    cf* p = lds + k1*256;
    cf w1 = make_float2(cs, sn);
    p[m2]              = v[0];
    p[16  + (m2^1)]    = cmul(v[RI(1)],  w1);
    cf w2 = cmul(w1, w1);
    p[32  + (m2^2)]    = cmul(v[RI(2)],  w2);
    cf w3 = cmul(w2, w1);
    p[48  + (m2^3)]    = cmul(v[RI(3)],  w3);
    cf w4 = cmul(w2, w2);
    p[64  + (m2^4)]    = cmul(v[RI(4)],  w4);
    cf w5 = cmul(w4, w1);
    p[80  + (m2^5)]    = cmul(v[RI(5)],  w5);
    cf w6 = cmul(w4, w2);
    p[96  + (m2^6)]    = cmul(v[RI(6)],  w6);
    cf w7 = cmul(w4, w3);
    p[112 + (m2^7)]    = cmul(v[RI(7)],  w7);
    cf w8 = cmul(w4, w4);
    p[128 + (m2^8)]    = cmul(v[RI(8)],  w8);
    p[144 + (m2^9)]    = cmul(v[RI(9)],  cmul(w8, w1));
    p[160 + (m2^10)]   = cmul(v[RI(10)], cmul(w8, w2));
    p[176 + (m2^11)]   = cmul(v[RI(11)], cmul(w8, w3));
    p[192 + (m2^12)]   = cmul(v[RI(12)], cmul(w8, w4));
    p[208 + (m2^13)]   = cmul(v[RI(13)], cmul(w8, w5));
    p[224 + (m2^14)]   = cmul(v[RI(14)], cmul(w8, w6));
    p[240 + (m2^15)]   = cmul(v[RI(15)], cmul(w8, w7));
  }
  __syncthreads();
  {
    const int ka = m2;
    cf* p = lds + k1*256 + ka*16;
    #pragma unroll
    for (int m2b = 0; m2b < 16; ++m2b) v[m2b] = p[m2b ^ ka];
  }
  fft16<DIR>(v);
}

// ---------------------------------------------------------------------------
// Kernel 1a: Cauchy generating function, Hermitian half (l = 0..2048).
// Even-bin identity: rfft(K,8192)[2m] = ar[m] -> KdE[d][m], m = 0..2048.
__global__ __launch_bounds__(256)
void cauchy_ar(const float* __restrict__ B_ri, const float* __restrict__ Ct_ri,
               const float* __restrict__ lam_ri, const float* __restrict__ p_ri,
               const float* __restrict__ q_ri, const float* __restrict__ log_step,
               float* __restrict__ KdE){
  __shared__ cf w00[64], w01[64], w10[64], w11[64], lamS[64];
  const int d     = blockIdx.x >> 3;
  const int chunk = blockIdx.x & 7;
  const int tid   = threadIdx.x;
  const float step = expf(log_step[d]);

  if (tid < 64){
    int n = tid;
    cf Bv = make_float2(B_ri[(d*64+n)*2],  B_ri[(d*64+n)*2+1]);
    cf Cv = make_float2(Ct_ri[(d*64+n)*2], Ct_ri[(d*64+n)*2+1]);
    cf pv = make_float2(p_ri[n*2], p_ri[n*2+1]);
    cf qv = make_float2(q_ri[n*2], q_ri[n*2+1]);
    lamS[n] = make_float2(lam_ri[n*2], lam_ri[n*2+1]);
    cf Cc = cconj(Cv), qc = cconj(qv);
    w00[n] = cmul(Cc, Bv);
    w01[n] = cmul(Cc, pv);
    w10[n] = cmul(qc, Bv);
    w11[n] = cmul(qc, pv);
  }
  __syncthreads();

  cf* out = (cf*)KdE + (size_t)d * 2049;
  const int l = chunk * 256 + tid;               // 0..2047
  {
    float th = -(6.28318530717958647692f * (float)l) * (1.0f/4096.0f);
    float sn = sinf(th), cs = cosf(th);          // accurate sin/cos
    cf opw = make_float2(1.0f + cs,  sn);        // 1 + omega
    cf omw = make_float2(1.0f - cs, -sn);        // 1 - omega
    float idn = 1.0f / fmaf(opw.x, opw.x, opw.y*opw.y);
    cf ratio = make_float2((omw.x*opw.x + omw.y*opw.y)*idn,
                           (omw.y*opw.x - omw.x*opw.y)*idn);
    cf g  = cscale(ratio, 2.0f / step);
    cf cc = make_float2(2.0f*opw.x*idn, -2.0f*opw.y*idn);   // 2/(1+omega)
    cf k00 = {0,0}, k01 = {0,0}, k10 = {0,0}, k11 = {0,0};
    #pragma unroll 4
    for (int n = 0; n < 64; ++n){
      cf lv  = lamS[n];
      cf den = make_float2(g.x - lv.x, g.y - lv.y);
      float is = 1.0f / fmaf(den.x, den.x, den.y*den.y);
      cf r = make_float2(den.x*is, -den.y*is);               // 1/(g - lam)
      k00 = cadd(k00, cmul(w00[n], r));
      k01 = cadd(k01, cmul(w01[n], r));
      k10 = cadd(k10, cmul(w10[n], r));
      k11 = cadd(k11, cmul(w11[n], r));
    }
    cf onep = make_float2(1.0f + k11.x, k11.y);
    float ii = 1.0f / fmaf(onep.x, onep.x, onep.y*onep.y);
    cf inv1p = make_float2(onep.x*ii, -onep.y*ii);
    cf corr = cmul(k01, cmul(k10, inv1p));
    out[l] = cmul(cc, csub(k00, corr));
  }
  if (chunk == 7 && tid == 255){
    cf s00 = make_float2(0.f, 0.f);
    for (int n = 0; n < 64; ++n) s00 = cadd(s00, w00[n]);
    out[2048] = cscale(s00, 0.5f * step);
  }
}

// ---------------------------------------------------------------------------
// Kernel 1b: odd bins. KdO[d][m] = FFT4096( Re(K[n]) e^{-i pi n/4096} )[m].
__global__ __launch_bounds__(256)
void fft_kd(const float* __restrict__ KdE, float* __restrict__ KdO){
  __shared__ cf L[4096];
  const int d = blockIdx.x, t = threadIdx.x;
  const cf* kdE = (const cf*)KdE + (size_t)d * 2049;
  cf* kdO = (cf*)KdO + (size_t)d * 2048;
  cf v[16];
  const float inv = 1.0f / 4096.0f;
  #pragma unroll
  for (int n1 = 0; n1 < 16; ++n1){
    int m = n1*256 + t;
    cf a = (m <= 2048) ? kdE[m] : cconj(kdE[4096 - m]);
    v[n1] = cscale(a, inv);
  }
  fft4096_reg<+1>(v, L);               // K (real part)
  const int k1 = t >> 4, ka = t & 15;
  const int xb = (k1 ^ ka) + 16*ka;    // folded SW for k1+16ka+256kb
  const int swt = t ^ k1;
  __syncthreads();
  #pragma unroll
  for (int kb = 0; kb < 16; ++kb){
    int g = k1 + 16*ka + 256*kb;
    float kr = v[RI(kb)].x;
    float sn, cs; __sincosf(-7.669903939428206e-4f * (float)g, &sn, &cs);
    L[xb + 256*kb] = make_float2(kr*cs, kr*sn);
  }
  __syncthreads();
  #pragma unroll
  for (int n1 = 0; n1 < 16; ++n1) v[n1] = L[swt + n1*256];
  fft4096_reg<-1>(v, L);
  #pragma unroll
  for (int kb = 0; kb < 8; ++kb)
    kdO[k1 + 16*ka + 256*kb] = v[RI(kb)];
}

// ---------------------------------------------------------------------------
// Kernel 2: tiled transpose u[B][L][D] -> ut[(b*256+d)][L]
__global__ __launch_bounds__(256)
void transpose_u(const float* __restrict__ u, float* __restrict__ ut){
  __shared__ float tile[32][33];
  const int b  = blockIdx.z;
  const int l0 = blockIdx.x * 32;
  const int d0 = blockIdx.y * 32;
  const int tx = threadIdx.x & 31;
  const int ty = threadIdx.x >> 5;
  const float* ub = u + (size_t)b * 4096 * 256;
  #pragma unroll
  for (int it = 0; it < 4; ++it){
    int l = l0 + ty + it*8;
    tile[tx][ty + it*8] = ub[(size_t)l*256 + d0 + tx];
  }
  __syncthreads();
  float* utb = ut + (size_t)b * 256 * 4096;
  #pragma unroll
  for (int it = 0; it < 4; ++it){
    int dd = d0 + ty + it*8;
    utb[(size_t)dd*4096 + l0 + tx] = tile[ty + it*8][tx];
  }
}

// ---------------------------------------------------------------------------
// Fast exact-GELU: Phi via A&S 7.1.26 erfc (|err| < 1.5e-7), ~12 VALU ops.
__device__ __forceinline__ float gelu_exact(float x){
  float z = fabsf(x) * 0.70710678118654752f;
  float tt = __builtin_amdgcn_rcpf(fmaf(0.3275911f, z, 1.0f));
  float poly = fmaf(fmaf(fmaf(fmaf(1.061405429f, tt, -1.453152027f), tt,
                    1.421413741f), tt, -0.284496736f), tt, 0.254829592f) * tt;
  float ec = poly * __expf(-z*z);          // erfc(z)
  float phi = (x >= 0.f) ? fmaf(-0.5f, ec, 1.0f) : 0.5f * ec;
  return x * phi;
}

// ---------------------------------------------------------------------------
// Kernel 3: per-(b,d) non-circular conv via packed real-FFT; fuses
// skip + GELU and writes bf16 Z overlaying the row's own storage.
__global__ __launch_bounds__(256)
void s4_conv(float* __restrict__ ut, const float* __restrict__ KdE,
             const float* __restrict__ KdO, const float* __restrict__ Dsk){
  __shared__ cf L[4096];
  const int row = blockIdx.x;           // b*256 + d
  const int d   = row & 255;
  const int t   = threadIdx.x;
  float2* rp = (float2*)(ut + (size_t)row * 4096);
  const float dskd = Dsk[d];

  cf v[16], uin[8];
  #pragma unroll
  for (int n1 = 0; n1 < 8; ++n1){ uin[n1] = rp[n1*256 + t]; v[n1] = uin[n1]; }
  #pragma unroll
  for (int n1 = 8; n1 < 16; ++n1) v[n1] = make_float2(0.f, 0.f);

  fft4096_reg<-1>(v, L);                // Z
  const int k1 = t >> 4, ka = t & 15;
  const int xb  = (k1 ^ ka) + 16*ka;    // folded SW for k1+16ka+256kb
  const int swt = t ^ k1;               // SW(t)
  const int t2  = 256 - t;
  const int swt2 = t2 ^ ((t2 >> 4) & 15);
  __syncthreads();
  #pragma unroll
  for (int kb = 0; kb < 16; ++kb)
    L[xb + 256*kb] = v[RI(kb)];
  __syncthreads();

  const cf* kdE = (const cf*)KdE + (size_t)d * 2049;
  const cf* kdO = (const cf*)KdO + (size_t)d * 2048;
  #pragma unroll
  for (int m = 0; m < 8; ++m){
    int k = t + m*256;                  // 0..2047
    if (k == 0){
      cf z0 = L[0];
      float U0 = z0.x + z0.y, UN = z0.x - z0.y;
      cf P0 = cscale(kdE[0], U0);
      cf PN = cscale(kdE[2048], UN);
      cf cPN = cconj(PN);
      cf Ep = cscale(cadd(P0, cPN), 0.5f);
      cf Op = cscale(csub(P0, cPN), 0.5f);
      L[0] = make_float2(Ep.x - Op.y, Ep.y + Op.x);
      cf P = cmul(cconj(L[2048]), kdE[1024]);
      L[2048] = cconj(P);
    } else {
      cf zk = L[swt + m*256];
      cf zj = L[(15 - m)*256 + swt2];
      cf E = make_float2(0.5f*(zk.x + zj.x),  0.5f*(zk.y - zj.y));
      cf O = make_float2(0.5f*(zk.y + zj.y), -0.5f*(zk.x - zj.x));
      float phi = 7.669903939428206e-4f * (float)k;     // pi*k/4096
      float sn, cs; __sincosf(phi, &sn, &cs);
      cf tw = make_float2(cs, -sn);
      cf tO = cmul(tw, O);
      cf Uk = cadd(E, tO);
      cf Uj = cconj(csub(E, tO));                        // U[4096-k]
      int h = k >> 1;
      cf kk, kj;
      if (k & 1){ kk = kdO[h]; kj = kdO[2047 - h]; }
      else      { kk = kdE[h]; kj = kdE[2048 - h]; }
      cf Pk = cmul(Uk, kk);
      cf Pj = cmul(Uj, kj);
      cf cPj = cconj(Pj), cPk = cconj(Pk);
      cf tp  = make_float2(cs, sn);
      cf Ek = cscale(cadd(Pk, cPj), 0.5f);
      cf Ok = cmul(tp, cscale(csub(Pk, cPj), 0.5f));
      L[swt + m*256] = make_float2(Ek.x - Ok.y, Ek.y + Ok.x);
      cf tpj = make_float2(-cs, sn);
      cf Ej = cscale(cadd(Pj, cPk), 0.5f);
      cf Oj = cmul(tpj, cscale(csub(Pj, cPk), 0.5f));
      L[(15 - m)*256 + swt2] = make_float2(Ej.x - Oj.y, Ej.y + Oj.x);
    }
  }
  __syncthreads();

  #pragma unroll
  for (int n1 = 0; n1 < 16; ++n1) v[n1] = L[swt + n1*256];
  fft4096_reg<+1>(v, L);

  // conv tokens -> LDS reorder -> align with uin layout -> gelu -> bf16
  __syncthreads();
  #pragma unroll
  for (int kb = 0; kb < 8; ++kb)
    L[xb + 256*kb] = v[RI(kb)];
  __syncthreads();
  const float inv = 1.0f / 4096.0f;
  unsigned* og = (unsigned*)rp;         // bf16 overlay (2 tokens / dword)
  #pragma unroll
  for (int n1 = 0; n1 < 8; ++n1){
    cf cv = L[swt + n1*256];
    float x0 = fmaf(dskd, uin[n1].x, cv.x * inv);
    float x1 = fmaf(dskd, uin[n1].y, cv.y * inv);
    unsigned b0 = (unsigned)(unsigned short)f2bf(gelu_exact(x0));
    unsigned b1 = (unsigned)(unsigned short)f2bf(gelu_exact(x1));
    og[n1*256 + t] = b0 | (b1 << 16);
  }
}

// ---------------------------------------------------------------------------
// Kernel 0: W[f][k] f32 -> Wb[f][k] bf16 (MFMA A-operand layout).
__global__ __launch_bounds__(256)
void convert_w(const float* __restrict__ W, short* __restrict__ Wb){
  int i = (blockIdx.x * 256 + threadIdx.x) * 4;
  float4 w = *(const float4*)(W + i);
  short4 o;
  o.x = f2bf(w.x); o.y = f2bf(w.y); o.z = f2bf(w.z); o.w = f2bf(w.w);
  *(short4*)(Wb + i) = o;
}

// ---------------------------------------------------------------------------
// Kernel 5: X = Z @ W^T + b + u ; LayerNorm -> out.  Z read as bf16 from the
// ut overlay ([k][token], row stride 16384 B).  Double-buffered 8 KB St tiles,
// XOR-swizzled; A = W rows (features), B = Z (tokens) -> in-lane LN.
__global__ __launch_bounds__(256)
void mfma_gemm_ln(const float* __restrict__ utg, const short* __restrict__ Wb,
                  const float* __restrict__ bias, const float* __restrict__ u,
                  const float* __restrict__ gamma, const float* __restrict__ beta,
                  float* __restrict__ out){
  __shared__ short St[2][64][64];
  __shared__ float prm[3][256];
  const int w    = threadIdx.x >> 6;
  const int l    = threadIdx.x & 63;
  const int lm   = l & 15;
  const int lk   = l >> 4;
  const int tokB = blockIdx.x * 64;   // never straddles batch (64 | 4096)
  const int b    = tokB >> 12;
  const int l0   = tokB & 4095;

  prm[0][threadIdx.x] = bias[threadIdx.x];
  prm[1][threadIdx.x] = gamma[threadIdx.x];
  prm[2][threadIdx.x] = beta[threadIdx.x];

  const int srow = (l >> 3);
  const int sg8  = l & 7;
  const char* ubase = (const char*)utg + (size_t)(b * 256) * 16384;

  bf16x8 pre[2];
  #pragma unroll
  for (int it = 0; it < 2; ++it){
    int r = w*16 + it*8 + srow;
    pre[it] = *(const bf16x8*)((const unsigned short*)(ubase + (size_t)r * 16384) + l0 + sg8*8);
  }

  f32x4 acc[16];
  #pragma unroll
  for (int nt = 0; nt < 16; ++nt) acc[nt] = (f32x4){0.f, 0.f, 0.f, 0.f};

  const int tg  = (w*16 + lm) >> 3;
  const int tlo = lm & 7;

  for (int c = 0; c < 4; ++c){
    const int buf = c & 1;
    #pragma unroll
    for (int it = 0; it < 2; ++it){
      int r = w*16 + it*8 + srow;
      int sl = (sg8 ^ ((r >> 3) & 7)) * 8;
      *(bf16x8*)&St[buf][r][sl] = pre[it];
    }
    __syncthreads();
    if (c < 3){
      #pragma unroll
      for (int it = 0; it < 2; ++it){
        int r = w*16 + it*8 + srow;
        pre[it] = *(const bf16x8*)((const unsigned short*)(ubase + (size_t)((c+1)*64 + r) * 16384) + l0 + sg8*8);
      }
    }
    #pragma unroll
    for (int s2 = 0; s2 < 2; ++s2){
      const int ks  = c*2 + s2;
      const int p   = (s2*4 + lk) & 7;
      const int idx = ((tg ^ p) << 3) | tlo;
      bf16x8 zf;
      #pragma unroll
      for (int j = 0; j < 8; ++j)
        zf[j] = St[buf][s2*32 + lk*8 + j][idx];
      #pragma unroll
      for (int nt = 0; nt < 16; ++nt){
        const bf16x8* ap = (const bf16x8*)(Wb + (size_t)(nt*16 + lm)*256 + ks*32 + lk*8);
        acc[nt] = __builtin_amdgcn_mfma_f32_16x16x32_bf16(*ap, zf, acc[nt], 0, 0, 0);
      }
    }
    __syncthreads();
  }

  const int tt = tokB + w*16 + lm;
  const float* ur = u + (size_t)tt * 256;
  float s = 0.f, s2 = 0.f;
  #pragma unroll
  for (int nt = 0; nt < 16; ++nt){
    const int f0 = nt*16 + lk*4;
    const float4 uv = *(const float4*)(ur + f0);
    const float4 bv = *(const float4*)&prm[0][f0];
    acc[nt][0] += bv.x + uv.x;
    acc[nt][1] += bv.y + uv.y;
    acc[nt][2] += bv.z + uv.z;
    acc[nt][3] += bv.w + uv.w;
    s += acc[nt][0] + acc[nt][1] + acc[nt][2] + acc[nt][3];
    s2 = fmaf(acc[nt][0], acc[nt][0], s2);
    s2 = fmaf(acc[nt][1], acc[nt][1], s2);
    s2 = fmaf(acc[nt][2], acc[nt][2], s2);
    s2 = fmaf(acc[nt][3], acc[nt][3], s2);
  }
  s  += __shfl_xor(s,  16); s  += __shfl_xor(s,  32);
  s2 += __shfl_xor(s2, 16); s2 += __shfl_xor(s2, 32);
  const float mu = s * (1.0f/256.0f);
  const float rs = rsqrtf(s2 * (1.0f/256.0f) - mu*mu + 1e-5f);
  float* orow = out + (size_t)tt * 256;
  #pragma unroll
  for (int nt = 0; nt < 16; ++nt){
    const int f0 = nt*16 + lk*4;
    const float4 gv = *(const float4*)&prm[1][f0];
    const float4 ev = *(const float4*)&prm[2][f0];
    float4 o;
    o.x = (acc[nt][0] - mu) * rs * gv.x + ev.x;
    o.y = (acc[nt][1] - mu) * rs * gv.y + ev.y;
    o.z = (acc[nt][2] - mu) * rs * gv.z + ev.z;
    o.w = (acc[nt][3] - mu) * rs * gv.w + ev.w;
    *(float4*)(orow + f0) = o;
  }
}

// ---------------------------------------------------------------------------
extern "C" void kernel_launch(void* const* d_in, const int* in_sizes, int n_in,
                              void* d_out, int out_size, void* d_ws, size_t ws_size,
                              hipStream_t stream){
  (void)in_sizes; (void)n_in; (void)out_size; (void)ws_size;
  const float* u        = (const float*)d_in[0];
  const float* B_ri     = (const float*)d_in[1];
  const float* Ct_ri    = (const float*)d_in[2];
  const float* lam_ri   = (const float*)d_in[3];
  const float* p_ri     = (const float*)d_in[4];
  const float* q_ri     = (const float*)d_in[5];
  const float* log_step = (const float*)d_in[6];
  const float* D_skip   = (const float*)d_in[7];
  const float* W        = (const float*)d_in[8];
  const float* bias     = (const float*)d_in[9];
  const float* gamma    = (const float*)d_in[10];
  const float* beta     = (const float*)d_in[11];
  float* out = (float*)d_out;

  // Workspace: KdE 4,196,352 | KdO 4,194,304 | Wb 131,072 | ut 33,554,432
  char* ws = (char*)d_ws;
  float* KdE = (float*)(ws);
  float* KdO = (float*)(ws + 4196352);
  short* Wb  = (short*)(ws + 4196352 + 4194304);
  float* ut  = (float*)(ws + 4196352 + 4194304 + 131072);

  convert_w   <<<64,              256, 0, stream>>>(W, Wb);
  cauchy_ar   <<<2048,            256, 0, stream>>>(B_ri, Ct_ri, lam_ri, p_ri, q_ri, log_step, KdE);
  fft_kd      <<<256,             256, 0, stream>>>(KdE, KdO);
  transpose_u <<<dim3(128, 8, 8), 256, 0, stream>>>(u, ut);
  s4_conv     <<<2048,            256, 0, stream>>>(ut, KdE, KdO, D_skip);
  mfma_gemm_ln<<<512,             256, 0, stream>>>(ut, Wb, bias, u, gamma, beta, out);
}

// Round 9
// 140.248 us; speedup vs baseline: 2.5991x; 1.0013x over previous
//
#include <hip/hip_runtime.h>
#include <math.h>

// S4 block: Cauchy (Hermitian-half) + even-bin identity + register four-step
// FFTs (16x16x16, template-DIR, tree twiddles, folded swizzle addressing);
// s4_conv fuses skip+GELU (fast erf) -> bf16; GEMM+LN pure bf16 MFMA with
// 32-token blocks and upfront load issue.  B=8, L=4096, D=256, N=64.

typedef float2 cf;
typedef __attribute__((ext_vector_type(8))) short bf16x8;
typedef __attribute__((ext_vector_type(4))) float f32x4;

__device__ __forceinline__ cf cmul(cf a, cf b){
  return make_float2(fmaf(a.x, b.x, -a.y*b.y), fmaf(a.x, b.y, a.y*b.x));
}
__device__ __forceinline__ cf cadd(cf a, cf b){ return make_float2(a.x+b.x, a.y+b.y); }
__device__ __forceinline__ cf csub(cf a, cf b){ return make_float2(a.x-b.x, a.y-b.y); }
__device__ __forceinline__ cf cscale(cf a, float s){ return make_float2(a.x*s, a.y*s); }
__device__ __forceinline__ cf cconj(cf a){ return make_float2(a.x, -a.y); }

__device__ __forceinline__ short f2bf(float x){   // RNE float->bf16
  union { float f; unsigned u; } v; v.f = x;
  unsigned r = v.u + 0x7fffu + ((v.u >> 16) & 1u);
  return (short)(r >> 16);
}

__device__ __forceinline__ int SW(int i){ return i ^ ((i >> 4) & 15); }
__device__ __forceinline__ constexpr int RI(int k){ return ((k & 3) << 2) | (k >> 2); }

#define C8 0.92387953251f
#define S8 0.38268343236f
#define RH 0.70710678119f

template<int DIR>
__device__ __forceinline__ void r4(cf& a, cf& b, cf& c, cf& d){
  cf T0 = cadd(a, c), T1 = csub(a, c);
  cf T2 = cadd(b, d), Bd = csub(b, d);
  cf T3 = (DIR > 0) ? make_float2(-Bd.y, Bd.x) : make_float2(Bd.y, -Bd.x);
  a = cadd(T0, T2); b = cadd(T1, T3); c = csub(T0, T2); d = csub(T1, T3);
}

template<int DIR>
__device__ __forceinline__ void fft16(cf* v){
  r4<DIR>(v[0], v[4], v[8],  v[12]);
  r4<DIR>(v[1], v[5], v[9],  v[13]);
  r4<DIR>(v[2], v[6], v[10], v[14]);
  r4<DIR>(v[3], v[7], v[11], v[15]);
  constexpr float D = (float)DIR;
  const cf w1 = make_float2(C8,  D*S8);
  const cf w2 = make_float2(RH,  D*RH);
  const cf w3 = make_float2(S8,  D*C8);
  const cf w6 = make_float2(-RH, D*RH);
  const cf w9 = make_float2(-C8, -D*S8);
  v[5]  = cmul(v[5],  w1);
  v[6]  = cmul(v[6],  w2);
  v[7]  = cmul(v[7],  w3);
  v[9]  = cmul(v[9],  w2);
  v[10] = make_float2(-D*v[10].y, D*v[10].x);
  v[11] = cmul(v[11], w6);
  v[13] = cmul(v[13], w3);
  v[14] = cmul(v[14], w6);
  v[15] = cmul(v[15], w9);
  r4<DIR>(v[0],  v[1],  v[2],  v[3]);
  r4<DIR>(v[4],  v[5],  v[6],  v[7]);
  r4<DIR>(v[8],  v[9],  v[10], v[11]);
  r4<DIR>(v[12], v[13], v[14], v[15]);
}

// 4096-pt FFT, four-step 16x(16x16).  Entry: v[n1] = x[n1*256 + t].
// Exit: V[k1+16*ka+256*kb] = v[RI(kb)], k1 = t>>4, ka = t&15.
template<int DIR>
__device__ void fft4096_reg(cf* v, cf* lds){
  const int t = threadIdx.x;
  const int k1 = t >> 4, m2 = t & 15;
  const int swt = t ^ k1;
  constexpr float D = (float)DIR;
  fft16<DIR>(v);
  float sn, cs;
  __sincosf(D * 1.5339807878856412e-3f * (float)t, &sn, &cs);   // 2pi/4096
  __syncthreads();
  {
    cf* p = lds + swt;
    cf w1 = make_float2(cs, sn);
    p[0]    = v[0];
    p[256]  = cmul(v[RI(1)],  w1);
    cf w2 = cmul(w1, w1);
    p[512]  = cmul(v[RI(2)],  w2);
    cf w3 = cmul(w2, w1);
    p[768]  = cmul(v[RI(3)],  w3);
    cf w4 = cmul(w2, w2);
    p[1024] = cmul(v[RI(4)],  w4);
    cf w5 = cmul(w4, w1);
    p[1280] = cmul(v[RI(5)],  w5);
    cf w6 = cmul(w4, w2);
    p[1536] = cmul(v[RI(6)],  w6);
    cf w7 = cmul(w4, w3);
    p[1792] = cmul(v[RI(7)],  w7);
    cf w8 = cmul(w4, w4);
    p[2048] = cmul(v[RI(8)],  w8);
    p[2304] = cmul(v[RI(9)],  cmul(w8, w1));
    p[2560] = cmul(v[RI(10)], cmul(w8, w2));
    p[2816] = cmul(v[RI(11)], cmul(w8, w3));
    p[3072] = cmul(v[RI(12)], cmul(w8, w4));
    p[3328] = cmul(v[RI(13)], cmul(w8, w5));
    p[3584] = cmul(v[RI(14)], cmul(w8, w6));
    p[3840] = cmul(v[RI(15)], cmul(w8, w7));
  }
  __syncthreads();
  {
    cf* p = lds + k1*256;
    #pragma unroll
    for (int m1 = 0; m1 < 16; ++m1) v[m1] = p[m1*16 + (m2 ^ m1)];
  }
  fft16<DIR>(v);
  __sincosf(D * 2.45436926061703e-2f * (float)m2, &sn, &cs);    // 2pi/256
  __syncthreads();
  {
    cf* p = lds + k1*256;
    cf w1 = make_float2(cs, sn);
    p[m2]              = v[0];
    p[16  + (m2^1)]    = cmul(v[RI(1)],  w1);
    cf w2 = cmul(w1, w1);
    p[32  + (m2^2)]    = cmul(v[RI(2)],  w2);
    cf w3 = cmul(w2, w1);
    p[48  + (m2^3)]    = cmul(v[RI(3)],  w3);
    cf w4 = cmul(w2, w2);
    p[64  + (m2^4)]    = cmul(v[RI(4)],  w4);
    cf w5 = cmul(w4, w1);
    p[80  + (m2^5)]    = cmul(v[RI(5)],  w5);
    cf w6 = cmul(w4, w2);
    p[96  + (m2^6)]    = cmul(v[RI(6)],  w6);
    cf w7 = cmul(w4, w3);
    p[112 + (m2^7)]    = cmul(v[RI(7)],  w7);
    cf w8 = cmul(w4, w4);
    p[128 + (m2^8)]    = cmul(v[RI(8)],  w8);
    p[144 + (m2^9)]    = cmul(v[RI(9)],  cmul(w8, w1));
    p[160 + (m2^10)]   = cmul(v[RI(10)], cmul(w8, w2));
    p[176 + (m2^11)]   = cmul(v[RI(11)], cmul(w8, w3));
    p[192 + (m2^12)]   = cmul(v[RI(12)], cmul(w8, w4));
    p[208 + (m2^13)]   = cmul(v[RI(13)], cmul(w8, w5));
    p[224 + (m2^14)]   = cmul(v[RI(14)], cmul(w8, w6));
    p[240 + (m2^15)]   = cmul(v[RI(15)], cmul(w8, w7));
  }
  __syncthreads();
  {
    const int ka = m2;
    cf* p = lds + k1*256 + ka*16;
    #pragma unroll
    for (int m2b = 0; m2b < 16; ++m2b) v[m2b] = p[m2b ^ ka];
  }
  fft16<DIR>(v);
}

// ---------------------------------------------------------------------------
// Kernel 1a: Cauchy generating function, Hermitian half (l = 0..2048).
__global__ __launch_bounds__(256)
void cauchy_ar(const float* __restrict__ B_ri, const float* __restrict__ Ct_ri,
               const float* __restrict__ lam_ri, const float* __restrict__ p_ri,
               const float* __restrict__ q_ri, const float* __restrict__ log_step,
               float* __restrict__ KdE){
  __shared__ cf w00[64], w01[64], w10[64], w11[64], lamS[64];
  const int d     = blockIdx.x >> 3;
  const int chunk = blockIdx.x & 7;
  const int tid   = threadIdx.x;
  const float step = expf(log_step[d]);

  if (tid < 64){
    int n = tid;
    cf Bv = make_float2(B_ri[(d*64+n)*2],  B_ri[(d*64+n)*2+1]);
    cf Cv = make_float2(Ct_ri[(d*64+n)*2], Ct_ri[(d*64+n)*2+1]);
    cf pv = make_float2(p_ri[n*2], p_ri[n*2+1]);
    cf qv = make_float2(q_ri[n*2], q_ri[n*2+1]);
    lamS[n] = make_float2(lam_ri[n*2], lam_ri[n*2+1]);
    cf Cc = cconj(Cv), qc = cconj(qv);
    w00[n] = cmul(Cc, Bv);
    w01[n] = cmul(Cc, pv);
    w10[n] = cmul(qc, Bv);
    w11[n] = cmul(qc, pv);
  }
  __syncthreads();

  cf* out = (cf*)KdE + (size_t)d * 2049;
  const int l = chunk * 256 + tid;               // 0..2047
  {
    float th = -(6.28318530717958647692f * (float)l) * (1.0f/4096.0f);
    float sn = sinf(th), cs = cosf(th);
    cf opw = make_float2(1.0f + cs,  sn);
    cf omw = make_float2(1.0f - cs, -sn);
    float idn = 1.0f / fmaf(opw.x, opw.x, opw.y*opw.y);
    cf ratio = make_float2((omw.x*opw.x + omw.y*opw.y)*idn,
                           (omw.y*opw.x - omw.x*opw.y)*idn);
    cf g  = cscale(ratio, 2.0f / step);
    cf cc = make_float2(2.0f*opw.x*idn, -2.0f*opw.y*idn);
    cf k00 = {0,0}, k01 = {0,0}, k10 = {0,0}, k11 = {0,0};
    #pragma unroll 4
    for (int n = 0; n < 64; ++n){
      cf lv  = lamS[n];
      cf den = make_float2(g.x - lv.x, g.y - lv.y);
      float is = 1.0f / fmaf(den.x, den.x, den.y*den.y);
      cf r = make_float2(den.x*is, -den.y*is);
      k00 = cadd(k00, cmul(w00[n], r));
      k01 = cadd(k01, cmul(w01[n], r));
      k10 = cadd(k10, cmul(w10[n], r));
      k11 = cadd(k11, cmul(w11[n], r));
    }
    cf onep = make_float2(1.0f + k11.x, k11.y);
    float ii = 1.0f / fmaf(onep.x, onep.x, onep.y*onep.y);
    cf inv1p = make_float2(onep.x*ii, -onep.y*ii);
    cf corr = cmul(k01, cmul(k10, inv1p));
    out[l] = cmul(cc, csub(k00, corr));
  }
  if (chunk == 7 && tid == 255){
    cf s00 = make_float2(0.f, 0.f);
    for (int n = 0; n < 64; ++n) s00 = cadd(s00, w00[n]);
    out[2048] = cscale(s00, 0.5f * step);
  }
}

// ---------------------------------------------------------------------------
// Kernel 1b: odd bins. KdO[d][m] = FFT4096( Re(K[n]) e^{-i pi n/4096} )[m].
__global__ __launch_bounds__(256)
void fft_kd(const float* __restrict__ KdE, float* __restrict__ KdO){
  __shared__ cf L[4096];
  const int d = blockIdx.x, t = threadIdx.x;
  const cf* kdE = (const cf*)KdE + (size_t)d * 2049;
  cf* kdO = (cf*)KdO + (size_t)d * 2048;
  cf v[16];
  const float inv = 1.0f / 4096.0f;
  #pragma unroll
  for (int n1 = 0; n1 < 16; ++n1){
    int m = n1*256 + t;
    cf a = (m <= 2048) ? kdE[m] : cconj(kdE[4096 - m]);
    v[n1] = cscale(a, inv);
  }
  fft4096_reg<+1>(v, L);
  const int k1 = t >> 4, ka = t & 15;
  const int xb = (k1 ^ ka) + 16*ka;
  const int swt = t ^ k1;
  __syncthreads();
  #pragma unroll
  for (int kb = 0; kb < 16; ++kb){
    int g = k1 + 16*ka + 256*kb;
    float kr = v[RI(kb)].x;
    float sn, cs; __sincosf(-7.669903939428206e-4f * (float)g, &sn, &cs);
    L[xb + 256*kb] = make_float2(kr*cs, kr*sn);
  }
  __syncthreads();
  #pragma unroll
  for (int n1 = 0; n1 < 16; ++n1) v[n1] = L[swt + n1*256];
  fft4096_reg<-1>(v, L);
  #pragma unroll
  for (int kb = 0; kb < 8; ++kb)
    kdO[k1 + 16*ka + 256*kb] = v[RI(kb)];
}

// ---------------------------------------------------------------------------
// Kernel 2: tiled transpose u[B][L][D] -> ut[(b*256+d)][L]
__global__ __launch_bounds__(256)
void transpose_u(const float* __restrict__ u, float* __restrict__ ut){
  __shared__ float tile[32][33];
  const int b  = blockIdx.z;
  const int l0 = blockIdx.x * 32;
  const int d0 = blockIdx.y * 32;
  const int tx = threadIdx.x & 31;
  const int ty = threadIdx.x >> 5;
  const float* ub = u + (size_t)b * 4096 * 256;
  #pragma unroll
  for (int it = 0; it < 4; ++it){
    int l = l0 + ty + it*8;
    tile[tx][ty + it*8] = ub[(size_t)l*256 + d0 + tx];
  }
  __syncthreads();
  float* utb = ut + (size_t)b * 256 * 4096;
  #pragma unroll
  for (int it = 0; it < 4; ++it){
    int dd = d0 + ty + it*8;
    utb[(size_t)dd*4096 + l0 + tx] = tile[ty + it*8][tx];
  }
}

// ---------------------------------------------------------------------------
// Fast exact-GELU: Phi via A&S 7.1.26 erfc (|err| < 1.5e-7).
__device__ __forceinline__ float gelu_exact(float x){
  float z = fabsf(x) * 0.70710678118654752f;
  float tt = __builtin_amdgcn_rcpf(fmaf(0.3275911f, z, 1.0f));
  float poly = fmaf(fmaf(fmaf(fmaf(1.061405429f, tt, -1.453152027f), tt,
                    1.421413741f), tt, -0.284496736f), tt, 0.254829592f) * tt;
  float ec = poly * __expf(-z*z);
  float phi = (x >= 0.f) ? fmaf(-0.5f, ec, 1.0f) : 0.5f * ec;
  return x * phi;
}

// ---------------------------------------------------------------------------
// Kernel 3: per-(b,d) non-circular conv via packed real-FFT; fuses
// skip + GELU and writes bf16 Z overlaying the row's own storage.
__global__ __launch_bounds__(256)
void s4_conv(float* __restrict__ ut, const float* __restrict__ KdE,
             const float* __restrict__ KdO, const float* __restrict__ Dsk){
  __shared__ cf L[4096];
  const int row = blockIdx.x;           // b*256 + d
  const int d   = row & 255;
  const int t   = threadIdx.x;
  float2* rp = (float2*)(ut + (size_t)row * 4096);
  const float dskd = Dsk[d];

  cf v[16], uin[8];
  #pragma unroll
  for (int n1 = 0; n1 < 8; ++n1){ uin[n1] = rp[n1*256 + t]; v[n1] = uin[n1]; }
  #pragma unroll
  for (int n1 = 8; n1 < 16; ++n1) v[n1] = make_float2(0.f, 0.f);

  fft4096_reg<-1>(v, L);                // Z
  const int k1 = t >> 4, ka = t & 15;
  const int xb  = (k1 ^ ka) + 16*ka;
  const int swt = t ^ k1;
  const int t2  = 256 - t;
  const int swt2 = t2 ^ ((t2 >> 4) & 15);
  __syncthreads();
  #pragma unroll
  for (int kb = 0; kb < 16; ++kb)
    L[xb + 256*kb] = v[RI(kb)];
  __syncthreads();

  const cf* kdE = (const cf*)KdE + (size_t)d * 2049;
  const cf* kdO = (const cf*)KdO + (size_t)d * 2048;
  #pragma unroll
  for (int m = 0; m < 8; ++m){
    int k = t + m*256;                  // 0..2047
    if (k == 0){
      cf z0 = L[0];
      float U0 = z0.x + z0.y, UN = z0.x - z0.y;
      cf P0 = cscale(kdE[0], U0);
      cf PN = cscale(kdE[2048], UN);
      cf cPN = cconj(PN);
      cf Ep = cscale(cadd(P0, cPN), 0.5f);
      cf Op = cscale(csub(P0, cPN), 0.5f);
      L[0] = make_float2(Ep.x - Op.y, Ep.y + Op.x);
      cf P = cmul(cconj(L[2048]), kdE[1024]);
      L[2048] = cconj(P);
    } else {
      cf zk = L[swt + m*256];
      cf zj = L[(15 - m)*256 + swt2];
      cf E = make_float2(0.5f*(zk.x + zj.x),  0.5f*(zk.y - zj.y));
      cf O = make_float2(0.5f*(zk.y + zj.y), -0.5f*(zk.x - zj.x));
      float phi = 7.669903939428206e-4f * (float)k;     // pi*k/4096
      float sn, cs; __sincosf(phi, &sn, &cs);
      cf tw = make_float2(cs, -sn);
      cf tO = cmul(tw, O);
      cf Uk = cadd(E, tO);
      cf Uj = cconj(csub(E, tO));
      int h = k >> 1;
      cf kk, kj;
      if (k & 1){ kk = kdO[h]; kj = kdO[2047 - h]; }
      else      { kk = kdE[h]; kj = kdE[2048 - h]; }
      cf Pk = cmul(Uk, kk);
      cf Pj = cmul(Uj, kj);
      cf cPj = cconj(Pj), cPk = cconj(Pk);
      cf tp  = make_float2(cs, sn);
      cf Ek = cscale(cadd(Pk, cPj), 0.5f);
      cf Ok = cmul(tp, cscale(csub(Pk, cPj), 0.5f));
      L[swt + m*256] = make_float2(Ek.x - Ok.y, Ek.y + Ok.x);
      cf tpj = make_float2(-cs, sn);
      cf Ej = cscale(cadd(Pj, cPk), 0.5f);
      cf Oj = cmul(tpj, cscale(csub(Pj, cPk), 0.5f));
      L[(15 - m)*256 + swt2] = make_float2(Ej.x - Oj.y, Ej.y + Oj.x);
    }
  }
  __syncthreads();

  #pragma unroll
  for (int n1 = 0; n1 < 16; ++n1) v[n1] = L[swt + n1*256];
  fft4096_reg<+1>(v, L);

  __syncthreads();
  #pragma unroll
  for (int kb = 0; kb < 8; ++kb)
    L[xb + 256*kb] = v[RI(kb)];
  __syncthreads();
  const float inv = 1.0f / 4096.0f;
  unsigned* og = (unsigned*)rp;         // bf16 overlay (2 tokens / dword)
  #pragma unroll
  for (int n1 = 0; n1 < 8; ++n1){
    cf cv = L[swt + n1*256];
    float x0 = fmaf(dskd, uin[n1].x, cv.x * inv);
    float x1 = fmaf(dskd, uin[n1].y, cv.y * inv);
    unsigned b0 = (unsigned)(unsigned short)f2bf(gelu_exact(x0));
    unsigned b1 = (unsigned)(unsigned short)f2bf(gelu_exact(x1));
    og[n1*256 + t] = b0 | (b1 << 16);
  }
}

// ---------------------------------------------------------------------------
// Kernel 0: W[f][k] f32 -> Wb[f][k] bf16 (MFMA A-operand layout).
__global__ __launch_bounds__(256)
void convert_w(const float* __restrict__ W, short* __restrict__ Wb){
  int i = (blockIdx.x * 256 + threadIdx.x) * 4;
  float4 w = *(const float4*)(W + i);
  short4 o;
  o.x = f2bf(w.x); o.y = f2bf(w.y); o.z = f2bf(w.z); o.w = f2bf(w.w);
  *(short4*)(Wb + i) = o;
}

// ---------------------------------------------------------------------------
// Kernel 5: X = Z @ W^T + b + u ; LayerNorm -> out.  32 tokens/block (grid
// 1024 -> 4 blocks/CU).  Per warp: 16 tokens ((w&1) half) x 128 features
// ((w>>1) half), acc[8].  All Z-chunk loads + u loads issued upfront.
// LN: in-warp shuffle (lk) + cross-warp LDS join (w ^ 2).
__global__ __launch_bounds__(256)
void mfma_gemm_ln(const float* __restrict__ utg, const short* __restrict__ Wb,
                  const float* __restrict__ bias, const float* __restrict__ u,
                  const float* __restrict__ gamma, const float* __restrict__ beta,
                  float* __restrict__ out){
  __shared__ short St[64][32];        // one k-chunk: 64 k x 32 tokens
  __shared__ float prm[3][256];
  __shared__ float2 red[2][2][16];    // [tok-half][feat-half][lm]
  const int w    = threadIdx.x >> 6;
  const int l    = threadIdx.x & 63;
  const int lm   = l & 15;
  const int lk   = l >> 4;
  const int tokB = blockIdx.x * 32;   // never straddles batch (32 | 4096)
  const int b    = tokB >> 12;
  const int l0   = tokB & 4095;

  prm[0][threadIdx.x] = bias[threadIdx.x];
  prm[1][threadIdx.x] = gamma[threadIdx.x];
  prm[2][threadIdx.x] = beta[threadIdx.x];

  // ---- issue ALL global loads up front ----
  const int srow = l >> 2;            // k-row within warp's 16 (0..15)
  const int tg   = l & 3;             // token-group of 8
  const char* ubase = (const char*)utg + (size_t)(b * 256) * 16384;
  bf16x8 pre[4];
  #pragma unroll
  for (int c = 0; c < 4; ++c){
    int r = c*64 + w*16 + srow;       // global k row
    pre[c] = *(const bf16x8*)((const unsigned short*)(ubase + (size_t)r * 16384) + l0 + tg*8);
  }
  const int th = (w & 1) * 16;        // token half
  const int fh = (w >> 1) * 128;      // feature half
  const int tt = tokB + th + lm;      // this lane's token
  const float* ur = u + (size_t)tt * 256 + fh;
  float4 uld[8];
  #pragma unroll
  for (int nt = 0; nt < 8; ++nt)
    uld[nt] = *(const float4*)(ur + nt*16 + lk*4);

  f32x4 acc[8];
  #pragma unroll
  for (int nt = 0; nt < 8; ++nt) acc[nt] = (f32x4){0.f, 0.f, 0.f, 0.f};

  const int tg_tok = (th + lm) >> 3;  // 0..3
  const int tlo    = lm & 7;

  #pragma unroll
  for (int c = 0; c < 4; ++c){
    __syncthreads();                  // St free (prev chunk's reads done)
    {
      int r  = w*16 + srow;           // k-row within chunk
      int sl = (tg ^ ((r >> 3) & 3)) * 8;
      *(bf16x8*)&St[r][sl] = pre[c];
    }
    __syncthreads();
    #pragma unroll
    for (int s2 = 0; s2 < 2; ++s2){
      const int ks  = c*2 + s2;
      const int idx = ((tg_tok ^ lk) << 3) | tlo;
      bf16x8 zf;
      #pragma unroll
      for (int j = 0; j < 8; ++j)
        zf[j] = St[s2*32 + lk*8 + j][idx];
      #pragma unroll
      for (int nt = 0; nt < 8; ++nt){
        const bf16x8* ap = (const bf16x8*)(Wb + (size_t)(fh + nt*16 + lm)*256 + ks*32 + lk*8);
        acc[nt] = __builtin_amdgcn_mfma_f32_16x16x32_bf16(*ap, zf, acc[nt], 0, 0, 0);
      }
    }
  }

  // epilogue: x = X + bias + u ; LN over 256 features (shuffle + LDS join)
  float s = 0.f, s2 = 0.f;
  #pragma unroll
  for (int nt = 0; nt < 8; ++nt){
    const int f0 = fh + nt*16 + lk*4;
    const float4 bv = *(const float4*)&prm[0][f0];
    acc[nt][0] += bv.x + uld[nt].x;
    acc[nt][1] += bv.y + uld[nt].y;
    acc[nt][2] += bv.z + uld[nt].z;
    acc[nt][3] += bv.w + uld[nt].w;
    s += acc[nt][0] + acc[nt][1] + acc[nt][2] + acc[nt][3];
    s2 = fmaf(acc[nt][0], acc[nt][0], s2);
    s2 = fmaf(acc[nt][1], acc[nt][1], s2);
    s2 = fmaf(acc[nt][2], acc[nt][2], s2);
    s2 = fmaf(acc[nt][3], acc[nt][3], s2);
  }
  s  += __shfl_xor(s,  16); s  += __shfl_xor(s,  32);   // sum over lk
  s2 += __shfl_xor(s2, 16); s2 += __shfl_xor(s2, 32);
  __syncthreads();                    // St reads done; reuse-safe for red
  if (lk == 0) red[w & 1][w >> 1][lm] = make_float2(s, s2);
  __syncthreads();
  const float2 pj = red[w & 1][(w >> 1) ^ 1][lm];
  const float st = s + pj.x, s2t = s2 + pj.y;
  const float mu = st * (1.0f/256.0f);
  const float rs = rsqrtf(s2t * (1.0f/256.0f) - mu*mu + 1e-5f);
  float* orow = out + (size_t)tt * 256 + fh;
  #pragma unroll
  for (int nt = 0; nt < 8; ++nt){
    const int f0 = fh + nt*16 + lk*4;
    const float4 gv = *(const float4*)&prm[1][f0];
    const float4 ev = *(const float4*)&prm[2][f0];
    float4 o;
    o.x = (acc[nt][0] - mu) * rs * gv.x + ev.x;
    o.y = (acc[nt][1] - mu) * rs * gv.y + ev.y;
    o.z = (acc[nt][2] - mu) * rs * gv.z + ev.z;
    o.w = (acc[nt][3] - mu) * rs * gv.w + ev.w;
    *(float4*)(orow + nt*16 + lk*4) = o;
  }
}

// ---------------------------------------------------------------------------
extern "C" void kernel_launch(void* const* d_in, const int* in_sizes, int n_in,
                              void* d_out, int out_size, void* d_ws, size_t ws_size,
                              hipStream_t stream){
  (void)in_sizes; (void)n_in; (void)out_size; (void)ws_size;
  const float* u        = (const float*)d_in[0];
  const float* B_ri     = (const float*)d_in[1];
  const float* Ct_ri    = (const float*)d_in[2];
  const float* lam_ri   = (const float*)d_in[3];
  const float* p_ri     = (const float*)d_in[4];
  const float* q_ri     = (const float*)d_in[5];
  const float* log_step = (const float*)d_in[6];
  const float* D_skip   = (const float*)d_in[7];
  const float* W        = (const float*)d_in[8];
  const float* bias     = (const float*)d_in[9];
  const float* gamma    = (const float*)d_in[10];
  const float* beta     = (const float*)d_in[11];
  float* out = (float*)d_out;

  // Workspace: KdE 4,196,352 | KdO 4,194,304 | Wb 131,072 | ut 33,554,432
  char* ws = (char*)d_ws;
  float* KdE = (float*)(ws);
  float* KdO = (float*)(ws + 4196352);
  short* Wb  = (short*)(ws + 4196352 + 4194304);
  float* ut  = (float*)(ws + 4196352 + 4194304 + 131072);

  convert_w   <<<64,              256, 0, stream>>>(W, Wb);
  cauchy_ar   <<<2048,            256, 0, stream>>>(B_ri, Ct_ri, lam_ri, p_ri, q_ri, log_step, KdE);
  fft_kd      <<<256,             256, 0, stream>>>(KdE, KdO);
  transpose_u <<<dim3(128, 8, 8), 256, 0, stream>>>(u, ut);
  s4_conv     <<<2048,            256, 0, stream>>>(ut, KdE, KdO, D_skip);
  mfma_gemm_ln<<<1024,            256, 0, stream>>>(ut, Wb, bias, u, gamma, beta, out);
}

// Round 10
// 124.761 us; speedup vs baseline: 2.9218x; 1.1241x over previous
//
#include <hip/hip_runtime.h>
#include <math.h>

// S4 block: Cauchy (Hermitian-half) + even-bin identity + register four-step
// FFTs (16x16x16); s4_conv fuses skip+GELU -> bf16 overlay; GEMM+LN bf16 MFMA
// with C-initialized accumulator (bias+u) and fragment-major W layout.
// B=8, L=4096, D=256, N=64.

typedef float2 cf;
typedef __attribute__((ext_vector_type(8))) short bf16x8;
typedef __attribute__((ext_vector_type(4))) float f32x4;

__device__ __forceinline__ cf cmul(cf a, cf b){
  return make_float2(fmaf(a.x, b.x, -a.y*b.y), fmaf(a.x, b.y, a.y*b.x));
}
__device__ __forceinline__ cf cadd(cf a, cf b){ return make_float2(a.x+b.x, a.y+b.y); }
__device__ __forceinline__ cf csub(cf a, cf b){ return make_float2(a.x-b.x, a.y-b.y); }
__device__ __forceinline__ cf cscale(cf a, float s){ return make_float2(a.x*s, a.y*s); }
__device__ __forceinline__ cf cconj(cf a){ return make_float2(a.x, -a.y); }

__device__ __forceinline__ short f2bf(float x){   // RNE float->bf16
  union { float f; unsigned u; } v; v.f = x;
  unsigned r = v.u + 0x7fffu + ((v.u >> 16) & 1u);
  return (short)(r >> 16);
}

__device__ __forceinline__ int SW(int i){ return i ^ ((i >> 4) & 15); }
__device__ __forceinline__ constexpr int RI(int k){ return ((k & 3) << 2) | (k >> 2); }

#define C8 0.92387953251f
#define S8 0.38268343236f
#define RH 0.70710678119f

template<int DIR>
__device__ __forceinline__ void r4(cf& a, cf& b, cf& c, cf& d){
  cf T0 = cadd(a, c), T1 = csub(a, c);
  cf T2 = cadd(b, d), Bd = csub(b, d);
  cf T3 = (DIR > 0) ? make_float2(-Bd.y, Bd.x) : make_float2(Bd.y, -Bd.x);
  a = cadd(T0, T2); b = cadd(T1, T3); c = csub(T0, T2); d = csub(T1, T3);
}

template<int DIR>
__device__ __forceinline__ void fft16(cf* v){
  r4<DIR>(v[0], v[4], v[8],  v[12]);
  r4<DIR>(v[1], v[5], v[9],  v[13]);
  r4<DIR>(v[2], v[6], v[10], v[14]);
  r4<DIR>(v[3], v[7], v[11], v[15]);
  constexpr float D = (float)DIR;
  const cf w1 = make_float2(C8,  D*S8);
  const cf w2 = make_float2(RH,  D*RH);
  const cf w3 = make_float2(S8,  D*C8);
  const cf w6 = make_float2(-RH, D*RH);
  const cf w9 = make_float2(-C8, -D*S8);
  v[5]  = cmul(v[5],  w1);
  v[6]  = cmul(v[6],  w2);
  v[7]  = cmul(v[7],  w3);
  v[9]  = cmul(v[9],  w2);
  v[10] = make_float2(-D*v[10].y, D*v[10].x);
  v[11] = cmul(v[11], w6);
  v[13] = cmul(v[13], w3);
  v[14] = cmul(v[14], w6);
  v[15] = cmul(v[15], w9);
  r4<DIR>(v[0],  v[1],  v[2],  v[3]);
  r4<DIR>(v[4],  v[5],  v[6],  v[7]);
  r4<DIR>(v[8],  v[9],  v[10], v[11]);
  r4<DIR>(v[12], v[13], v[14], v[15]);
}

// 4096-pt FFT, four-step 16x(16x16).  Entry: v[n1] = x[n1*256 + t].
// Exit: V[k1+16*ka+256*kb] = v[RI(kb)], k1 = t>>4, ka = t&15.
template<int DIR>
__device__ void fft4096_reg(cf* v, cf* lds){
  const int t = threadIdx.x;
  const int k1 = t >> 4, m2 = t & 15;
  const int swt = t ^ k1;
  constexpr float D = (float)DIR;
  fft16<DIR>(v);
  float sn, cs;
  __sincosf(D * 1.5339807878856412e-3f * (float)t, &sn, &cs);   // 2pi/4096
  __syncthreads();
  {
    cf* p = lds + swt;
    cf w1 = make_float2(cs, sn);
    p[0]    = v[0];
    p[256]  = cmul(v[RI(1)],  w1);
    cf w2 = cmul(w1, w1);
    p[512]  = cmul(v[RI(2)],  w2);
    cf w3 = cmul(w2, w1);
    p[768]  = cmul(v[RI(3)],  w3);
    cf w4 = cmul(w2, w2);
    p[1024] = cmul(v[RI(4)],  w4);
    cf w5 = cmul(w4, w1);
    p[1280] = cmul(v[RI(5)],  w5);
    cf w6 = cmul(w4, w2);
    p[1536] = cmul(v[RI(6)],  w6);
    cf w7 = cmul(w4, w3);
    p[1792] = cmul(v[RI(7)],  w7);
    cf w8 = cmul(w4, w4);
    p[2048] = cmul(v[RI(8)],  w8);
    p[2304] = cmul(v[RI(9)],  cmul(w8, w1));
    p[2560] = cmul(v[RI(10)], cmul(w8, w2));
    p[2816] = cmul(v[RI(11)], cmul(w8, w3));
    p[3072] = cmul(v[RI(12)], cmul(w8, w4));
    p[3328] = cmul(v[RI(13)], cmul(w8, w5));
    p[3584] = cmul(v[RI(14)], cmul(w8, w6));
    p[3840] = cmul(v[RI(15)], cmul(w8, w7));
  }
  __syncthreads();
  {
    cf* p = lds + k1*256;
    #pragma unroll
    for (int m1 = 0; m1 < 16; ++m1) v[m1] = p[m1*16 + (m2 ^ m1)];
  }
  fft16<DIR>(v);
  __sincosf(D * 2.45436926061703e-2f * (float)m2, &sn, &cs);    // 2pi/256
  __syncthreads();
  {
    cf* p = lds + k1*256;
    cf w1 = make_float2(cs, sn);
    p[m2]              = v[0];
    p[16  + (m2^1)]    = cmul(v[RI(1)],  w1);
    cf w2 = cmul(w1, w1);
    p[32  + (m2^2)]    = cmul(v[RI(2)],  w2);
    cf w3 = cmul(w2, w1);
    p[48  + (m2^3)]    = cmul(v[RI(3)],  w3);
    cf w4 = cmul(w2, w2);
    p[64  + (m2^4)]    = cmul(v[RI(4)],  w4);
    cf w5 = cmul(w4, w1);
    p[80  + (m2^5)]    = cmul(v[RI(5)],  w5);
    cf w6 = cmul(w4, w2);
    p[96  + (m2^6)]    = cmul(v[RI(6)],  w6);
    cf w7 = cmul(w4, w3);
    p[112 + (m2^7)]    = cmul(v[RI(7)],  w7);
    cf w8 = cmul(w4, w4);
    p[128 + (m2^8)]    = cmul(v[RI(8)],  w8);
    p[144 + (m2^9)]    = cmul(v[RI(9)],  cmul(w8, w1));
    p[160 + (m2^10)]   = cmul(v[RI(10)], cmul(w8, w2));
    p[176 + (m2^11)]   = cmul(v[RI(11)], cmul(w8, w3));
    p[192 + (m2^12)]   = cmul(v[RI(12)], cmul(w8, w4));
    p[208 + (m2^13)]   = cmul(v[RI(13)], cmul(w8, w5));
    p[224 + (m2^14)]   = cmul(v[RI(14)], cmul(w8, w6));
    p[240 + (m2^15)]   = cmul(v[RI(15)], cmul(w8, w7));
  }
  __syncthreads();
  {
    const int ka = m2;
    cf* p = lds + k1*256 + ka*16;
    #pragma unroll
    for (int m2b = 0; m2b < 16; ++m2b) v[m2b] = p[m2b ^ ka];
  }
  fft16<DIR>(v);
}

// ---------------------------------------------------------------------------
// Kernel 1a: Cauchy generating function, Hermitian half (l = 0..2048).
__global__ __launch_bounds__(256)
void cauchy_ar(const float* __restrict__ B_ri, const float* __restrict__ Ct_ri,
               const float* __restrict__ lam_ri, const float* __restrict__ p_ri,
               const float* __restrict__ q_ri, const float* __restrict__ log_step,
               float* __restrict__ KdE){
  __shared__ cf w00[64], w01[64], w10[64], w11[64], lamS[64];
  const int d     = blockIdx.x >> 3;
  const int chunk = blockIdx.x & 7;
  const int tid   = threadIdx.x;
  const float step = expf(log_step[d]);

  if (tid < 64){
    int n = tid;
    cf Bv = make_float2(B_ri[(d*64+n)*2],  B_ri[(d*64+n)*2+1]);
    cf Cv = make_float2(Ct_ri[(d*64+n)*2], Ct_ri[(d*64+n)*2+1]);
    cf pv = make_float2(p_ri[n*2], p_ri[n*2+1]);
    cf qv = make_float2(q_ri[n*2], q_ri[n*2+1]);
    lamS[n] = make_float2(lam_ri[n*2], lam_ri[n*2+1]);
    cf Cc = cconj(Cv), qc = cconj(qv);
    w00[n] = cmul(Cc, Bv);
    w01[n] = cmul(Cc, pv);
    w10[n] = cmul(qc, Bv);
    w11[n] = cmul(qc, pv);
  }
  __syncthreads();

  cf* out = (cf*)KdE + (size_t)d * 2049;
  const int l = chunk * 256 + tid;               // 0..2047
  {
    float th = -(6.28318530717958647692f * (float)l) * (1.0f/4096.0f);
    float sn = sinf(th), cs = cosf(th);
    cf opw = make_float2(1.0f + cs,  sn);
    cf omw = make_float2(1.0f - cs, -sn);
    float idn = 1.0f / fmaf(opw.x, opw.x, opw.y*opw.y);
    cf ratio = make_float2((omw.x*opw.x + omw.y*opw.y)*idn,
                           (omw.y*opw.x - omw.x*opw.y)*idn);
    cf g  = cscale(ratio, 2.0f / step);
    cf cc = make_float2(2.0f*opw.x*idn, -2.0f*opw.y*idn);
    cf k00 = {0,0}, k01 = {0,0}, k10 = {0,0}, k11 = {0,0};
    #pragma unroll 4
    for (int n = 0; n < 64; ++n){
      cf lv  = lamS[n];
      cf den = make_float2(g.x - lv.x, g.y - lv.y);
      float is = 1.0f / fmaf(den.x, den.x, den.y*den.y);
      cf r = make_float2(den.x*is, -den.y*is);
      k00 = cadd(k00, cmul(w00[n], r));
      k01 = cadd(k01, cmul(w01[n], r));
      k10 = cadd(k10, cmul(w10[n], r));
      k11 = cadd(k11, cmul(w11[n], r));
    }
    cf onep = make_float2(1.0f + k11.x, k11.y);
    float ii = 1.0f / fmaf(onep.x, onep.x, onep.y*onep.y);
    cf inv1p = make_float2(onep.x*ii, -onep.y*ii);
    cf corr = cmul(k01, cmul(k10, inv1p));
    out[l] = cmul(cc, csub(k00, corr));
  }
  if (chunk == 7 && tid == 255){
    cf s00 = make_float2(0.f, 0.f);
    for (int n = 0; n < 64; ++n) s00 = cadd(s00, w00[n]);
    out[2048] = cscale(s00, 0.5f * step);
  }
}

// ---------------------------------------------------------------------------
// Kernel 1b: odd bins. KdO[d][m] = FFT4096( Re(K[n]) e^{-i pi n/4096} )[m].
__global__ __launch_bounds__(256)
void fft_kd(const float* __restrict__ KdE, float* __restrict__ KdO){
  __shared__ cf L[4096];
  const int d = blockIdx.x, t = threadIdx.x;
  const cf* kdE = (const cf*)KdE + (size_t)d * 2049;
  cf* kdO = (cf*)KdO + (size_t)d * 2048;
  cf v[16];
  const float inv = 1.0f / 4096.0f;
  #pragma unroll
  for (int n1 = 0; n1 < 16; ++n1){
    int m = n1*256 + t;
    cf a = (m <= 2048) ? kdE[m] : cconj(kdE[4096 - m]);
    v[n1] = cscale(a, inv);
  }
  fft4096_reg<+1>(v, L);
  const int k1 = t >> 4, ka = t & 15;
  const int xb = (k1 ^ ka) + 16*ka;
  const int swt = t ^ k1;
  __syncthreads();
  #pragma unroll
  for (int kb = 0; kb < 16; ++kb){
    int g = k1 + 16*ka + 256*kb;
    float kr = v[RI(kb)].x;
    float sn, cs; __sincosf(-7.669903939428206e-4f * (float)g, &sn, &cs);
    L[xb + 256*kb] = make_float2(kr*cs, kr*sn);
  }
  __syncthreads();
  #pragma unroll
  for (int n1 = 0; n1 < 16; ++n1) v[n1] = L[swt + n1*256];
  fft4096_reg<-1>(v, L);
  #pragma unroll
  for (int kb = 0; kb < 8; ++kb)
    kdO[k1 + 16*ka + 256*kb] = v[RI(kb)];
}

// ---------------------------------------------------------------------------
// Kernel 2: tiled transpose u[B][L][D] -> ut[(b*256+d)][L]
__global__ __launch_bounds__(256)
void transpose_u(const float* __restrict__ u, float* __restrict__ ut){
  __shared__ float tile[32][33];
  const int b  = blockIdx.z;
  const int l0 = blockIdx.x * 32;
  const int d0 = blockIdx.y * 32;
  const int tx = threadIdx.x & 31;
  const int ty = threadIdx.x >> 5;
  const float* ub = u + (size_t)b * 4096 * 256;
  #pragma unroll
  for (int it = 0; it < 4; ++it){
    int l = l0 + ty + it*8;
    tile[tx][ty + it*8] = ub[(size_t)l*256 + d0 + tx];
  }
  __syncthreads();
  float* utb = ut + (size_t)b * 256 * 4096;
  #pragma unroll
  for (int it = 0; it < 4; ++it){
    int dd = d0 + ty + it*8;
    utb[(size_t)dd*4096 + l0 + tx] = tile[ty + it*8][tx];
  }
}

// ---------------------------------------------------------------------------
// Fast exact-GELU: Phi via A&S 7.1.26 erfc (|err| < 1.5e-7).
__device__ __forceinline__ float gelu_exact(float x){
  float z = fabsf(x) * 0.70710678118654752f;
  float tt = __builtin_amdgcn_rcpf(fmaf(0.3275911f, z, 1.0f));
  float poly = fmaf(fmaf(fmaf(fmaf(1.061405429f, tt, -1.453152027f), tt,
                    1.421413741f), tt, -0.284496736f), tt, 0.254829592f) * tt;
  float ec = poly * __expf(-z*z);
  float phi = (x >= 0.f) ? fmaf(-0.5f, ec, 1.0f) : 0.5f * ec;
  return x * phi;
}

// ---------------------------------------------------------------------------
// Kernel 3: per-(b,d) non-circular conv via packed real-FFT; fuses
// skip + GELU and writes bf16 Z overlaying the row's own storage.
__global__ __launch_bounds__(256)
void s4_conv(float* __restrict__ ut, const float* __restrict__ KdE,
             const float* __restrict__ KdO, const float* __restrict__ Dsk){
  __shared__ cf L[4096];
  const int row = blockIdx.x;           // b*256 + d
  const int d   = row & 255;
  const int t   = threadIdx.x;
  float2* rp = (float2*)(ut + (size_t)row * 4096);
  const float dskd = Dsk[d];

  cf v[16], uin[8];
  #pragma unroll
  for (int n1 = 0; n1 < 8; ++n1){ uin[n1] = rp[n1*256 + t]; v[n1] = uin[n1]; }
  #pragma unroll
  for (int n1 = 8; n1 < 16; ++n1) v[n1] = make_float2(0.f, 0.f);

  fft4096_reg<-1>(v, L);                // Z
  const int k1 = t >> 4, ka = t & 15;
  const int xb  = (k1 ^ ka) + 16*ka;
  const int swt = t ^ k1;
  const int t2  = 256 - t;
  const int swt2 = t2 ^ ((t2 >> 4) & 15);
  __syncthreads();
  #pragma unroll
  for (int kb = 0; kb < 16; ++kb)
    L[xb + 256*kb] = v[RI(kb)];
  __syncthreads();

  const cf* kdE = (const cf*)KdE + (size_t)d * 2049;
  const cf* kdO = (const cf*)KdO + (size_t)d * 2048;
  #pragma unroll
  for (int m = 0; m < 8; ++m){
    int k = t + m*256;                  // 0..2047
    if (k == 0){
      cf z0 = L[0];
      float U0 = z0.x + z0.y, UN = z0.x - z0.y;
      cf P0 = cscale(kdE[0], U0);
      cf PN = cscale(kdE[2048], UN);
      cf cPN = cconj(PN);
      cf Ep = cscale(cadd(P0, cPN), 0.5f);
      cf Op = cscale(csub(P0, cPN), 0.5f);
      L[0] = make_float2(Ep.x - Op.y, Ep.y + Op.x);
      cf P = cmul(cconj(L[2048]), kdE[1024]);
      L[2048] = cconj(P);
    } else {
      cf zk = L[swt + m*256];
      cf zj = L[(15 - m)*256 + swt2];
      cf E = make_float2(0.5f*(zk.x + zj.x),  0.5f*(zk.y - zj.y));
      cf O = make_float2(0.5f*(zk.y + zj.y), -0.5f*(zk.x - zj.x));
      float phi = 7.669903939428206e-4f * (float)k;     // pi*k/4096
      float sn, cs; __sincosf(phi, &sn, &cs);
      cf tw = make_float2(cs, -sn);
      cf tO = cmul(tw, O);
      cf Uk = cadd(E, tO);
      cf Uj = cconj(csub(E, tO));
      int h = k >> 1;
      cf kk, kj;
      if (k & 1){ kk = kdO[h]; kj = kdO[2047 - h]; }
      else      { kk = kdE[h]; kj = kdE[2048 - h]; }
      cf Pk = cmul(Uk, kk);
      cf Pj = cmul(Uj, kj);
      cf cPj = cconj(Pj), cPk = cconj(Pk);
      cf tp  = make_float2(cs, sn);
      cf Ek = cscale(cadd(Pk, cPj), 0.5f);
      cf Ok = cmul(tp, cscale(csub(Pk, cPj), 0.5f));
      L[swt + m*256] = make_float2(Ek.x - Ok.y, Ek.y + Ok.x);
      cf tpj = make_float2(-cs, sn);
      cf Ej = cscale(cadd(Pj, cPk), 0.5f);
      cf Oj = cmul(tpj, cscale(csub(Pj, cPk), 0.5f));
      L[(15 - m)*256 + swt2] = make_float2(Ej.x - Oj.y, Ej.y + Oj.x);
    }
  }
  __syncthreads();

  #pragma unroll
  for (int n1 = 0; n1 < 16; ++n1) v[n1] = L[swt + n1*256];
  fft4096_reg<+1>(v, L);

  __syncthreads();
  #pragma unroll
  for (int kb = 0; kb < 8; ++kb)
    L[xb + 256*kb] = v[RI(kb)];
  __syncthreads();
  const float inv = 1.0f / 4096.0f;
  unsigned* og = (unsigned*)rp;         // bf16 overlay (2 tokens / dword)
  #pragma unroll
  for (int n1 = 0; n1 < 8; ++n1){
    cf cv = L[swt + n1*256];
    float x0 = fmaf(dskd, uin[n1].x, cv.x * inv);
    float x1 = fmaf(dskd, uin[n1].y, cv.y * inv);
    unsigned b0 = (unsigned)(unsigned short)f2bf(gelu_exact(x0));
    unsigned b1 = (unsigned)(unsigned short)f2bf(gelu_exact(x1));
    og[n1*256 + t] = b0 | (b1 << 16);
  }
}

// ---------------------------------------------------------------------------
// Kernel 0: W[f][k] f32 -> Wbf fragment-major bf16:
// Wbf[((((ks*2 + fh2)*8 + nt)*4 + lk)*16 + lm)*8 + j], where
// f = fh2*128 + nt*16 + lm, k = ks*32 + lk*8 + j.
// Per-warp GEMM stream becomes linear; each instruction reads 1 KB contiguous.
__global__ __launch_bounds__(256)
void convert_w(const float* __restrict__ W, short* __restrict__ Wbf){
  int t  = blockIdx.x * 256 + threadIdx.x;    // 16384 threads
  int o4 = t * 4;                             // 4 shorts per thread
  int j   = o4 & 7;                           // 0 or 4
  int lm  = (o4 >> 3)  & 15;
  int lk  = (o4 >> 7)  & 3;
  int nt  = (o4 >> 9)  & 7;
  int fh2 = (o4 >> 12) & 1;
  int ks  = o4 >> 13;
  int f = fh2*128 + nt*16 + lm;
  int k = ks*32 + lk*8 + j;
  float4 wv = *(const float4*)(W + (size_t)f*256 + k);
  short4 o;
  o.x = f2bf(wv.x); o.y = f2bf(wv.y); o.z = f2bf(wv.z); o.w = f2bf(wv.w);
  *(short4*)(Wbf + o4) = o;
}

// ---------------------------------------------------------------------------
// Kernel 5: X = Z @ W^T + b + u ; LayerNorm -> out.  32 tokens/block (grid
// 1024).  acc C-INITIALIZED with (bias + u): u loads are a dependency of the
// first MFMA -> compiler cannot sink them; no epilogue load tail.
// Wbf fragment-major: per-instruction 1 KB contiguous.
__global__ __launch_bounds__(256)
void mfma_gemm_ln(const float* __restrict__ utg, const short* __restrict__ Wbf,
                  const float* __restrict__ bias, const float* __restrict__ u,
                  const float* __restrict__ gamma, const float* __restrict__ beta,
                  float* __restrict__ out){
  __shared__ short St[64][32];        // one k-chunk: 64 k x 32 tokens
  __shared__ float prm[2][256];       // gamma / beta
  __shared__ float2 red[2][2][16];    // [tok-half][feat-half][lm]
  const int w    = threadIdx.x >> 6;
  const int l    = threadIdx.x & 63;
  const int lm   = l & 15;
  const int lk   = l >> 4;
  const int tokB = blockIdx.x * 32;   // never straddles batch (32 | 4096)
  const int b    = tokB >> 12;
  const int l0   = tokB & 4095;

  prm[0][threadIdx.x] = gamma[threadIdx.x];
  prm[1][threadIdx.x] = beta[threadIdx.x];

  // ---- Z chunk loads (all 4 upfront) ----
  const int srow = l >> 2;            // k-row within warp's 16
  const int tg   = l & 3;             // token-group of 8
  const char* ubase = (const char*)utg + (size_t)(b * 256) * 16384;
  bf16x8 pre[4];
  #pragma unroll
  for (int c = 0; c < 4; ++c){
    int r = c*64 + w*16 + srow;
    pre[c] = *(const bf16x8*)((const unsigned short*)(ubase + (size_t)r * 16384) + l0 + tg*8);
  }

  // ---- C-init: acc = bias + u (forces u loads before first MFMA) ----
  const int th = (w & 1) * 16;        // token half
  const int fh2 = w >> 1;
  const int fh = fh2 * 128;           // feature half
  const int tt = tokB + th + lm;      // this lane's token
  const float* ur = u + (size_t)tt * 256 + fh;
  const float* br = bias + fh;
  f32x4 acc[8];
  #pragma unroll
  for (int nt = 0; nt < 8; ++nt){
    const float4 uv = *(const float4*)(ur + nt*16 + lk*4);
    const float4 bv = *(const float4*)(br + nt*16 + lk*4);
    acc[nt] = (f32x4){uv.x + bv.x, uv.y + bv.y, uv.z + bv.z, uv.w + bv.w};
  }

  const int tg_tok = (th + lm) >> 3;
  const int tlo    = lm & 7;

  #pragma unroll
  for (int c = 0; c < 4; ++c){
    __syncthreads();                  // St free (prev chunk's reads done)
    {
      int r  = w*16 + srow;
      int sl = (tg ^ ((r >> 3) & 3)) * 8;
      *(bf16x8*)&St[r][sl] = pre[c];
    }
    __syncthreads();
    #pragma unroll
    for (int s2 = 0; s2 < 2; ++s2){
      const int ks  = c*2 + s2;
      const int idx = ((tg_tok ^ lk) << 3) | tlo;
      bf16x8 zf;
      #pragma unroll
      for (int j = 0; j < 8; ++j)
        zf[j] = St[s2*32 + lk*8 + j][idx];
      const short* wbase = Wbf + (size_t)(ks*2 + fh2)*4096 + lk*128 + lm*8;
      #pragma unroll
      for (int nt = 0; nt < 8; ++nt){
        const bf16x8* ap = (const bf16x8*)(wbase + nt*512);
        acc[nt] = __builtin_amdgcn_mfma_f32_16x16x32_bf16(*ap, zf, acc[nt], 0, 0, 0);
      }
    }
  }

  // epilogue: LN over 256 features (shuffle over lk + cross-warp LDS join)
  float s = 0.f, s2 = 0.f;
  #pragma unroll
  for (int nt = 0; nt < 8; ++nt){
    s += acc[nt][0] + acc[nt][1] + acc[nt][2] + acc[nt][3];
    s2 = fmaf(acc[nt][0], acc[nt][0], s2);
    s2 = fmaf(acc[nt][1], acc[nt][1], s2);
    s2 = fmaf(acc[nt][2], acc[nt][2], s2);
    s2 = fmaf(acc[nt][3], acc[nt][3], s2);
  }
  s  += __shfl_xor(s,  16); s  += __shfl_xor(s,  32);
  s2 += __shfl_xor(s2, 16); s2 += __shfl_xor(s2, 32);
  __syncthreads();
  if (lk == 0) red[w & 1][fh2][lm] = make_float2(s, s2);
  __syncthreads();
  const float2 pj = red[w & 1][fh2 ^ 1][lm];
  const float st = s + pj.x, s2t = s2 + pj.y;
  const float mu = st * (1.0f/256.0f);
  const float rs = rsqrtf(s2t * (1.0f/256.0f) - mu*mu + 1e-5f);
  float* orow = out + (size_t)tt * 256 + fh;
  #pragma unroll
  for (int nt = 0; nt < 8; ++nt){
    const int f0 = fh + nt*16 + lk*4;
    const float4 gv = *(const float4*)&prm[0][f0];
    const float4 ev = *(const float4*)&prm[1][f0];
    float4 o;
    o.x = (acc[nt][0] - mu) * rs * gv.x + ev.x;
    o.y = (acc[nt][1] - mu) * rs * gv.y + ev.y;
    o.z = (acc[nt][2] - mu) * rs * gv.z + ev.z;
    o.w = (acc[nt][3] - mu) * rs * gv.w + ev.w;
    *(float4*)(orow + nt*16 + lk*4) = o;
  }
}

// ---------------------------------------------------------------------------
extern "C" void kernel_launch(void* const* d_in, const int* in_sizes, int n_in,
                              void* d_out, int out_size, void* d_ws, size_t ws_size,
                              hipStream_t stream){
  (void)in_sizes; (void)n_in; (void)out_size; (void)ws_size;
  const float* u        = (const float*)d_in[0];
  const float* B_ri     = (const float*)d_in[1];
  const float* Ct_ri    = (const float*)d_in[2];
  const float* lam_ri   = (const float*)d_in[3];
  const float* p_ri     = (const float*)d_in[4];
  const float* q_ri     = (const float*)d_in[5];
  const float* log_step = (const float*)d_in[6];
  const float* D_skip   = (const float*)d_in[7];
  const float* W        = (const float*)d_in[8];
  const float* bias     = (const float*)d_in[9];
  const float* gamma    = (const float*)d_in[10];
  const float* beta     = (const float*)d_in[11];
  float* out = (float*)d_out;

  // Workspace: KdE 4,196,352 | KdO 4,194,304 | Wbf 131,072 | ut 33,554,432
  char* ws = (char*)d_ws;
  float* KdE = (float*)(ws);
  float* KdO = (float*)(ws + 4196352);
  short* Wbf = (short*)(ws + 4196352 + 4194304);
  float* ut  = (float*)(ws + 4196352 + 4194304 + 131072);

  convert_w   <<<64,              256, 0, stream>>>(W, Wbf);
  cauchy_ar   <<<2048,            256, 0, stream>>>(B_ri, Ct_ri, lam_ri, p_ri, q_ri, log_step, KdE);
  fft_kd      <<<256,             256, 0, stream>>>(KdE, KdO);
  transpose_u <<<dim3(128, 8, 8), 256, 0, stream>>>(u, ut);
  s4_conv     <<<2048,            256, 0, stream>>>(ut, KdE, KdO, D_skip);
  mfma_gemm_ln<<<1024,            256, 0, stream>>>(ut, Wbf, bias, u, gamma, beta, out);
}

// Round 11
// 115.047 us; speedup vs baseline: 3.1685x; 1.0844x over previous
//
#include <hip/hip_runtime.h>
#include <math.h>

// S4 block: fused-head (Cauchy + W-convert), fused-mid (Kd-odd-bins FFT
// co-scheduled with u-transpose), s4_conv (reg FFTs + skip+GELU -> bf16
// overlay), MFMA GEMM+LN (C-init bias+u, fragment-major W).
// B=8, L=4096, D=256, N=64.

typedef float2 cf;
typedef __attribute__((ext_vector_type(8))) short bf16x8;
typedef __attribute__((ext_vector_type(4))) float f32x4;

__device__ __forceinline__ cf cmul(cf a, cf b){
  return make_float2(fmaf(a.x, b.x, -a.y*b.y), fmaf(a.x, b.y, a.y*b.x));
}
__device__ __forceinline__ cf cadd(cf a, cf b){ return make_float2(a.x+b.x, a.y+b.y); }
__device__ __forceinline__ cf csub(cf a, cf b){ return make_float2(a.x-b.x, a.y-b.y); }
__device__ __forceinline__ cf cscale(cf a, float s){ return make_float2(a.x*s, a.y*s); }
__device__ __forceinline__ cf cconj(cf a){ return make_float2(a.x, -a.y); }

__device__ __forceinline__ short f2bf(float x){   // RNE float->bf16
  union { float f; unsigned u; } v; v.f = x;
  unsigned r = v.u + 0x7fffu + ((v.u >> 16) & 1u);
  return (short)(r >> 16);
}

__device__ __forceinline__ int SW(int i){ return i ^ ((i >> 4) & 15); }
__device__ __forceinline__ constexpr int RI(int k){ return ((k & 3) << 2) | (k >> 2); }

#define C8 0.92387953251f
#define S8 0.38268343236f
#define RH 0.70710678119f

template<int DIR>
__device__ __forceinline__ void r4(cf& a, cf& b, cf& c, cf& d){
  cf T0 = cadd(a, c), T1 = csub(a, c);
  cf T2 = cadd(b, d), Bd = csub(b, d);
  cf T3 = (DIR > 0) ? make_float2(-Bd.y, Bd.x) : make_float2(Bd.y, -Bd.x);
  a = cadd(T0, T2); b = cadd(T1, T3); c = csub(T0, T2); d = csub(T1, T3);
}

template<int DIR>
__device__ __forceinline__ void fft16(cf* v){
  r4<DIR>(v[0], v[4], v[8],  v[12]);
  r4<DIR>(v[1], v[5], v[9],  v[13]);
  r4<DIR>(v[2], v[6], v[10], v[14]);
  r4<DIR>(v[3], v[7], v[11], v[15]);
  constexpr float D = (float)DIR;
  const cf w1 = make_float2(C8,  D*S8);
  const cf w2 = make_float2(RH,  D*RH);
  const cf w3 = make_float2(S8,  D*C8);
  const cf w6 = make_float2(-RH, D*RH);
  const cf w9 = make_float2(-C8, -D*S8);
  v[5]  = cmul(v[5],  w1);
  v[6]  = cmul(v[6],  w2);
  v[7]  = cmul(v[7],  w3);
  v[9]  = cmul(v[9],  w2);
  v[10] = make_float2(-D*v[10].y, D*v[10].x);
  v[11] = cmul(v[11], w6);
  v[13] = cmul(v[13], w3);
  v[14] = cmul(v[14], w6);
  v[15] = cmul(v[15], w9);
  r4<DIR>(v[0],  v[1],  v[2],  v[3]);
  r4<DIR>(v[4],  v[5],  v[6],  v[7]);
  r4<DIR>(v[8],  v[9],  v[10], v[11]);
  r4<DIR>(v[12], v[13], v[14], v[15]);
}

// 4096-pt FFT, four-step 16x(16x16).  Entry: v[n1] = x[n1*256 + t].
// Exit: V[k1+16*ka+256*kb] = v[RI(kb)], k1 = t>>4, ka = t&15.
template<int DIR>
__device__ void fft4096_reg(cf* v, cf* lds){
  const int t = threadIdx.x;
  const int k1 = t >> 4, m2 = t & 15;
  const int swt = t ^ k1;
  constexpr float D = (float)DIR;
  fft16<DIR>(v);
  float sn, cs;
  __sincosf(D * 1.5339807878856412e-3f * (float)t, &sn, &cs);   // 2pi/4096
  __syncthreads();
  {
    cf* p = lds + swt;
    cf w1 = make_float2(cs, sn);
    p[0]    = v[0];
    p[256]  = cmul(v[RI(1)],  w1);
    cf w2 = cmul(w1, w1);
    p[512]  = cmul(v[RI(2)],  w2);
    cf w3 = cmul(w2, w1);
    p[768]  = cmul(v[RI(3)],  w3);
    cf w4 = cmul(w2, w2);
    p[1024] = cmul(v[RI(4)],  w4);
    cf w5 = cmul(w4, w1);
    p[1280] = cmul(v[RI(5)],  w5);
    cf w6 = cmul(w4, w2);
    p[1536] = cmul(v[RI(6)],  w6);
    cf w7 = cmul(w4, w3);
    p[1792] = cmul(v[RI(7)],  w7);
    cf w8 = cmul(w4, w4);
    p[2048] = cmul(v[RI(8)],  w8);
    p[2304] = cmul(v[RI(9)],  cmul(w8, w1));
    p[2560] = cmul(v[RI(10)], cmul(w8, w2));
    p[2816] = cmul(v[RI(11)], cmul(w8, w3));
    p[3072] = cmul(v[RI(12)], cmul(w8, w4));
    p[3328] = cmul(v[RI(13)], cmul(w8, w5));
    p[3584] = cmul(v[RI(14)], cmul(w8, w6));
    p[3840] = cmul(v[RI(15)], cmul(w8, w7));
  }
  __syncthreads();
  {
    cf* p = lds + k1*256;
    #pragma unroll
    for (int m1 = 0; m1 < 16; ++m1) v[m1] = p[m1*16 + (m2 ^ m1)];
  }
  fft16<DIR>(v);
  __sincosf(D * 2.45436926061703e-2f * (float)m2, &sn, &cs);    // 2pi/256
  __syncthreads();
  {
    cf* p = lds + k1*256;
    cf w1 = make_float2(cs, sn);
    p[m2]              = v[0];
    p[16  + (m2^1)]    = cmul(v[RI(1)],  w1);
    cf w2 = cmul(w1, w1);
    p[32  + (m2^2)]    = cmul(v[RI(2)],  w2);
    cf w3 = cmul(w2, w1);
    p[48  + (m2^3)]    = cmul(v[RI(3)],  w3);
    cf w4 = cmul(w2, w2);
    p[64  + (m2^4)]    = cmul(v[RI(4)],  w4);
    cf w5 = cmul(w4, w1);
    p[80  + (m2^5)]    = cmul(v[RI(5)],  w5);
    cf w6 = cmul(w4, w2);
    p[96  + (m2^6)]    = cmul(v[RI(6)],  w6);
    cf w7 = cmul(w4, w3);
    p[112 + (m2^7)]    = cmul(v[RI(7)],  w7);
    cf w8 = cmul(w4, w4);
    p[128 + (m2^8)]    = cmul(v[RI(8)],  w8);
    p[144 + (m2^9)]    = cmul(v[RI(9)],  cmul(w8, w1));
    p[160 + (m2^10)]   = cmul(v[RI(10)], cmul(w8, w2));
    p[176 + (m2^11)]   = cmul(v[RI(11)], cmul(w8, w3));
    p[192 + (m2^12)]   = cmul(v[RI(12)], cmul(w8, w4));
    p[208 + (m2^13)]   = cmul(v[RI(13)], cmul(w8, w5));
    p[224 + (m2^14)]   = cmul(v[RI(14)], cmul(w8, w6));
    p[240 + (m2^15)]   = cmul(v[RI(15)], cmul(w8, w7));
  }
  __syncthreads();
  {
    const int ka = m2;
    cf* p = lds + k1*256 + ka*16;
    #pragma unroll
    for (int m2b = 0; m2b < 16; ++m2b) v[m2b] = p[m2b ^ ka];
  }
  fft16<DIR>(v);
}

// ---------------------------------------------------------------------------
// fused_head: blocks [0,2048) = Cauchy generating function (Hermitian half,
// even-bin identity -> KdE); blocks [2048,2112) = W f32->bf16 fragment-major.
__global__ __launch_bounds__(256)
void fused_head(const float* __restrict__ B_ri, const float* __restrict__ Ct_ri,
                const float* __restrict__ lam_ri, const float* __restrict__ p_ri,
                const float* __restrict__ q_ri, const float* __restrict__ log_step,
                float* __restrict__ KdE,
                const float* __restrict__ W, short* __restrict__ Wbf){
  __shared__ cf w00[64], w01[64], w10[64], w11[64], lamS[64];
  const int bid = blockIdx.x;
  const int tid = threadIdx.x;

  if (bid >= 2048){
    // ---- convert_w: fragment-major Wbf ----
    int t  = (bid - 2048) * 256 + tid;          // 16384 threads
    int o4 = t * 4;
    int j   = o4 & 7;
    int lm  = (o4 >> 3)  & 15;
    int lk  = (o4 >> 7)  & 3;
    int nt  = (o4 >> 9)  & 7;
    int fh2 = (o4 >> 12) & 1;
    int ks  = o4 >> 13;
    int f = fh2*128 + nt*16 + lm;
    int k = ks*32 + lk*8 + j;
    float4 wv = *(const float4*)(W + (size_t)f*256 + k);
    short4 o;
    o.x = f2bf(wv.x); o.y = f2bf(wv.y); o.z = f2bf(wv.z); o.w = f2bf(wv.w);
    *(short4*)(Wbf + o4) = o;
    return;
  }

  // ---- cauchy_ar ----
  const int d     = bid >> 3;
  const int chunk = bid & 7;
  const float step = expf(log_step[d]);

  if (tid < 64){
    int n = tid;
    cf Bv = make_float2(B_ri[(d*64+n)*2],  B_ri[(d*64+n)*2+1]);
    cf Cv = make_float2(Ct_ri[(d*64+n)*2], Ct_ri[(d*64+n)*2+1]);
    cf pv = make_float2(p_ri[n*2], p_ri[n*2+1]);
    cf qv = make_float2(q_ri[n*2], q_ri[n*2+1]);
    lamS[n] = make_float2(lam_ri[n*2], lam_ri[n*2+1]);
    cf Cc = cconj(Cv), qc = cconj(qv);
    w00[n] = cmul(Cc, Bv);
    w01[n] = cmul(Cc, pv);
    w10[n] = cmul(qc, Bv);
    w11[n] = cmul(qc, pv);
  }
  __syncthreads();

  cf* out = (cf*)KdE + (size_t)d * 2049;
  const int l = chunk * 256 + tid;               // 0..2047
  {
    float th = -(6.28318530717958647692f * (float)l) * (1.0f/4096.0f);
    float sn = sinf(th), cs = cosf(th);
    cf opw = make_float2(1.0f + cs,  sn);
    cf omw = make_float2(1.0f - cs, -sn);
    float idn = 1.0f / fmaf(opw.x, opw.x, opw.y*opw.y);
    cf ratio = make_float2((omw.x*opw.x + omw.y*opw.y)*idn,
                           (omw.y*opw.x - omw.x*opw.y)*idn);
    cf g  = cscale(ratio, 2.0f / step);
    cf cc = make_float2(2.0f*opw.x*idn, -2.0f*opw.y*idn);
    cf k00 = {0,0}, k01 = {0,0}, k10 = {0,0}, k11 = {0,0};
    #pragma unroll 4
    for (int n = 0; n < 64; ++n){
      cf lv  = lamS[n];
      cf den = make_float2(g.x - lv.x, g.y - lv.y);
      float is = 1.0f / fmaf(den.x, den.x, den.y*den.y);
      cf r = make_float2(den.x*is, -den.y*is);
      k00 = cadd(k00, cmul(w00[n], r));
      k01 = cadd(k01, cmul(w01[n], r));
      k10 = cadd(k10, cmul(w10[n], r));
      k11 = cadd(k11, cmul(w11[n], r));
    }
    cf onep = make_float2(1.0f + k11.x, k11.y);
    float ii = 1.0f / fmaf(onep.x, onep.x, onep.y*onep.y);
    cf inv1p = make_float2(onep.x*ii, -onep.y*ii);
    cf corr = cmul(k01, cmul(k10, inv1p));
    out[l] = cmul(cc, csub(k00, corr));
  }
  if (chunk == 7 && tid == 255){
    cf s00 = make_float2(0.f, 0.f);
    for (int n = 0; n < 64; ++n) s00 = cadd(s00, w00[n]);
    out[2048] = cscale(s00, 0.5f * step);
  }
}

// ---------------------------------------------------------------------------
// fft_kd body (one d): odd bins KdO[d][m] = FFT4096(Re(K[n]) e^{-i pi n/4096})[m].
__device__ void fft_kd_body(int d, cf* L, const float* __restrict__ KdE,
                            float* __restrict__ KdO){
  const int t = threadIdx.x;
  const cf* kdE = (const cf*)KdE + (size_t)d * 2049;
  cf* kdO = (cf*)KdO + (size_t)d * 2048;
  cf v[16];
  const float inv = 1.0f / 4096.0f;
  #pragma unroll
  for (int n1 = 0; n1 < 16; ++n1){
    int m = n1*256 + t;
    cf a = (m <= 2048) ? kdE[m] : cconj(kdE[4096 - m]);
    v[n1] = cscale(a, inv);
  }
  fft4096_reg<+1>(v, L);
  const int k1 = t >> 4, ka = t & 15;
  const int xb = (k1 ^ ka) + 16*ka;
  const int swt = t ^ k1;
  __syncthreads();
  #pragma unroll
  for (int kb = 0; kb < 16; ++kb){
    int g = k1 + 16*ka + 256*kb;
    float kr = v[RI(kb)].x;
    float sn, cs; __sincosf(-7.669903939428206e-4f * (float)g, &sn, &cs);
    L[xb + 256*kb] = make_float2(kr*cs, kr*sn);
  }
  __syncthreads();
  #pragma unroll
  for (int n1 = 0; n1 < 16; ++n1) v[n1] = L[swt + n1*256];
  fft4096_reg<-1>(v, L);
  #pragma unroll
  for (int kb = 0; kb < 8; ++kb)
    kdO[k1 + 16*ka + 256*kb] = v[RI(kb)];
}

// ---------------------------------------------------------------------------
// fused_mid: blocks [0,256) = fft_kd (latency-bound, dispatched first);
// blocks [256,8448) = u transpose (BW-bound, hides fft_kd's stalls).
__global__ __launch_bounds__(256)
void fused_mid(const float* __restrict__ KdE, float* __restrict__ KdO,
               const float* __restrict__ u, float* __restrict__ ut){
  __shared__ cf L[4096];
  const int bid = blockIdx.x;
  if (bid < 256){
    fft_kd_body(bid, L, KdE, KdO);
    return;
  }
  // ---- transpose_u tile (uses first 4.2 KB of L) ----
  float (*tile)[33] = (float(*)[33])L;
  const int m  = bid - 256;
  const int l0 = (m & 127) * 32;
  const int d0 = ((m >> 7) & 7) * 32;
  const int b  = m >> 10;
  const int tx = threadIdx.x & 31;
  const int ty = threadIdx.x >> 5;
  const float* ub = u + (size_t)b * 4096 * 256;
  #pragma unroll
  for (int it = 0; it < 4; ++it){
    int l = l0 + ty + it*8;
    tile[tx][ty + it*8] = ub[(size_t)l*256 + d0 + tx];
  }
  __syncthreads();
  float* utb = ut + (size_t)b * 256 * 4096;
  #pragma unroll
  for (int it = 0; it < 4; ++it){
    int dd = d0 + ty + it*8;
    utb[(size_t)dd*4096 + l0 + tx] = tile[ty + it*8][tx];
  }
}

// ---------------------------------------------------------------------------
// Fast exact-GELU: Phi via A&S 7.1.26 erfc (|err| < 1.5e-7).
__device__ __forceinline__ float gelu_exact(float x){
  float z = fabsf(x) * 0.70710678118654752f;
  float tt = __builtin_amdgcn_rcpf(fmaf(0.3275911f, z, 1.0f));
  float poly = fmaf(fmaf(fmaf(fmaf(1.061405429f, tt, -1.453152027f), tt,
                    1.421413741f), tt, -0.284496736f), tt, 0.254829592f) * tt;
  float ec = poly * __expf(-z*z);
  float phi = (x >= 0.f) ? fmaf(-0.5f, ec, 1.0f) : 0.5f * ec;
  return x * phi;
}

// ---------------------------------------------------------------------------
// Kernel 3: per-(b,d) non-circular conv via packed real-FFT; fuses
// skip + GELU and writes bf16 Z overlaying the row's own storage.
__global__ __launch_bounds__(256)
void s4_conv(float* __restrict__ ut, const float* __restrict__ KdE,
             const float* __restrict__ KdO, const float* __restrict__ Dsk){
  __shared__ cf L[4096];
  const int row = blockIdx.x;           // b*256 + d
  const int d   = row & 255;
  const int t   = threadIdx.x;
  float2* rp = (float2*)(ut + (size_t)row * 4096);
  const float dskd = Dsk[d];

  cf v[16], uin[8];
  #pragma unroll
  for (int n1 = 0; n1 < 8; ++n1){ uin[n1] = rp[n1*256 + t]; v[n1] = uin[n1]; }
  #pragma unroll
  for (int n1 = 8; n1 < 16; ++n1) v[n1] = make_float2(0.f, 0.f);

  fft4096_reg<-1>(v, L);                // Z
  const int k1 = t >> 4, ka = t & 15;
  const int xb  = (k1 ^ ka) + 16*ka;
  const int swt = t ^ k1;
  const int t2  = 256 - t;
  const int swt2 = t2 ^ ((t2 >> 4) & 15);
  __syncthreads();
  #pragma unroll
  for (int kb = 0; kb < 16; ++kb)
    L[xb + 256*kb] = v[RI(kb)];
  __syncthreads();

  const cf* kdE = (const cf*)KdE + (size_t)d * 2049;
  const cf* kdO = (const cf*)KdO + (size_t)d * 2048;
  #pragma unroll
  for (int m = 0; m < 8; ++m){
    int k = t + m*256;                  // 0..2047
    if (k == 0){
      cf z0 = L[0];
      float U0 = z0.x + z0.y, UN = z0.x - z0.y;
      cf P0 = cscale(kdE[0], U0);
      cf PN = cscale(kdE[2048], UN);
      cf cPN = cconj(PN);
      cf Ep = cscale(cadd(P0, cPN), 0.5f);
      cf Op = cscale(csub(P0, cPN), 0.5f);
      L[0] = make_float2(Ep.x - Op.y, Ep.y + Op.x);
      cf P = cmul(cconj(L[2048]), kdE[1024]);
      L[2048] = cconj(P);
    } else {
      cf zk = L[swt + m*256];
      cf zj = L[(15 - m)*256 + swt2];
      cf E = make_float2(0.5f*(zk.x + zj.x),  0.5f*(zk.y - zj.y));
      cf O = make_float2(0.5f*(zk.y + zj.y), -0.5f*(zk.x - zj.x));
      float phi = 7.669903939428206e-4f * (float)k;     // pi*k/4096
      float sn, cs; __sincosf(phi, &sn, &cs);
      cf tw = make_float2(cs, -sn);
      cf tO = cmul(tw, O);
      cf Uk = cadd(E, tO);
      cf Uj = cconj(csub(E, tO));
      int h = k >> 1;
      cf kk, kj;
      if (k & 1){ kk = kdO[h]; kj = kdO[2047 - h]; }
      else      { kk = kdE[h]; kj = kdE[2048 - h]; }
      cf Pk = cmul(Uk, kk);
      cf Pj = cmul(Uj, kj);
      cf cPj = cconj(Pj), cPk = cconj(Pk);
      cf tp  = make_float2(cs, sn);
      cf Ek = cscale(cadd(Pk, cPj), 0.5f);
      cf Ok = cmul(tp, cscale(csub(Pk, cPj), 0.5f));
      L[swt + m*256] = make_float2(Ek.x - Ok.y, Ek.y + Ok.x);
      cf tpj = make_float2(-cs, sn);
      cf Ej = cscale(cadd(Pj, cPk), 0.5f);
      cf Oj = cmul(tpj, cscale(csub(Pj, cPk), 0.5f));
      L[(15 - m)*256 + swt2] = make_float2(Ej.x - Oj.y, Ej.y + Oj.x);
    }
  }
  __syncthreads();

  #pragma unroll
  for (int n1 = 0; n1 < 16; ++n1) v[n1] = L[swt + n1*256];
  fft4096_reg<+1>(v, L);

  __syncthreads();
  #pragma unroll
  for (int kb = 0; kb < 8; ++kb)
    L[xb + 256*kb] = v[RI(kb)];
  __syncthreads();
  const float inv = 1.0f / 4096.0f;
  unsigned* og = (unsigned*)rp;         // bf16 overlay (2 tokens / dword)
  #pragma unroll
  for (int n1 = 0; n1 < 8; ++n1){
    cf cv = L[swt + n1*256];
    float x0 = fmaf(dskd, uin[n1].x, cv.x * inv);
    float x1 = fmaf(dskd, uin[n1].y, cv.y * inv);
    unsigned b0 = (unsigned)(unsigned short)f2bf(gelu_exact(x0));
    unsigned b1 = (unsigned)(unsigned short)f2bf(gelu_exact(x1));
    og[n1*256 + t] = b0 | (b1 << 16);
  }
}

// ---------------------------------------------------------------------------
// Kernel 5: X = Z @ W^T + b + u ; LayerNorm -> out.  32 tokens/block (grid
// 1024).  acc C-INITIALIZED with (bias + u); Wbf fragment-major.
__global__ __launch_bounds__(256)
void mfma_gemm_ln(const float* __restrict__ utg, const short* __restrict__ Wbf,
                  const float* __restrict__ bias, const float* __restrict__ u,
                  const float* __restrict__ gamma, const float* __restrict__ beta,
                  float* __restrict__ out){
  __shared__ short St[64][32];        // one k-chunk: 64 k x 32 tokens
  __shared__ float prm[2][256];       // gamma / beta
  __shared__ float2 red[2][2][16];    // [tok-half][feat-half][lm]
  const int w    = threadIdx.x >> 6;
  const int l    = threadIdx.x & 63;
  const int lm   = l & 15;
  const int lk   = l >> 4;
  const int tokB = blockIdx.x * 32;   // never straddles batch (32 | 4096)
  const int b    = tokB >> 12;
  const int l0   = tokB & 4095;

  prm[0][threadIdx.x] = gamma[threadIdx.x];
  prm[1][threadIdx.x] = beta[threadIdx.x];

  // ---- Z chunk loads (all 4 upfront) ----
  const int srow = l >> 2;            // k-row within warp's 16
  const int tg   = l & 3;             // token-group of 8
  const char* ubase = (const char*)utg + (size_t)(b * 256) * 16384;
  bf16x8 pre[4];
  #pragma unroll
  for (int c = 0; c < 4; ++c){
    int r = c*64 + w*16 + srow;
    pre[c] = *(const bf16x8*)((const unsigned short*)(ubase + (size_t)r * 16384) + l0 + tg*8);
  }

  // ---- C-init: acc = bias + u ----
  const int th = (w & 1) * 16;        // token half
  const int fh2 = w >> 1;
  const int fh = fh2 * 128;           // feature half
  const int tt = tokB + th + lm;      // this lane's token
  const float* ur = u + (size_t)tt * 256 + fh;
  const float* br = bias + fh;
  f32x4 acc[8];
  #pragma unroll
  for (int nt = 0; nt < 8; ++nt){
    const float4 uv = *(const float4*)(ur + nt*16 + lk*4);
    const float4 bv = *(const float4*)(br + nt*16 + lk*4);
    acc[nt] = (f32x4){uv.x + bv.x, uv.y + bv.y, uv.z + bv.z, uv.w + bv.w};
  }

  const int tg_tok = (th + lm) >> 3;
  const int tlo    = lm & 7;

  #pragma unroll
  for (int c = 0; c < 4; ++c){
    __syncthreads();
    {
      int r  = w*16 + srow;
      int sl = (tg ^ ((r >> 3) & 3)) * 8;
      *(bf16x8*)&St[r][sl] = pre[c];
    }
    __syncthreads();
    #pragma unroll
    for (int s2 = 0; s2 < 2; ++s2){
      const int ks  = c*2 + s2;
      const int idx = ((tg_tok ^ lk) << 3) | tlo;
      bf16x8 zf;
      #pragma unroll
      for (int j = 0; j < 8; ++j)
        zf[j] = St[s2*32 + lk*8 + j][idx];
      const short* wbase = Wbf + (size_t)(ks*2 + fh2)*4096 + lk*128 + lm*8;
      #pragma unroll
      for (int nt = 0; nt < 8; ++nt){
        const bf16x8* ap = (const bf16x8*)(wbase + nt*512);
        acc[nt] = __builtin_amdgcn_mfma_f32_16x16x32_bf16(*ap, zf, acc[nt], 0, 0, 0);
      }
    }
  }

  // epilogue: LN over 256 features (shuffle over lk + cross-warp LDS join)
  float s = 0.f, s2 = 0.f;
  #pragma unroll
  for (int nt = 0; nt < 8; ++nt){
    s += acc[nt][0] + acc[nt][1] + acc[nt][2] + acc[nt][3];
    s2 = fmaf(acc[nt][0], acc[nt][0], s2);
    s2 = fmaf(acc[nt][1], acc[nt][1], s2);
    s2 = fmaf(acc[nt][2], acc[nt][2], s2);
    s2 = fmaf(acc[nt][3], acc[nt][3], s2);
  }
  s  += __shfl_xor(s,  16); s  += __shfl_xor(s,  32);
  s2 += __shfl_xor(s2, 16); s2 += __shfl_xor(s2, 32);
  __syncthreads();
  if (lk == 0) red[w & 1][fh2][lm] = make_float2(s, s2);
  __syncthreads();
  const float2 pj = red[w & 1][fh2 ^ 1][lm];
  const float st = s + pj.x, s2t = s2 + pj.y;
  const float mu = st * (1.0f/256.0f);
  const float rs = rsqrtf(s2t * (1.0f/256.0f) - mu*mu + 1e-5f);
  float* orow = out + (size_t)tt * 256 + fh;
  #pragma unroll
  for (int nt = 0; nt < 8; ++nt){
    const int f0 = fh + nt*16 + lk*4;
    const float4 gv = *(const float4*)&prm[0][f0];
    const float4 ev = *(const float4*)&prm[1][f0];
    float4 o;
    o.x = (acc[nt][0] - mu) * rs * gv.x + ev.x;
    o.y = (acc[nt][1] - mu) * rs * gv.y + ev.y;
    o.z = (acc[nt][2] - mu) * rs * gv.z + ev.z;
    o.w = (acc[nt][3] - mu) * rs * gv.w + ev.w;
    *(float4*)(orow + nt*16 + lk*4) = o;
  }
}

// ---------------------------------------------------------------------------
extern "C" void kernel_launch(void* const* d_in, const int* in_sizes, int n_in,
                              void* d_out, int out_size, void* d_ws, size_t ws_size,
                              hipStream_t stream){
  (void)in_sizes; (void)n_in; (void)out_size; (void)ws_size;
  const float* u        = (const float*)d_in[0];
  const float* B_ri     = (const float*)d_in[1];
  const float* Ct_ri    = (const float*)d_in[2];
  const float* lam_ri   = (const float*)d_in[3];
  const float* p_ri     = (const float*)d_in[4];
  const float* q_ri     = (const float*)d_in[5];
  const float* log_step = (const float*)d_in[6];
  const float* D_skip   = (const float*)d_in[7];
  const float* W        = (const float*)d_in[8];
  const float* bias     = (const float*)d_in[9];
  const float* gamma    = (const float*)d_in[10];
  const float* beta     = (const float*)d_in[11];
  float* out = (float*)d_out;

  // Workspace: KdE 4,196,352 | KdO 4,194,304 | Wbf 131,072 | ut 33,554,432
  char* ws = (char*)d_ws;
  float* KdE = (float*)(ws);
  float* KdO = (float*)(ws + 4196352);
  short* Wbf = (short*)(ws + 4196352 + 4194304);
  float* ut  = (float*)(ws + 4196352 + 4194304 + 131072);

  fused_head  <<<2112, 256, 0, stream>>>(B_ri, Ct_ri, lam_ri, p_ri, q_ri,
                                         log_step, KdE, W, Wbf);
  fused_mid   <<<8448, 256, 0, stream>>>(KdE, KdO, u, ut);
  s4_conv     <<<2048, 256, 0, stream>>>(ut, KdE, KdO, D_skip);
  mfma_gemm_ln<<<1024, 256, 0, stream>>>(ut, Wbf, bias, u, gamma, beta, out);
}

// Round 13
// 109.325 us; speedup vs baseline: 3.3343x; 1.0523x over previous
//
#include <hip/hip_runtime.h>
#include <math.h>

// S4 block: fused-head (Cauchy + W-convert), fused-mid (Kd FFT + u-transpose),
// s4_conv (reg FFTs + skip+GELU -> bf16 overlay), MFMA GEMM+LN.
// cf = ext_vector float2: compiler forms v_pk_add/mul_f32 from vector ops.
// B=8, L=4096, D=256, N=64.

typedef __attribute__((ext_vector_type(2))) float cf;
typedef __attribute__((ext_vector_type(8))) short bf16x8;
typedef __attribute__((ext_vector_type(4))) float f32x4;

__device__ __forceinline__ cf mkcf(float x, float y){ cf r; r.x = x; r.y = y; return r; }

__device__ __forceinline__ cf cadd(cf a, cf b){ return a + b; }       // v_pk_add_f32
__device__ __forceinline__ cf csub(cf a, cf b){ return a - b; }       // v_pk_add_f32 (neg)
__device__ __forceinline__ cf cscale(cf a, float s){ return a * s; }  // v_pk_mul_f32
__device__ __forceinline__ cf cconj(cf a){ return mkcf(a.x, -a.y); }
__device__ __forceinline__ cf cmul(cf a, cf b){                       // scalar (known-correct)
  return mkcf(fmaf(a.x, b.x, -a.y*b.y), fmaf(a.x, b.y, a.y*b.x));
}
// p + i*q, p - i*q
__device__ __forceinline__ cf caddi(cf p, cf q){ return mkcf(p.x - q.y, p.y + q.x); }
__device__ __forceinline__ cf csubi(cf p, cf q){ return mkcf(p.x + q.y, p.y - q.x); }

__device__ __forceinline__ short f2bf(float x){   // RNE float->bf16
  union { float f; unsigned u; } v; v.f = x;
  unsigned r = v.u + 0x7fffu + ((v.u >> 16) & 1u);
  return (short)(r >> 16);
}

__device__ __forceinline__ constexpr int RI(int k){ return ((k & 3) << 2) | (k >> 2); }

#define C8 0.92387953251f
#define S8 0.38268343236f
#define RH 0.70710678119f

template<int DIR>
__device__ __forceinline__ void r4(cf& a, cf& b, cf& c, cf& d){
  cf T0 = a + c, T1 = a - c;
  cf T2 = b + d, Bd = b - d;
  a = T0 + T2; c = T0 - T2;
  if (DIR > 0){ b = caddi(T1, Bd); d = csubi(T1, Bd); }
  else        { b = csubi(T1, Bd); d = caddi(T1, Bd); }
}

template<int DIR>
__device__ __forceinline__ void fft16(cf* v){
  r4<DIR>(v[0], v[4], v[8],  v[12]);
  r4<DIR>(v[1], v[5], v[9],  v[13]);
  r4<DIR>(v[2], v[6], v[10], v[14]);
  r4<DIR>(v[3], v[7], v[11], v[15]);
  constexpr float D = (float)DIR;
  const cf w1 = mkcf(C8,  D*S8);
  const cf w2 = mkcf(RH,  D*RH);
  const cf w3 = mkcf(S8,  D*C8);
  const cf w6 = mkcf(-RH, D*RH);
  const cf w9 = mkcf(-C8, -D*S8);
  v[5]  = cmul(v[5],  w1);
  v[6]  = cmul(v[6],  w2);
  v[7]  = cmul(v[7],  w3);
  v[9]  = cmul(v[9],  w2);
  v[10] = (DIR > 0) ? mkcf(-v[10].y, v[10].x) : mkcf(v[10].y, -v[10].x);
  v[11] = cmul(v[11], w6);
  v[13] = cmul(v[13], w3);
  v[14] = cmul(v[14], w6);
  v[15] = cmul(v[15], w9);
  r4<DIR>(v[0],  v[1],  v[2],  v[3]);
  r4<DIR>(v[4],  v[5],  v[6],  v[7]);
  r4<DIR>(v[8],  v[9],  v[10], v[11]);
  r4<DIR>(v[12], v[13], v[14], v[15]);
}

// 4096-pt FFT, four-step 16x(16x16).  Entry: v[n1] = x[n1*256 + t].
// Exit: V[k1+16*ka+256*kb] = v[RI(kb)], k1 = t>>4, ka = t&15.
template<int DIR>
__device__ void fft4096_reg(cf* v, cf* lds){
  const int t = threadIdx.x;
  const int k1 = t >> 4, m2 = t & 15;
  const int swt = t ^ k1;
  constexpr float D = (float)DIR;
  fft16<DIR>(v);
  float sn, cs;
  __sincosf(D * 1.5339807878856412e-3f * (float)t, &sn, &cs);   // 2pi/4096
  __syncthreads();
  {
    cf* p = lds + swt;
    cf w1 = mkcf(cs, sn);
    p[0]    = v[0];
    p[256]  = cmul(v[RI(1)],  w1);
    cf w2 = cmul(w1, w1);
    p[512]  = cmul(v[RI(2)],  w2);
    cf w3 = cmul(w2, w1);
    p[768]  = cmul(v[RI(3)],  w3);
    cf w4 = cmul(w2, w2);
    p[1024] = cmul(v[RI(4)],  w4);
    cf w5 = cmul(w4, w1);
    p[1280] = cmul(v[RI(5)],  w5);
    cf w6 = cmul(w4, w2);
    p[1536] = cmul(v[RI(6)],  w6);
    cf w7 = cmul(w4, w3);
    p[1792] = cmul(v[RI(7)],  w7);
    cf w8 = cmul(w4, w4);
    p[2048] = cmul(v[RI(8)],  w8);
    p[2304] = cmul(v[RI(9)],  cmul(w8, w1));
    p[2560] = cmul(v[RI(10)], cmul(w8, w2));
    p[2816] = cmul(v[RI(11)], cmul(w8, w3));
    p[3072] = cmul(v[RI(12)], cmul(w8, w4));
    p[3328] = cmul(v[RI(13)], cmul(w8, w5));
    p[3584] = cmul(v[RI(14)], cmul(w8, w6));
    p[3840] = cmul(v[RI(15)], cmul(w8, w7));
  }
  __syncthreads();
  {
    cf* p = lds + k1*256;
    #pragma unroll
    for (int m1 = 0; m1 < 16; ++m1) v[m1] = p[m1*16 + (m2 ^ m1)];
  }
  fft16<DIR>(v);
  __sincosf(D * 2.45436926061703e-2f * (float)m2, &sn, &cs);    // 2pi/256
  __syncthreads();
  {
    cf* p = lds + k1*256;
    cf w1 = mkcf(cs, sn);
    p[m2]              = v[0];
    p[16  + (m2^1)]    = cmul(v[RI(1)],  w1);
    cf w2 = cmul(w1, w1);
    p[32  + (m2^2)]    = cmul(v[RI(2)],  w2);
    cf w3 = cmul(w2, w1);
    p[48  + (m2^3)]    = cmul(v[RI(3)],  w3);
    cf w4 = cmul(w2, w2);
    p[64  + (m2^4)]    = cmul(v[RI(4)],  w4);
    cf w5 = cmul(w4, w1);
    p[80  + (m2^5)]    = cmul(v[RI(5)],  w5);
    cf w6 = cmul(w4, w2);
    p[96  + (m2^6)]    = cmul(v[RI(6)],  w6);
    cf w7 = cmul(w4, w3);
    p[112 + (m2^7)]    = cmul(v[RI(7)],  w7);
    cf w8 = cmul(w4, w4);
    p[128 + (m2^8)]    = cmul(v[RI(8)],  w8);
    p[144 + (m2^9)]    = cmul(v[RI(9)],  cmul(w8, w1));
    p[160 + (m2^10)]   = cmul(v[RI(10)], cmul(w8, w2));
    p[176 + (m2^11)]   = cmul(v[RI(11)], cmul(w8, w3));
    p[192 + (m2^12)]   = cmul(v[RI(12)], cmul(w8, w4));
    p[208 + (m2^13)]   = cmul(v[RI(13)], cmul(w8, w5));
    p[224 + (m2^14)]   = cmul(v[RI(14)], cmul(w8, w6));
    p[240 + (m2^15)]   = cmul(v[RI(15)], cmul(w8, w7));
  }
  __syncthreads();
  {
    const int ka = m2;
    cf* p = lds + k1*256 + ka*16;
    #pragma unroll
    for (int m2b = 0; m2b < 16; ++m2b) v[m2b] = p[m2b ^ ka];
  }
  fft16<DIR>(v);
}

// ---------------------------------------------------------------------------
// fused_head: blocks [0,2048) = Cauchy (Hermitian half -> KdE even bins);
// blocks [2048,2112) = W f32->bf16 fragment-major.
__global__ __launch_bounds__(256)
void fused_head(const float* __restrict__ B_ri, const float* __restrict__ Ct_ri,
                const float* __restrict__ lam_ri, const float* __restrict__ p_ri,
                const float* __restrict__ q_ri, const float* __restrict__ log_step,
                float* __restrict__ KdE,
                const float* __restrict__ W, short* __restrict__ Wbf){
  __shared__ cf w00[64], w01[64], w10[64], w11[64], lamS[64];
  const int bid = blockIdx.x;
  const int tid = threadIdx.x;

  if (bid >= 2048){
    int t  = (bid - 2048) * 256 + tid;          // 16384 threads
    int o4 = t * 4;
    int j   = o4 & 7;
    int lm  = (o4 >> 3)  & 15;
    int lk  = (o4 >> 7)  & 3;
    int nt  = (o4 >> 9)  & 7;
    int fh2 = (o4 >> 12) & 1;
    int ks  = o4 >> 13;
    int f = fh2*128 + nt*16 + lm;
    int k = ks*32 + lk*8 + j;
    float4 wv = *(const float4*)(W + (size_t)f*256 + k);
    short4 o;
    o.x = f2bf(wv.x); o.y = f2bf(wv.y); o.z = f2bf(wv.z); o.w = f2bf(wv.w);
    *(short4*)(Wbf + o4) = o;
    return;
  }

  const int d     = bid >> 3;
  const int chunk = bid & 7;
  const float step = expf(log_step[d]);

  if (tid < 64){
    int n = tid;
    cf Bv = mkcf(B_ri[(d*64+n)*2],  B_ri[(d*64+n)*2+1]);
    cf Cv = mkcf(Ct_ri[(d*64+n)*2], Ct_ri[(d*64+n)*2+1]);
    cf pv = mkcf(p_ri[n*2], p_ri[n*2+1]);
    cf qv = mkcf(q_ri[n*2], q_ri[n*2+1]);
    lamS[n] = mkcf(lam_ri[n*2], lam_ri[n*2+1]);
    cf Cc = cconj(Cv), qc = cconj(qv);
    w00[n] = cmul(Cc, Bv);
    w01[n] = cmul(Cc, pv);
    w10[n] = cmul(qc, Bv);
    w11[n] = cmul(qc, pv);
  }
  __syncthreads();

  cf* out = (cf*)KdE + (size_t)d * 2049;
  const int l = chunk * 256 + tid;               // 0..2047
  {
    float th = -(6.28318530717958647692f * (float)l) * (1.0f/4096.0f);
    float sn = sinf(th), cs = cosf(th);          // accurate sin/cos
    cf opw = mkcf(1.0f + cs,  sn);               // 1 + omega
    cf omw = mkcf(1.0f - cs, -sn);               // 1 - omega
    float idn = __builtin_amdgcn_rcpf(fmaf(opw.x, opw.x, opw.y*opw.y));
    cf ratio = mkcf((omw.x*opw.x + omw.y*opw.y)*idn,
                    (omw.y*opw.x - omw.x*opw.y)*idn);
    cf g  = cscale(ratio, 2.0f / step);
    cf cc = mkcf(2.0f*opw.x*idn, -2.0f*opw.y*idn);   // 2/(1+omega)
    cf k00 = mkcf(0,0), k01 = mkcf(0,0), k10 = mkcf(0,0), k11 = mkcf(0,0);
    #pragma unroll 4
    for (int n = 0; n < 64; ++n){
      cf den = g - lamS[n];
      float is = __builtin_amdgcn_rcpf(fmaf(den.x, den.x, den.y*den.y));
      cf r = mkcf(den.x*is, -den.y*is);              // 1/(g - lam)
      k00 = cadd(k00, cmul(w00[n], r));
      k01 = cadd(k01, cmul(w01[n], r));
      k10 = cadd(k10, cmul(w10[n], r));
      k11 = cadd(k11, cmul(w11[n], r));
    }
    cf onep = mkcf(1.0f + k11.x, k11.y);
    float ii = __builtin_amdgcn_rcpf(fmaf(onep.x, onep.x, onep.y*onep.y));
    cf inv1p = mkcf(onep.x*ii, -onep.y*ii);
    cf corr = cmul(k01, cmul(k10, inv1p));
    out[l] = cmul(cc, csub(k00, corr));
  }
  if (chunk == 7 && tid == 255){
    cf s00 = mkcf(0.f, 0.f);
    for (int n = 0; n < 64; ++n) s00 = cadd(s00, w00[n]);
    out[2048] = cscale(s00, 0.5f * step);
  }
}

// ---------------------------------------------------------------------------
// fft_kd body (one d): odd bins KdO[d][m] = FFT4096(Re(K[n]) e^{-i pi n/4096})[m].
__device__ void fft_kd_body(int d, cf* L, const float* __restrict__ KdE,
                            float* __restrict__ KdO){
  const int t = threadIdx.x;
  const cf* kdE = (const cf*)KdE + (size_t)d * 2049;
  cf* kdO = (cf*)KdO + (size_t)d * 2048;
  cf v[16];
  const float inv = 1.0f / 4096.0f;
  #pragma unroll
  for (int n1 = 0; n1 < 16; ++n1){
    int m = n1*256 + t;
    cf a = (m <= 2048) ? kdE[m] : cconj(kdE[4096 - m]);
    v[n1] = cscale(a, inv);
  }
  fft4096_reg<+1>(v, L);
  const int k1 = t >> 4, ka = t & 15;
  const int xb = (k1 ^ ka) + 16*ka;
  const int swt = t ^ k1;
  __syncthreads();
  #pragma unroll
  for (int kb = 0; kb < 16; ++kb){
    int g = k1 + 16*ka + 256*kb;
    float kr = v[RI(kb)].x;
    float sn, cs; __sincosf(-7.669903939428206e-4f * (float)g, &sn, &cs);
    L[xb + 256*kb] = mkcf(kr*cs, kr*sn);
  }
  __syncthreads();
  #pragma unroll
  for (int n1 = 0; n1 < 16; ++n1) v[n1] = L[swt + n1*256];
  fft4096_reg<-1>(v, L);
  #pragma unroll
  for (int kb = 0; kb < 8; ++kb)
    kdO[k1 + 16*ka + 256*kb] = v[RI(kb)];
}

// ---------------------------------------------------------------------------
// fused_mid: blocks [0,256) = fft_kd; blocks [256,8448) = u transpose.
__global__ __launch_bounds__(256)
void fused_mid(const float* __restrict__ KdE, float* __restrict__ KdO,
               const float* __restrict__ u, float* __restrict__ ut){
  __shared__ cf L[4096];
  const int bid = blockIdx.x;
  if (bid < 256){
    fft_kd_body(bid, L, KdE, KdO);
    return;
  }
  float (*tile)[33] = (float(*)[33])L;
  const int m  = bid - 256;
  const int l0 = (m & 127) * 32;
  const int d0 = ((m >> 7) & 7) * 32;
  const int b  = m >> 10;
  const int tx = threadIdx.x & 31;
  const int ty = threadIdx.x >> 5;
  const float* ub = u + (size_t)b * 4096 * 256;
  #pragma unroll
  for (int it = 0; it < 4; ++it){
    int l = l0 + ty + it*8;
    tile[tx][ty + it*8] = ub[(size_t)l*256 + d0 + tx];
  }
  __syncthreads();
  float* utb = ut + (size_t)b * 256 * 4096;
  #pragma unroll
  for (int it = 0; it < 4; ++it){
    int dd = d0 + ty + it*8;
    utb[(size_t)dd*4096 + l0 + tx] = tile[ty + it*8][tx];
  }
}

// ---------------------------------------------------------------------------
// Fast exact-GELU: Phi via A&S 7.1.26 erfc (|err| < 1.5e-7).
__device__ __forceinline__ float gelu_exact(float x){
  float z = fabsf(x) * 0.70710678118654752f;
  float tt = __builtin_amdgcn_rcpf(fmaf(0.3275911f, z, 1.0f));
  float poly = fmaf(fmaf(fmaf(fmaf(1.061405429f, tt, -1.453152027f), tt,
                    1.421413741f), tt, -0.284496736f), tt, 0.254829592f) * tt;
  float ec = poly * __expf(-z*z);
  float phi = (x >= 0.f) ? fmaf(-0.5f, ec, 1.0f) : 0.5f * ec;
  return x * phi;
}

// ---------------------------------------------------------------------------
// Kernel 3: per-(b,d) non-circular conv via packed real-FFT; fuses
// skip + GELU and writes bf16 Z overlaying the row's own storage.
__global__ __launch_bounds__(256)
void s4_conv(float* __restrict__ ut, const float* __restrict__ KdE,
             const float* __restrict__ KdO, const float* __restrict__ Dsk){
  __shared__ cf L[4096];
  const int row = blockIdx.x;           // b*256 + d
  const int d   = row & 255;
  const int t   = threadIdx.x;
  cf* rp = (cf*)(ut + (size_t)row * 4096);
  const float dskd = Dsk[d];

  cf v[16], uin[8];
  #pragma unroll
  for (int n1 = 0; n1 < 8; ++n1){ uin[n1] = rp[n1*256 + t]; v[n1] = uin[n1]; }
  #pragma unroll
  for (int n1 = 8; n1 < 16; ++n1) v[n1] = mkcf(0.f, 0.f);

  fft4096_reg<-1>(v, L);                // Z
  const int k1 = t >> 4, ka = t & 15;
  const int xb  = (k1 ^ ka) + 16*ka;
  const int swt = t ^ k1;
  const int t2  = 256 - t;
  const int swt2 = t2 ^ ((t2 >> 4) & 15);
  __syncthreads();
  #pragma unroll
  for (int kb = 0; kb < 16; ++kb)
    L[xb + 256*kb] = v[RI(kb)];
  __syncthreads();

  const cf* kdE = (const cf*)KdE + (size_t)d * 2049;
  const cf* kdO = (const cf*)KdO + (size_t)d * 2048;
  #pragma unroll
  for (int m = 0; m < 8; ++m){
    int k = t + m*256;                  // 0..2047
    if (k == 0){
      cf z0 = L[0];
      float U0 = z0.x + z0.y, UN = z0.x - z0.y;
      cf P0 = cscale(kdE[0], U0);
      cf PN = cscale(kdE[2048], UN);
      cf cPN = cconj(PN);
      cf Ep = cscale(cadd(P0, cPN), 0.5f);
      cf Op = cscale(csub(P0, cPN), 0.5f);
      L[0] = mkcf(Ep.x - Op.y, Ep.y + Op.x);
      cf P = cmul(cconj(L[2048]), kdE[1024]);
      L[2048] = cconj(P);
    } else {
      cf zk = L[swt + m*256];
      cf zj = L[(15 - m)*256 + swt2];
      cf E = mkcf(0.5f*(zk.x + zj.x),  0.5f*(zk.y - zj.y));
      cf O = mkcf(0.5f*(zk.y + zj.y), -0.5f*(zk.x - zj.x));
      float phi = 7.669903939428206e-4f * (float)k;     // pi*k/4096
      float sn, cs; __sincosf(phi, &sn, &cs);
      cf tw = mkcf(cs, -sn);
      cf tO = cmul(tw, O);
      cf Uk = cadd(E, tO);
      cf Uj = cconj(csub(E, tO));                        // U[4096-k]
      int h = k >> 1;
      cf kk, kj;
      if (k & 1){ kk = kdO[h]; kj = kdO[2047 - h]; }
      else      { kk = kdE[h]; kj = kdE[2048 - h]; }
      cf Pk = cmul(Uk, kk);
      cf Pj = cmul(Uj, kj);
      cf cPj = cconj(Pj), cPk = cconj(Pk);
      cf tp  = mkcf(cs, sn);
      cf Ek = cscale(cadd(Pk, cPj), 0.5f);
      cf Ok = cmul(tp, cscale(csub(Pk, cPj), 0.5f));
      L[swt + m*256] = mkcf(Ek.x - Ok.y, Ek.y + Ok.x);
      cf tpj = mkcf(-cs, sn);
      cf Ej = cscale(cadd(Pj, cPk), 0.5f);
      cf Oj = cmul(tpj, cscale(csub(Pj, cPk), 0.5f));
      L[(15 - m)*256 + swt2] = mkcf(Ej.x - Oj.y, Ej.y + Oj.x);
    }
  }
  __syncthreads();

  #pragma unroll
  for (int n1 = 0; n1 < 16; ++n1) v[n1] = L[swt + n1*256];
  fft4096_reg<+1>(v, L);

  __syncthreads();
  #pragma unroll
  for (int kb = 0; kb < 8; ++kb)
    L[xb + 256*kb] = v[RI(kb)];
  __syncthreads();
  const float inv = 1.0f / 4096.0f;
  unsigned* og = (unsigned*)rp;         // bf16 overlay (2 tokens / dword)
  #pragma unroll
  for (int n1 = 0; n1 < 8; ++n1){
    cf cv = L[swt + n1*256];
    float x0 = fmaf(dskd, uin[n1].x, cv.x * inv);
    float x1 = fmaf(dskd, uin[n1].y, cv.y * inv);
    unsigned b0 = (unsigned)(unsigned short)f2bf(gelu_exact(x0));
    unsigned b1 = (unsigned)(unsigned short)f2bf(gelu_exact(x1));
    og[n1*256 + t] = b0 | (b1 << 16);
  }
}

// ---------------------------------------------------------------------------
// Kernel 5: X = Z @ W^T + b + u ; LayerNorm -> out.  32 tokens/block (grid
// 1024).  acc C-INITIALIZED with (bias + u); Wbf fragment-major.
__global__ __launch_bounds__(256)
void mfma_gemm_ln(const float* __restrict__ utg, const short* __restrict__ Wbf,
                  const float* __restrict__ bias, const float* __restrict__ u,
                  const float* __restrict__ gamma, const float* __restrict__ beta,
                  float* __restrict__ out){
  __shared__ short St[64][32];        // one k-chunk: 64 k x 32 tokens
  __shared__ float prm[2][256];       // gamma / beta
  __shared__ float2 red[2][2][16];    // [tok-half][feat-half][lm]
  const int w    = threadIdx.x >> 6;
  const int l    = threadIdx.x & 63;
  const int lm   = l & 15;
  const int lk   = l >> 4;
  const int tokB = blockIdx.x * 32;   // never straddles batch (32 | 4096)
  const int b    = tokB >> 12;
  const int l0   = tokB & 4095;

  prm[0][threadIdx.x] = gamma[threadIdx.x];
  prm[1][threadIdx.x] = beta[threadIdx.x];

  const int srow = l >> 2;            // k-row within warp's 16
  const int tg   = l & 3;             // token-group of 8
  const char* ubase = (const char*)utg + (size_t)(b * 256) * 16384;
  bf16x8 pre[4];
  #pragma unroll
  for (int c = 0; c < 4; ++c){
    int r = c*64 + w*16 + srow;
    pre[c] = *(const bf16x8*)((const unsigned short*)(ubase + (size_t)r * 16384) + l0 + tg*8);
  }

  const int th = (w & 1) * 16;        // token half
  const int fh2 = w >> 1;
  const int fh = fh2 * 128;           // feature half
  const int tt = tokB + th + lm;      // this lane's token
  const float* ur = u + (size_t)tt * 256 + fh;
  const float* br = bias + fh;
  f32x4 acc[8];
  #pragma unroll
  for (int nt = 0; nt < 8; ++nt){
    const float4 uv = *(const float4*)(ur + nt*16 + lk*4);
    const float4 bv = *(const float4*)(br + nt*16 + lk*4);
    acc[nt] = (f32x4){uv.x + bv.x, uv.y + bv.y, uv.z + bv.z, uv.w + bv.w};
  }

  const int tg_tok = (th + lm) >> 3;
  const int tlo    = lm & 7;

  #pragma unroll
  for (int c = 0; c < 4; ++c){
    __syncthreads();
    {
      int r  = w*16 + srow;
      int sl = (tg ^ ((r >> 3) & 3)) * 8;
      *(bf16x8*)&St[r][sl] = pre[c];
    }
    __syncthreads();
    #pragma unroll
    for (int s2 = 0; s2 < 2; ++s2){
      const int ks  = c*2 + s2;
      const int idx = ((tg_tok ^ lk) << 3) | tlo;
      bf16x8 zf;
      #pragma unroll
      for (int j = 0; j < 8; ++j)
        zf[j] = St[s2*32 + lk*8 + j][idx];
      const short* wbase = Wbf + (size_t)(ks*2 + fh2)*4096 + lk*128 + lm*8;
      #pragma unroll
      for (int nt = 0; nt < 8; ++nt){
        const bf16x8* ap = (const bf16x8*)(wbase + nt*512);
        acc[nt] = __builtin_amdgcn_mfma_f32_16x16x32_bf16(*ap, zf, acc[nt], 0, 0, 0);
      }
    }
  }

  float s = 0.f, s2 = 0.f;
  #pragma unroll
  for (int nt = 0; nt < 8; ++nt){
    s += acc[nt][0] + acc[nt][1] + acc[nt][2] + acc[nt][3];
    s2 = fmaf(acc[nt][0], acc[nt][0], s2);
    s2 = fmaf(acc[nt][1], acc[nt][1], s2);
    s2 = fmaf(acc[nt][2], acc[nt][2], s2);
    s2 = fmaf(acc[nt][3], acc[nt][3], s2);
  }
  s  += __shfl_xor(s,  16); s  += __shfl_xor(s,  32);
  s2 += __shfl_xor(s2, 16); s2 += __shfl_xor(s2, 32);
  __syncthreads();
  if (lk == 0) red[w & 1][fh2][lm] = make_float2(s, s2);
  __syncthreads();
  const float2 pj = red[w & 1][fh2 ^ 1][lm];
  const float st = s + pj.x, s2t = s2 + pj.y;
  const float mu = st * (1.0f/256.0f);
  const float rs = rsqrtf(s2t * (1.0f/256.0f) - mu*mu + 1e-5f);
  float* orow = out + (size_t)tt * 256 + fh;
  #pragma unroll
  for (int nt = 0; nt < 8; ++nt){
    const int f0 = fh + nt*16 + lk*4;
    const float4 gv = *(const float4*)&prm[0][f0];
    const float4 ev = *(const float4*)&prm[1][f0];
    float4 o;
    o.x = (acc[nt][0] - mu) * rs * gv.x + ev.x;
    o.y = (acc[nt][1] - mu) * rs * gv.y + ev.y;
    o.z = (acc[nt][2] - mu) * rs * gv.z + ev.z;
    o.w = (acc[nt][3] - mu) * rs * gv.w + ev.w;
    *(float4*)(orow + nt*16 + lk*4) = o;
  }
}

// ---------------------------------------------------------------------------
extern "C" void kernel_launch(void* const* d_in, const int* in_sizes, int n_in,
                              void* d_out, int out_size, void* d_ws, size_t ws_size,
                              hipStream_t stream){
  (void)in_sizes; (void)n_in; (void)out_size; (void)ws_size;
  const float* u        = (const float*)d_in[0];
  const float* B_ri     = (const float*)d_in[1];
  const float* Ct_ri    = (const float*)d_in[2];
  const float* lam_ri   = (const float*)d_in[3];
  const float* p_ri     = (const float*)d_in[4];
  const float* q_ri     = (const float*)d_in[5];
  const float* log_step = (const float*)d_in[6];
  const float* D_skip   = (const float*)d_in[7];
  const float* W        = (const float*)d_in[8];
  const float* bias     = (const float*)d_in[9];
  const float* gamma    = (const float*)d_in[10];
  const float* beta     = (const float*)d_in[11];
  float* out = (float*)d_out;

  // Workspace: KdE 4,196,352 | KdO 4,194,304 | Wbf 131,072 | ut 33,554,432
  char* ws = (char*)d_ws;
  float* KdE = (float*)(ws);
  float* KdO = (float*)(ws + 4196352);
  short* Wbf = (short*)(ws + 4196352 + 4194304);
  float* ut  = (float*)(ws + 4196352 + 4194304 + 131072);

  fused_head  <<<2112, 256, 0, stream>>>(B_ri, Ct_ri, lam_ri, p_ri, q_ri,
                                         log_step, KdE, W, Wbf);
  fused_mid   <<<8448, 256, 0, stream>>>(KdE, KdO, u, ut);
  s4_conv     <<<2048, 256, 0, stream>>>(ut, KdE, KdO, D_skip);
  mfma_gemm_ln<<<1024, 256, 0, stream>>>(ut, Wbf, bias, u, gamma, beta, out);
}

// Round 14
// 103.110 us; speedup vs baseline: 3.5353x; 1.0603x over previous
//
#include <hip/hip_runtime.h>
#include <math.h>

// S4 block: fused-head (Cauchy + W-convert), fused-mid (Kd FFT + u-transpose),
// s4_conv (reg FFTs + collapsed pointwise + skip+GELU -> bf16 overlay),
// MFMA GEMM+LN.  B=8, L=4096, D=256, N=64.

typedef __attribute__((ext_vector_type(2))) float cf;
typedef __attribute__((ext_vector_type(8))) short bf16x8;
typedef __attribute__((ext_vector_type(4))) float f32x4;

__device__ __forceinline__ cf mkcf(float x, float y){ cf r; r.x = x; r.y = y; return r; }

__device__ __forceinline__ cf cadd(cf a, cf b){ return a + b; }       // v_pk_add_f32
__device__ __forceinline__ cf csub(cf a, cf b){ return a - b; }
__device__ __forceinline__ cf cscale(cf a, float s){ return a * s; }  // v_pk_mul_f32
__device__ __forceinline__ cf cconj(cf a){ return mkcf(a.x, -a.y); }
__device__ __forceinline__ cf cmul(cf a, cf b){                       // scalar 4-fma
  return mkcf(fmaf(a.x, b.x, -a.y*b.y), fmaf(a.x, b.y, a.y*b.x));
}
// acc += a*b, fused (4 fma, no separate add)
__device__ __forceinline__ void cmacc(cf& acc, cf a, cf b){
  acc.x = fmaf(a.x, b.x, fmaf(-a.y, b.y, acc.x));
  acc.y = fmaf(a.x, b.y, fmaf( a.y, b.x, acc.y));
}
// p + i*q, p - i*q
__device__ __forceinline__ cf caddi(cf p, cf q){ return mkcf(p.x - q.y, p.y + q.x); }
__device__ __forceinline__ cf csubi(cf p, cf q){ return mkcf(p.x + q.y, p.y - q.x); }

__device__ __forceinline__ short f2bf(float x){   // RNE float->bf16
  union { float f; unsigned u; } v; v.f = x;
  unsigned r = v.u + 0x7fffu + ((v.u >> 16) & 1u);
  return (short)(r >> 16);
}

__device__ __forceinline__ constexpr int RI(int k){ return ((k & 3) << 2) | (k >> 2); }

#define C8 0.92387953251f
#define S8 0.38268343236f
#define RH 0.70710678119f

template<int DIR>
__device__ __forceinline__ void r4(cf& a, cf& b, cf& c, cf& d){
  cf T0 = a + c, T1 = a - c;
  cf T2 = b + d, Bd = b - d;
  a = T0 + T2; c = T0 - T2;
  if (DIR > 0){ b = caddi(T1, Bd); d = csubi(T1, Bd); }
  else        { b = csubi(T1, Bd); d = caddi(T1, Bd); }
}

// FFT16; if HZ, inputs v[8..15] are known zero (stage-1 r4s degenerate).
template<int DIR, bool HZ>
__device__ __forceinline__ void fft16(cf* v){
  if constexpr (HZ){
    #pragma unroll
    for (int i = 0; i < 4; ++i){
      cf a = v[i], b = v[i+4];
      v[i]   = a + b;
      v[i+8] = a - b;
      if (DIR > 0){ v[i+4] = caddi(a, b); v[i+12] = csubi(a, b); }
      else        { v[i+4] = csubi(a, b); v[i+12] = caddi(a, b); }
    }
  } else {
    r4<DIR>(v[0], v[4], v[8],  v[12]);
    r4<DIR>(v[1], v[5], v[9],  v[13]);
    r4<DIR>(v[2], v[6], v[10], v[14]);
    r4<DIR>(v[3], v[7], v[11], v[15]);
  }
  constexpr float D = (float)DIR;
  const cf w1 = mkcf(C8,  D*S8);
  const cf w2 = mkcf(RH,  D*RH);
  const cf w3 = mkcf(S8,  D*C8);
  const cf w6 = mkcf(-RH, D*RH);
  const cf w9 = mkcf(-C8, -D*S8);
  v[5]  = cmul(v[5],  w1);
  v[6]  = cmul(v[6],  w2);
  v[7]  = cmul(v[7],  w3);
  v[9]  = cmul(v[9],  w2);
  v[10] = (DIR > 0) ? mkcf(-v[10].y, v[10].x) : mkcf(v[10].y, -v[10].x);
  v[11] = cmul(v[11], w6);
  v[13] = cmul(v[13], w3);
  v[14] = cmul(v[14], w6);
  v[15] = cmul(v[15], w9);
  r4<DIR>(v[0],  v[1],  v[2],  v[3]);
  r4<DIR>(v[4],  v[5],  v[6],  v[7]);
  r4<DIR>(v[8],  v[9],  v[10], v[11]);
  r4<DIR>(v[12], v[13], v[14], v[15]);
}

// 4096-pt FFT, four-step 16x(16x16).  Entry: v[n1] = x[n1*256 + t].
// Exit: V[k1+16*ka+256*kb] = v[RI(kb)], k1 = t>>4, ka = t&15.
template<int DIR, bool HZ = false>
__device__ void fft4096_reg(cf* v, cf* lds){
  const int t = threadIdx.x;
  const int k1 = t >> 4, m2 = t & 15;
  const int swt = t ^ k1;
  constexpr float D = (float)DIR;
  fft16<DIR, HZ>(v);
  float sn, cs;
  __sincosf(D * 1.5339807878856412e-3f * (float)t, &sn, &cs);   // 2pi/4096
  __syncthreads();
  {
    cf* p = lds + swt;
    cf w1 = mkcf(cs, sn);
    p[0]    = v[0];
    p[256]  = cmul(v[RI(1)],  w1);
    cf w2 = cmul(w1, w1);
    p[512]  = cmul(v[RI(2)],  w2);
    cf w3 = cmul(w2, w1);
    p[768]  = cmul(v[RI(3)],  w3);
    cf w4 = cmul(w2, w2);
    p[1024] = cmul(v[RI(4)],  w4);
    cf w5 = cmul(w4, w1);
    p[1280] = cmul(v[RI(5)],  w5);
    cf w6 = cmul(w4, w2);
    p[1536] = cmul(v[RI(6)],  w6);
    cf w7 = cmul(w4, w3);
    p[1792] = cmul(v[RI(7)],  w7);
    cf w8 = cmul(w4, w4);
    p[2048] = cmul(v[RI(8)],  w8);
    p[2304] = cmul(v[RI(9)],  cmul(w8, w1));
    p[2560] = cmul(v[RI(10)], cmul(w8, w2));
    p[2816] = cmul(v[RI(11)], cmul(w8, w3));
    p[3072] = cmul(v[RI(12)], cmul(w8, w4));
    p[3328] = cmul(v[RI(13)], cmul(w8, w5));
    p[3584] = cmul(v[RI(14)], cmul(w8, w6));
    p[3840] = cmul(v[RI(15)], cmul(w8, w7));
  }
  __syncthreads();
  {
    cf* p = lds + k1*256;
    #pragma unroll
    for (int m1 = 0; m1 < 16; ++m1) v[m1] = p[m1*16 + (m2 ^ m1)];
  }
  fft16<DIR, false>(v);
  __sincosf(D * 2.45436926061703e-2f * (float)m2, &sn, &cs);    // 2pi/256
  __syncthreads();
  {
    cf* p = lds + k1*256;
    cf w1 = mkcf(cs, sn);
    p[m2]              = v[0];
    p[16  + (m2^1)]    = cmul(v[RI(1)],  w1);
    cf w2 = cmul(w1, w1);
    p[32  + (m2^2)]    = cmul(v[RI(2)],  w2);
    cf w3 = cmul(w2, w1);
    p[48  + (m2^3)]    = cmul(v[RI(3)],  w3);
    cf w4 = cmul(w2, w2);
    p[64  + (m2^4)]    = cmul(v[RI(4)],  w4);
    cf w5 = cmul(w4, w1);
    p[80  + (m2^5)]    = cmul(v[RI(5)],  w5);
    cf w6 = cmul(w4, w2);
    p[96  + (m2^6)]    = cmul(v[RI(6)],  w6);
    cf w7 = cmul(w4, w3);
    p[112 + (m2^7)]    = cmul(v[RI(7)],  w7);
    cf w8 = cmul(w4, w4);
    p[128 + (m2^8)]    = cmul(v[RI(8)],  w8);
    p[144 + (m2^9)]    = cmul(v[RI(9)],  cmul(w8, w1));
    p[160 + (m2^10)]   = cmul(v[RI(10)], cmul(w8, w2));
    p[176 + (m2^11)]   = cmul(v[RI(11)], cmul(w8, w3));
    p[192 + (m2^12)]   = cmul(v[RI(12)], cmul(w8, w4));
    p[208 + (m2^13)]   = cmul(v[RI(13)], cmul(w8, w5));
    p[224 + (m2^14)]   = cmul(v[RI(14)], cmul(w8, w6));
    p[240 + (m2^15)]   = cmul(v[RI(15)], cmul(w8, w7));
  }
  __syncthreads();
  {
    const int ka = m2;
    cf* p = lds + k1*256 + ka*16;
    #pragma unroll
    for (int m2b = 0; m2b < 16; ++m2b) v[m2b] = p[m2b ^ ka];
  }
  fft16<DIR, false>(v);
}

// ---------------------------------------------------------------------------
// fused_head: blocks [0,2048) = Cauchy (Hermitian half -> KdE even bins);
// blocks [2048,2112) = W f32->bf16 fragment-major.
__global__ __launch_bounds__(256)
void fused_head(const float* __restrict__ B_ri, const float* __restrict__ Ct_ri,
                const float* __restrict__ lam_ri, const float* __restrict__ p_ri,
                const float* __restrict__ q_ri, const float* __restrict__ log_step,
                float* __restrict__ KdE,
                const float* __restrict__ W, short* __restrict__ Wbf){
  __shared__ cf w00[64], w01[64], w10[64], w11[64], lamS[64];
  const int bid = blockIdx.x;
  const int tid = threadIdx.x;

  if (bid >= 2048){
    int t  = (bid - 2048) * 256 + tid;          // 16384 threads
    int o4 = t * 4;
    int j   = o4 & 7;
    int lm  = (o4 >> 3)  & 15;
    int lk  = (o4 >> 7)  & 3;
    int nt  = (o4 >> 9)  & 7;
    int fh2 = (o4 >> 12) & 1;
    int ks  = o4 >> 13;
    int f = fh2*128 + nt*16 + lm;
    int k = ks*32 + lk*8 + j;
    float4 wv = *(const float4*)(W + (size_t)f*256 + k);
    short4 o;
    o.x = f2bf(wv.x); o.y = f2bf(wv.y); o.z = f2bf(wv.z); o.w = f2bf(wv.w);
    *(short4*)(Wbf + o4) = o;
    return;
  }

  const int d     = bid >> 3;
  const int chunk = bid & 7;
  const float step = expf(log_step[d]);

  if (tid < 64){
    int n = tid;
    cf Bv = mkcf(B_ri[(d*64+n)*2],  B_ri[(d*64+n)*2+1]);
    cf Cv = mkcf(Ct_ri[(d*64+n)*2], Ct_ri[(d*64+n)*2+1]);
    cf pv = mkcf(p_ri[n*2], p_ri[n*2+1]);
    cf qv = mkcf(q_ri[n*2], q_ri[n*2+1]);
    lamS[n] = mkcf(lam_ri[n*2], lam_ri[n*2+1]);
    cf Cc = cconj(Cv), qc = cconj(qv);
    w00[n] = cmul(Cc, Bv);
    w01[n] = cmul(Cc, pv);
    w10[n] = cmul(qc, Bv);
    w11[n] = cmul(qc, pv);
  }
  __syncthreads();

  cf* out = (cf*)KdE + (size_t)d * 2049;
  const int l = chunk * 256 + tid;               // 0..2047
  {
    float th = -(6.28318530717958647692f * (float)l) * (1.0f/4096.0f);
    float sn, cs; __sincosf(th, &sn, &cs);
    cf opw = mkcf(1.0f + cs,  sn);               // 1 + omega
    cf omw = mkcf(1.0f - cs, -sn);               // 1 - omega
    float idn = __builtin_amdgcn_rcpf(fmaf(opw.x, opw.x, opw.y*opw.y));
    cf ratio = mkcf((omw.x*opw.x + omw.y*opw.y)*idn,
                    (omw.y*opw.x - omw.x*opw.y)*idn);
    cf g  = cscale(ratio, 2.0f / step);
    cf cc = mkcf(2.0f*opw.x*idn, -2.0f*opw.y*idn);   // 2/(1+omega)
    cf k00 = mkcf(0,0), k01 = mkcf(0,0), k10 = mkcf(0,0), k11 = mkcf(0,0);
    #pragma unroll 4
    for (int n = 0; n < 64; ++n){
      cf den = g - lamS[n];
      float is = __builtin_amdgcn_rcpf(fmaf(den.x, den.x, den.y*den.y));
      cf r = mkcf(den.x*is, -den.y*is);              // 1/(g - lam)
      cmacc(k00, w00[n], r);
      cmacc(k01, w01[n], r);
      cmacc(k10, w10[n], r);
      cmacc(k11, w11[n], r);
    }
    cf onep = mkcf(1.0f + k11.x, k11.y);
    float ii = __builtin_amdgcn_rcpf(fmaf(onep.x, onep.x, onep.y*onep.y));
    cf inv1p = mkcf(onep.x*ii, -onep.y*ii);
    cf corr = cmul(k01, cmul(k10, inv1p));
    out[l] = cmul(cc, csub(k00, corr));
  }
  if (chunk == 7 && tid == 255){
    cf s00 = mkcf(0.f, 0.f);
    for (int n = 0; n < 64; ++n) s00 = cadd(s00, w00[n]);
    out[2048] = cscale(s00, 0.5f * step);
  }
}

// ---------------------------------------------------------------------------
// fft_kd body (one d): odd bins KdO[d][m] = FFT4096(Re(K[n]) e^{-i pi n/4096})[m].
__device__ void fft_kd_body(int d, cf* L, const float* __restrict__ KdE,
                            float* __restrict__ KdO){
  const int t = threadIdx.x;
  const cf* kdE = (const cf*)KdE + (size_t)d * 2049;
  cf* kdO = (cf*)KdO + (size_t)d * 2048;
  cf v[16];
  const float inv = 1.0f / 4096.0f;
  #pragma unroll
  for (int n1 = 0; n1 < 16; ++n1){
    int m = n1*256 + t;
    cf a = (m <= 2048) ? kdE[m] : cconj(kdE[4096 - m]);
    v[n1] = cscale(a, inv);
  }
  fft4096_reg<+1>(v, L);
  const int k1 = t >> 4, ka = t & 15;
  const int xb = (k1 ^ ka) + 16*ka;
  const int swt = t ^ k1;
  __syncthreads();
  #pragma unroll
  for (int kb = 0; kb < 16; ++kb){
    int g = k1 + 16*ka + 256*kb;
    float kr = v[RI(kb)].x;
    float sn, cs; __sincosf(-7.669903939428206e-4f * (float)g, &sn, &cs);
    L[xb + 256*kb] = mkcf(kr*cs, kr*sn);
  }
  __syncthreads();
  #pragma unroll
  for (int n1 = 0; n1 < 16; ++n1) v[n1] = L[swt + n1*256];
  fft4096_reg<-1>(v, L);
  #pragma unroll
  for (int kb = 0; kb < 8; ++kb)
    kdO[k1 + 16*ka + 256*kb] = v[RI(kb)];
}

// ---------------------------------------------------------------------------
// fused_mid: blocks [0,256) = fft_kd; blocks [256,8448) = u transpose.
__global__ __launch_bounds__(256)
void fused_mid(const float* __restrict__ KdE, float* __restrict__ KdO,
               const float* __restrict__ u, float* __restrict__ ut){
  __shared__ cf L[4096];
  const int bid = blockIdx.x;
  if (bid < 256){
    fft_kd_body(bid, L, KdE, KdO);
    return;
  }
  float (*tile)[33] = (float(*)[33])L;
  const int m  = bid - 256;
  const int l0 = (m & 127) * 32;
  const int d0 = ((m >> 7) & 7) * 32;
  const int b  = m >> 10;
  const int tx = threadIdx.x & 31;
  const int ty = threadIdx.x >> 5;
  const float* ub = u + (size_t)b * 4096 * 256;
  #pragma unroll
  for (int it = 0; it < 4; ++it){
    int l = l0 + ty + it*8;
    tile[tx][ty + it*8] = ub[(size_t)l*256 + d0 + tx];
  }
  __syncthreads();
  float* utb = ut + (size_t)b * 256 * 4096;
  #pragma unroll
  for (int it = 0; it < 4; ++it){
    int dd = d0 + ty + it*8;
    utb[(size_t)dd*4096 + l0 + tx] = tile[ty + it*8][tx];
  }
}

// ---------------------------------------------------------------------------
// Fast exact-GELU: Phi via A&S 7.1.26 erfc (|err| < 1.5e-7).
__device__ __forceinline__ float gelu_exact(float x){
  float z = fabsf(x) * 0.70710678118654752f;
  float tt = __builtin_amdgcn_rcpf(fmaf(0.3275911f, z, 1.0f));
  float poly = fmaf(fmaf(fmaf(fmaf(1.061405429f, tt, -1.453152027f), tt,
                    1.421413741f), tt, -0.284496736f), tt, 0.254829592f) * tt;
  float ec = poly * __expf(-z*z);
  float phi = (x >= 0.f) ? fmaf(-0.5f, ec, 1.0f) : 0.5f * ec;
  return x * phi;
}

// ---------------------------------------------------------------------------
// Kernel 3: per-(b,d) non-circular conv via packed real-FFT; collapsed
// pointwise A[k] = KA*Zk + KB*conj(Zj); fuses skip + GELU -> bf16 overlay.
__global__ __launch_bounds__(256)
void s4_conv(float* __restrict__ ut, const float* __restrict__ KdE,
             const float* __restrict__ KdO, const float* __restrict__ Dsk){
  __shared__ cf L[4096];
  const int row = blockIdx.x;           // b*256 + d
  const int d   = row & 255;
  const int t   = threadIdx.x;
  cf* rp = (cf*)(ut + (size_t)row * 4096);
  const float dskd = Dsk[d];

  cf v[16], uin[8];
  #pragma unroll
  for (int n1 = 0; n1 < 8; ++n1){ uin[n1] = rp[n1*256 + t]; v[n1] = uin[n1]; }
  #pragma unroll
  for (int n1 = 8; n1 < 16; ++n1) v[n1] = mkcf(0.f, 0.f);

  fft4096_reg<-1, true>(v, L);          // Z (half-zero input)
  const int k1 = t >> 4, ka = t & 15;
  const int xb  = (k1 ^ ka) + 16*ka;
  const int swt = t ^ k1;
  const int t2  = 256 - t;
  const int swt2 = t2 ^ ((t2 >> 4) & 15);
  __syncthreads();
  #pragma unroll
  for (int kb = 0; kb < 16; ++kb)
    L[xb + 256*kb] = v[RI(kb)];
  __syncthreads();

  const cf* kdE = (const cf*)KdE + (size_t)d * 2049;
  const cf* kdO = (const cf*)KdO + (size_t)d * 2048;
  #pragma unroll
  for (int m = 0; m < 8; ++m){
    int k = t + m*256;                  // 0..2047
    if (k == 0){
      cf z0 = L[0];
      float U0 = z0.x + z0.y, UN = z0.x - z0.y;
      cf P0 = cscale(kdE[0], U0);
      cf PN = cscale(kdE[2048], UN);
      cf cPN = cconj(PN);
      cf Ep = cscale(cadd(P0, cPN), 0.5f);
      cf Op = cscale(csub(P0, cPN), 0.5f);
      L[0] = mkcf(Ep.x - Op.y, Ep.y + Op.x);
      cf P = cmul(cconj(L[2048]), kdE[1024]);
      L[2048] = cconj(P);
    } else {
      cf zk = L[swt + m*256];
      cf zj = L[(15 - m)*256 + swt2];
      int h = k >> 1;
      cf kk, kj;
      if (k & 1){ kk = kdO[h]; kj = kdO[2047 - h]; }
      else      { kk = kdE[h]; kj = kdE[2048 - h]; }
      float sn, cs; __sincosf(7.669903939428206e-4f * (float)k, &sn, &cs); // pi*k/4096
      cf KS = mkcf(0.5f*(kk.x + kj.x), 0.5f*(kk.y - kj.y));
      cf KD = mkcf(0.5f*(kk.x - kj.x), 0.5f*(kk.y + kj.y));
      cf KA  = KS - KD * sn;            // vector pk_fma
      cf KAp = KS + KD * sn;
      cf KB  = mkcf(-cs * KD.y, cs * KD.x);   // i*c*KD
      cf Ak, Aj;
      // A[k] = KA*zk + KB*conj(zj)
      Ak.x = fmaf(KA.x, zk.x, fmaf(-KA.y, zk.y, fmaf(KB.x, zj.x,  KB.y*zj.y)));
      Ak.y = fmaf(KA.x, zk.y, fmaf( KA.y, zk.x, fmaf(KB.y, zj.x, -KB.x*zj.y)));
      // A[4096-k] = conj(KAp)*zj - conj(KB*zk)
      Aj.x = fmaf( KAp.x, zj.x, fmaf(KAp.y, zj.y, fmaf(-KB.x, zk.x, KB.y*zk.y)));
      Aj.y = fmaf(-KAp.y, zj.x, fmaf(KAp.x, zj.y, fmaf( KB.x, zk.y, KB.y*zk.x)));
      L[swt + m*256] = Ak;
      L[(15 - m)*256 + swt2] = Aj;
    }
  }
  __syncthreads();

  #pragma unroll
  for (int n1 = 0; n1 < 16; ++n1) v[n1] = L[swt + n1*256];
  fft4096_reg<+1>(v, L);

  __syncthreads();
  #pragma unroll
  for (int kb = 0; kb < 8; ++kb)
    L[xb + 256*kb] = v[RI(kb)];
  __syncthreads();
  const float inv = 1.0f / 4096.0f;
  unsigned* og = (unsigned*)rp;         // bf16 overlay (2 tokens / dword)
  #pragma unroll
  for (int n1 = 0; n1 < 8; ++n1){
    cf cv = L[swt + n1*256];
    float x0 = fmaf(dskd, uin[n1].x, cv.x * inv);
    float x1 = fmaf(dskd, uin[n1].y, cv.y * inv);
    unsigned b0 = (unsigned)(unsigned short)f2bf(gelu_exact(x0));
    unsigned b1 = (unsigned)(unsigned short)f2bf(gelu_exact(x1));
    og[n1*256 + t] = b0 | (b1 << 16);
  }
}

// ---------------------------------------------------------------------------
// Kernel 5: X = Z @ W^T + b + u ; LayerNorm -> out.  32 tokens/block (grid
// 1024).  acc C-INITIALIZED with (bias + u); Wbf fragment-major.
__global__ __launch_bounds__(256)
void mfma_gemm_ln(const float* __restrict__ utg, const short* __restrict__ Wbf,
                  const float* __restrict__ bias, const float* __restrict__ u,
                  const float* __restrict__ gamma, const float* __restrict__ beta,
                  float* __restrict__ out){
  __shared__ short St[64][32];        // one k-chunk: 64 k x 32 tokens
  __shared__ float prm[2][256];       // gamma / beta
  __shared__ float2 red[2][2][16];    // [tok-half][feat-half][lm]
  const int w    = threadIdx.x >> 6;
  const int l    = threadIdx.x & 63;
  const int lm   = l & 15;
  const int lk   = l >> 4;
  const int tokB = blockIdx.x * 32;   // never straddles batch (32 | 4096)
  const int b    = tokB >> 12;
  const int l0   = tokB & 4095;

  prm[0][threadIdx.x] = gamma[threadIdx.x];
  prm[1][threadIdx.x] = beta[threadIdx.x];

  const int srow = l >> 2;            // k-row within warp's 16
  const int tg   = l & 3;             // token-group of 8
  const char* ubase = (const char*)utg + (size_t)(b * 256) * 16384;
  bf16x8 pre[4];
  #pragma unroll
  for (int c = 0; c < 4; ++c){
    int r = c*64 + w*16 + srow;
    pre[c] = *(const bf16x8*)((const unsigned short*)(ubase + (size_t)r * 16384) + l0 + tg*8);
  }

  const int th = (w & 1) * 16;        // token half
  const int fh2 = w >> 1;
  const int fh = fh2 * 128;           // feature half
  const int tt = tokB + th + lm;      // this lane's token
  const float* ur = u + (size_t)tt * 256 + fh;
  const float* br = bias + fh;
  f32x4 acc[8];
  #pragma unroll
  for (int nt = 0; nt < 8; ++nt){
    const float4 uv = *(const float4*)(ur + nt*16 + lk*4);
    const float4 bv = *(const float4*)(br + nt*16 + lk*4);
    acc[nt] = (f32x4){uv.x + bv.x, uv.y + bv.y, uv.z + bv.z, uv.w + bv.w};
  }

  const int tg_tok = (th + lm) >> 3;
  const int tlo    = lm & 7;

  #pragma unroll
  for (int c = 0; c < 4; ++c){
    __syncthreads();
    {
      int r  = w*16 + srow;
      int sl = (tg ^ ((r >> 3) & 3)) * 8;
      *(bf16x8*)&St[r][sl] = pre[c];
    }
    __syncthreads();
    #pragma unroll
    for (int s2 = 0; s2 < 2; ++s2){
      const int ks  = c*2 + s2;
      const int idx = ((tg_tok ^ lk) << 3) | tlo;
      bf16x8 zf;
      #pragma unroll
      for (int j = 0; j < 8; ++j)
        zf[j] = St[s2*32 + lk*8 + j][idx];
      const short* wbase = Wbf + (size_t)(ks*2 + fh2)*4096 + lk*128 + lm*8;
      #pragma unroll
      for (int nt = 0; nt < 8; ++nt){
        const bf16x8* ap = (const bf16x8*)(wbase + nt*512);
        acc[nt] = __builtin_amdgcn_mfma_f32_16x16x32_bf16(*ap, zf, acc[nt], 0, 0, 0);
      }
    }
  }

  float s = 0.f, s2 = 0.f;
  #pragma unroll
  for (int nt = 0; nt < 8; ++nt){
    s += acc[nt][0] + acc[nt][1] + acc[nt][2] + acc[nt][3];
    s2 = fmaf(acc[nt][0], acc[nt][0], s2);
    s2 = fmaf(acc[nt][1], acc[nt][1], s2);
    s2 = fmaf(acc[nt][2], acc[nt][2], s2);
    s2 = fmaf(acc[nt][3], acc[nt][3], s2);
  }
  s  += __shfl_xor(s,  16); s  += __shfl_xor(s,  32);
  s2 += __shfl_xor(s2, 16); s2 += __shfl_xor(s2, 32);
  __syncthreads();
  if (lk == 0) red[w & 1][fh2][lm] = make_float2(s, s2);
  __syncthreads();
  const float2 pj = red[w & 1][fh2 ^ 1][lm];
  const float st = s + pj.x, s2t = s2 + pj.y;
  const float mu = st * (1.0f/256.0f);
  const float rs = rsqrtf(s2t * (1.0f/256.0f) - mu*mu + 1e-5f);
  float* orow = out + (size_t)tt * 256 + fh;
  #pragma unroll
  for (int nt = 0; nt < 8; ++nt){
    const int f0 = fh + nt*16 + lk*4;
    const float4 gv = *(const float4*)&prm[0][f0];
    const float4 ev = *(const float4*)&prm[1][f0];
    float4 o;
    o.x = (acc[nt][0] - mu) * rs * gv.x + ev.x;
    o.y = (acc[nt][1] - mu) * rs * gv.y + ev.y;
    o.z = (acc[nt][2] - mu) * rs * gv.z + ev.z;
    o.w = (acc[nt][3] - mu) * rs * gv.w + ev.w;
    *(float4*)(orow + nt*16 + lk*4) = o;
  }
}

// ---------------------------------------------------------------------------
extern "C" void kernel_launch(void* const* d_in, const int* in_sizes, int n_in,
                              void* d_out, int out_size, void* d_ws, size_t ws_size,
                              hipStream_t stream){
  (void)in_sizes; (void)n_in; (void)out_size; (void)ws_size;
  const float* u        = (const float*)d_in[0];
  const float* B_ri     = (const float*)d_in[1];
  const float* Ct_ri    = (const float*)d_in[2];
  const float* lam_ri   = (const float*)d_in[3];
  const float* p_ri     = (const float*)d_in[4];
  const float* q_ri     = (const float*)d_in[5];
  const float* log_step = (const float*)d_in[6];
  const float* D_skip   = (const float*)d_in[7];
  const float* W        = (const float*)d_in[8];
  const float* bias     = (const float*)d_in[9];
  const float* gamma    = (const float*)d_in[10];
  const float* beta     = (const float*)d_in[11];
  float* out = (float*)d_out;

  // Workspace: KdE 4,196,352 | KdO 4,194,304 | Wbf 131,072 | ut 33,554,432
  char* ws = (char*)d_ws;
  float* KdE = (float*)(ws);
  float* KdO = (float*)(ws + 4196352);
  short* Wbf = (short*)(ws + 4196352 + 4194304);
  float* ut  = (float*)(ws + 4196352 + 4194304 + 131072);

  fused_head  <<<2112, 256, 0, stream>>>(B_ri, Ct_ri, lam_ri, p_ri, q_ri,
                                         log_step, KdE, W, Wbf);
  fused_mid   <<<8448, 256, 0, stream>>>(KdE, KdO, u, ut);
  s4_conv     <<<2048, 256, 0, stream>>>(ut, KdE, KdO, D_skip);
  mfma_gemm_ln<<<1024, 256, 0, stream>>>(ut, Wbf, bias, u, gamma, beta, out);
}